// Round 1
// baseline (1116.369 us; speedup 1.0000x reference)
//
#include <hip/hip_runtime.h>

#define NN 50000
#define NE 600000
#define NB 4096
#define DD 128
#define EPSV 1e-5f

// ---------------- CSR build ----------------
__global__ void k_deg(const int* __restrict__ dst, int* __restrict__ cnt) {
    int e = blockIdx.x * 256 + threadIdx.x;
    if (e < NE) atomicAdd(&cnt[dst[e]], 1);
}

__global__ void k_scan1(const int* __restrict__ cnt, int* __restrict__ ptr,
                        int* __restrict__ bsum) {
    int tid = threadIdx.x;
    int i = blockIdx.x * 256 + tid;
    int v = (i < NN) ? cnt[i] : 0;
    int lane = tid & 63, wid = tid >> 6;
    int x = v;
#pragma unroll
    for (int off = 1; off < 64; off <<= 1) {
        int y = __shfl_up(x, off, 64);
        if (lane >= off) x += y;
    }
    __shared__ int wsum[4];
    if (lane == 63) wsum[wid] = x;
    __syncthreads();
    int add = 0;
#pragma unroll
    for (int w = 0; w < 4; w++)
        if (w < wid) add += wsum[w];
    int incl = x + add;
    if (i < NN) ptr[i] = incl - v;          // block-local exclusive scan
    if (tid == 255) bsum[blockIdx.x] = incl; // block total
}

__global__ void k_scan2(const int* __restrict__ bsum, int* __restrict__ boff, int nb) {
    int tid = threadIdx.x;
    int v = (tid < nb) ? bsum[tid] : 0;
    int lane = tid & 63, wid = tid >> 6;
    int x = v;
#pragma unroll
    for (int off = 1; off < 64; off <<= 1) {
        int y = __shfl_up(x, off, 64);
        if (lane >= off) x += y;
    }
    __shared__ int wsum[4];
    if (lane == 63) wsum[wid] = x;
    __syncthreads();
    int add = 0;
#pragma unroll
    for (int w = 0; w < 4; w++)
        if (w < wid) add += wsum[w];
    boff[tid] = x + add - v;                 // exclusive
}

__global__ void k_scan3(const int* __restrict__ cnt, const int* __restrict__ boff,
                        int* __restrict__ ptr, int* __restrict__ nxt,
                        float* __restrict__ invd) {
    int i = blockIdx.x * 256 + threadIdx.x;
    if (i < NN) {
        int p = ptr[i] + boff[blockIdx.x];
        ptr[i] = p;
        nxt[i] = p;
        int c = cnt[i];
        invd[i] = 1.0f / (float)(c > 1 ? c : 1);
    }
    if (i == 0) ptr[NN] = NE;
}

__global__ void k_scatter(const int* __restrict__ src, const int* __restrict__ dst,
                          int* __restrict__ nxt, int* __restrict__ csr) {
    int e = blockIdx.x * 256 + threadIdx.x;
    if (e < NE) {
        int d = dst[e];
        int p = atomicAdd(&nxt[d], 1);
        csr[p] = src[e];
    }
}

// ---------------- neighbor mean-aggregation (pull via CSR) ----------------
// one wave per node; lane covers 2 feature dims
__global__ void k_gather(const float* __restrict__ x, const int* __restrict__ ptr,
                         const int* __restrict__ csr, const float* __restrict__ invd,
                         float* __restrict__ agg) {
    int wid = threadIdx.x >> 6;
    int lane = threadIdx.x & 63;
    int n = blockIdx.x * 4 + wid;
    if (n >= NN) return;
    int beg = ptr[n], end = ptr[n + 1];
    float a0 = 0.f, a1 = 0.f;
    for (int e = beg; e < end; e++) {
        int s = csr[e];
        float2 v = *(const float2*)(x + (size_t)s * DD + 2 * lane);
        a0 += v.x;
        a1 += v.y;
    }
    float id = invd[n];
    float2 o;
    o.x = a0 * id;
    o.y = a1 * id;
    *(float2*)(agg + (size_t)n * DD + 2 * lane) = o;
}

// ---------------- fused SAGE layer GEMM ----------------
// C[r][j] = relu( s[j]*(sum_k A[r][k]*Wl[k][j] + sum_k X[r][k]*Wr[k][j] + bl[j] - mn[j]) + be[j] )
// C may alias A (row-local op: each block reads only its own rows before writing them).
__launch_bounds__(256)
__global__ void k_gemm(const float* __restrict__ A, const float* __restrict__ X,
                       const float* __restrict__ Wl, const float* __restrict__ Wr,
                       const float* __restrict__ bl, const float* __restrict__ g,
                       const float* __restrict__ be, const float* __restrict__ mn,
                       const float* __restrict__ vr, float* __restrict__ C) {
    __shared__ float As[32][68];   // [k][row], +4 pad keeps float4 reads aligned & banks spread
    __shared__ float Bs[32][128];  // [k][j]
    int tid = threadIdx.x;
    int r0 = blockIdx.x * 64;
    int trow = (tid >> 4) * 4;   // 0..60
    int tcol = (tid & 15) * 8;   // 0..120

    float acc[4][8];
#pragma unroll
    for (int i = 0; i < 4; i++)
#pragma unroll
        for (int j = 0; j < 8; j++) acc[i][j] = 0.f;

    int la_r = tid >> 3;         // 0..31 (A loader: 8 threads x float4 per row)
    int la_k = (tid & 7) * 4;
    int lb_k = tid >> 5;         // 0..7  (B loader: 32 threads x float4 per k-row)
    int lb_j = (tid & 31) * 4;

#pragma unroll
    for (int phase = 0; phase < 2; phase++) {
        const float* S = phase ? X : A;
        const float* W = phase ? Wr : Wl;
        for (int kc = 0; kc < 128; kc += 32) {
            __syncthreads();
            // stage A-tile transposed: As[k][row]
#pragma unroll
            for (int p = 0; p < 2; p++) {
                int row = p * 32 + la_r;
                int grow = r0 + row;
                float4 v = make_float4(0.f, 0.f, 0.f, 0.f);
                if (grow < NN) v = *(const float4*)(S + (size_t)grow * DD + kc + la_k);
                As[la_k + 0][row] = v.x;
                As[la_k + 1][row] = v.y;
                As[la_k + 2][row] = v.z;
                As[la_k + 3][row] = v.w;
            }
            // stage W-tile: Bs[k][j]
#pragma unroll
            for (int p = 0; p < 4; p++) {
                int k = p * 8 + lb_k;
                *(float4*)&Bs[k][lb_j] = *(const float4*)(W + (size_t)(kc + k) * DD + lb_j);
            }
            __syncthreads();
#pragma unroll
            for (int kk = 0; kk < 32; kk++) {
                float4 a4 = *(const float4*)&As[kk][trow];
                float4 b0 = *(const float4*)&Bs[kk][tcol];
                float4 b1 = *(const float4*)&Bs[kk][tcol + 4];
                float av[4] = {a4.x, a4.y, a4.z, a4.w};
                float bv[8] = {b0.x, b0.y, b0.z, b0.w, b1.x, b1.y, b1.z, b1.w};
#pragma unroll
                for (int i = 0; i < 4; i++)
#pragma unroll
                    for (int j = 0; j < 8; j++) acc[i][j] += av[i] * bv[j];
            }
        }
    }

    // epilogue: bias + BN(eval) + relu
    float sc[8], sh[8];
#pragma unroll
    for (int j = 0; j < 8; j++) {
        int jj = tcol + j;
        float s = g[jj] * rsqrtf(vr[jj] + EPSV);
        sc[j] = s;
        sh[j] = (bl[jj] - mn[jj]) * s + be[jj];
    }
#pragma unroll
    for (int i = 0; i < 4; i++) {
        int grow = r0 + trow + i;
        if (grow < NN) {
            float4 o0, o1;
            o0.x = fmaxf(acc[i][0] * sc[0] + sh[0], 0.f);
            o0.y = fmaxf(acc[i][1] * sc[1] + sh[1], 0.f);
            o0.z = fmaxf(acc[i][2] * sc[2] + sh[2], 0.f);
            o0.w = fmaxf(acc[i][3] * sc[3] + sh[3], 0.f);
            o1.x = fmaxf(acc[i][4] * sc[4] + sh[4], 0.f);
            o1.y = fmaxf(acc[i][5] * sc[5] + sh[5], 0.f);
            o1.z = fmaxf(acc[i][6] * sc[6] + sh[6], 0.f);
            o1.w = fmaxf(acc[i][7] * sc[7] + sh[7], 0.f);
            *(float4*)(C + (size_t)grow * DD + tcol) = o0;
            *(float4*)(C + (size_t)grow * DD + tcol + 4) = o1;
        }
    }
}

// ---------------- global add pool ----------------
__global__ void k_pool(const float* __restrict__ h, const int* __restrict__ batch,
                       float* __restrict__ p) {
    int wid = threadIdx.x >> 6;
    int lane = threadIdx.x & 63;
    int n = blockIdx.x * 4 + wid;
    if (n >= NN) return;
    int b = batch[n];
    float2 v = *(const float2*)(h + (size_t)n * DD + 2 * lane);
    atomicAdd(&p[(size_t)b * DD + 2 * lane], v.x);
    atomicAdd(&p[(size_t)b * DD + 2 * lane + 1], v.y);
}

// ---------------- final MLP head ----------------
__launch_bounds__(128)
__global__ void k_mlp(const float* __restrict__ p1, const float* __restrict__ p2,
                      const int* __restrict__ rel, const float* __restrict__ kge,
                      const float* __restrict__ W1, const float* __restrict__ b1,
                      const float* __restrict__ W2, const float* __restrict__ b2,
                      float* __restrict__ out) {
    int b = blockIdx.x;
    int tid = threadIdx.x;
    __shared__ float z[384];
    z[tid] = p1[(size_t)b * DD + tid];
    z[tid + 128] = p2[(size_t)b * DD + tid];
    int r = rel[b];
    z[tid + 256] = kge[(size_t)r * DD + tid];
    __syncthreads();
    float acc = b1[tid];
#pragma unroll 8
    for (int k = 0; k < 384; k++) acc += z[k] * W1[k * DD + tid];
    float h = fmaxf(acc, 0.f);
    float v = h * W2[tid];
#pragma unroll
    for (int off = 32; off > 0; off >>= 1) v += __shfl_down(v, off, 64);
    __shared__ float wsf[2];
    if ((tid & 63) == 0) wsf[tid >> 6] = v;
    __syncthreads();
    if (tid == 0) out[b] = wsf[0] + wsf[1] + b2[0];
}

extern "C" void kernel_launch(void* const* d_in, const int* in_sizes, int n_in,
                              void* d_out, int out_size, void* d_ws, size_t ws_size,
                              hipStream_t stream) {
    const float* x1  = (const float*)d_in[0];
    const float* x2  = (const float*)d_in[1];
    const int*   ei1 = (const int*)d_in[2];
    const int*   ei2 = (const int*)d_in[3];
    const int*   bt1 = (const int*)d_in[4];
    const int*   bt2 = (const int*)d_in[5];
    const int*   rel = (const int*)d_in[6];
    const float* Wl  = (const float*)d_in[7];
    const float* bl  = (const float*)d_in[8];
    const float* Wr  = (const float*)d_in[9];
    const float* g   = (const float*)d_in[10];
    const float* be  = (const float*)d_in[11];
    const float* mn  = (const float*)d_in[12];
    const float* vr  = (const float*)d_in[13];
    const float* kge = (const float*)d_in[14];
    const float* W1  = (const float*)d_in[15];
    const float* b1v = (const float*)d_in[16];
    const float* W2  = (const float*)d_in[17];
    const float* b2v = (const float*)d_in[18];

    char* ws = (char*)d_ws;
    size_t off = 0;
    auto alloc = [&](size_t bytes) {
        void* p = ws + off;
        off += (bytes + 255) & ~(size_t)255;
        return p;
    };
    float* bufA  = (float*)alloc((size_t)NN * DD * 4);
    float* bufB  = (float*)alloc((size_t)NN * DD * 4);
    float* p1    = (float*)alloc((size_t)NB * DD * 4);
    float* p2    = (float*)alloc((size_t)NB * DD * 4);
    int*   cnt   = (int*)alloc((size_t)NN * 4);
    int*   ptr   = (int*)alloc((size_t)(NN + 1) * 4);
    int*   nxt   = (int*)alloc((size_t)NN * 4);
    float* invd  = (float*)alloc((size_t)NN * 4);
    int*   csr   = (int*)alloc((size_t)NE * 4);
    int*   bsum  = (int*)alloc(256 * 4);
    int*   boff  = (int*)alloc(256 * 4);
    if (off > ws_size) return;  // workspace too small: fail loud (wrong output) not crash

    const int nbScan = (NN + 255) / 256;     // 196
    const int nbEdge = (NE + 255) / 256;     // 2344
    const int nbNode4 = (NN + 3) / 4;        // 12500
    const int nbGemm = (NN + 63) / 64;       // 782

    for (int side = 0; side < 2; side++) {
        const float* x   = side ? x2 : x1;
        const int*   src = side ? ei2 : ei1;
        const int*   dst = src + NE;
        const int*   bat = side ? bt2 : bt1;
        float*       pp  = side ? p2 : p1;

        hipMemsetAsync(cnt, 0, (size_t)NN * 4, stream);
        hipMemsetAsync(pp, 0, (size_t)NB * DD * 4, stream);
        k_deg<<<nbEdge, 256, 0, stream>>>(dst, cnt);
        k_scan1<<<nbScan, 256, 0, stream>>>(cnt, ptr, bsum);
        k_scan2<<<1, 256, 0, stream>>>(bsum, boff, nbScan);
        k_scan3<<<nbScan, 256, 0, stream>>>(cnt, boff, ptr, nxt, invd);
        k_scatter<<<nbEdge, 256, 0, stream>>>(src, dst, nxt, csr);

        // layer 0: x -> agg(bufB); gemm(bufB, x) -> bufB (in place)
        k_gather<<<nbNode4, 256, 0, stream>>>(x, ptr, csr, invd, bufB);
        k_gemm<<<nbGemm, 256, 0, stream>>>(bufB, x, Wl, Wr, bl, g, be, mn, vr, bufB);
        // layer 1: bufB -> agg(bufA); gemm(bufA, bufB) -> bufA
        k_gather<<<nbNode4, 256, 0, stream>>>(bufB, ptr, csr, invd, bufA);
        k_gemm<<<nbGemm, 256, 0, stream>>>(bufA, bufB, Wl + 16384, Wr + 16384, bl + 128,
                                           g + 128, be + 128, mn + 128, vr + 128, bufA);
        // layer 2: bufA -> agg(bufB); gemm(bufB, bufA) -> bufB
        k_gather<<<nbNode4, 256, 0, stream>>>(bufA, ptr, csr, invd, bufB);
        k_gemm<<<nbGemm, 256, 0, stream>>>(bufB, bufA, Wl + 32768, Wr + 32768, bl + 256,
                                           g + 256, be + 256, mn + 256, vr + 256, bufB);

        k_pool<<<nbNode4, 256, 0, stream>>>(bufB, bat, pp);
    }

    k_mlp<<<NB, 128, 0, stream>>>(p1, p2, rel, kge, W1, b1v, W2, b2v, (float*)d_out);
}

// Round 2
// 1023.613 us; speedup vs baseline: 1.0906x; 1.0906x over previous
//
#include <hip/hip_runtime.h>

#define NN 50000
#define NE 600000
#define NB 4096
#define DD 128
#define EPSV 1e-5f

// ---------------- CSR build ----------------
__global__ void k_deg(const int* __restrict__ dst, int* __restrict__ cnt) {
    int e = blockIdx.x * 256 + threadIdx.x;
    if (e < NE) atomicAdd(&cnt[dst[e]], 1);
}

__global__ void k_scan1(const int* __restrict__ cnt, int* __restrict__ ptr,
                        int* __restrict__ bsum) {
    int tid = threadIdx.x;
    int i = blockIdx.x * 256 + tid;
    int v = (i < NN) ? cnt[i] : 0;
    int lane = tid & 63, wid = tid >> 6;
    int x = v;
#pragma unroll
    for (int off = 1; off < 64; off <<= 1) {
        int y = __shfl_up(x, off, 64);
        if (lane >= off) x += y;
    }
    __shared__ int wsum[4];
    if (lane == 63) wsum[wid] = x;
    __syncthreads();
    int add = 0;
#pragma unroll
    for (int w = 0; w < 4; w++)
        if (w < wid) add += wsum[w];
    int incl = x + add;
    if (i < NN) ptr[i] = incl - v;           // block-local exclusive scan
    if (tid == 255) bsum[blockIdx.x] = incl; // block total
}

__global__ void k_scan2(const int* __restrict__ bsum, int* __restrict__ boff, int nb) {
    int tid = threadIdx.x;
    int v = (tid < nb) ? bsum[tid] : 0;
    int lane = tid & 63, wid = tid >> 6;
    int x = v;
#pragma unroll
    for (int off = 1; off < 64; off <<= 1) {
        int y = __shfl_up(x, off, 64);
        if (lane >= off) x += y;
    }
    __shared__ int wsum[4];
    if (lane == 63) wsum[wid] = x;
    __syncthreads();
    int add = 0;
#pragma unroll
    for (int w = 0; w < 4; w++)
        if (w < wid) add += wsum[w];
    boff[tid] = x + add - v;                 // exclusive
}

__global__ void k_scan3(const int* __restrict__ cnt, const int* __restrict__ boff,
                        int* __restrict__ ptr, int* __restrict__ nxt,
                        float* __restrict__ invd) {
    int i = blockIdx.x * 256 + threadIdx.x;
    if (i < NN) {
        int p = ptr[i] + boff[blockIdx.x];
        ptr[i] = p;
        nxt[i] = p;
        int c = cnt[i];
        invd[i] = 1.0f / (float)(c > 1 ? c : 1);
    }
    if (i == 0) ptr[NN] = NE;
}

__global__ void k_scatter(const int* __restrict__ src, const int* __restrict__ dst,
                          int* __restrict__ nxt, int* __restrict__ csr) {
    int e = blockIdx.x * 256 + threadIdx.x;
    if (e < NE) {
        int d = dst[e];
        int p = atomicAdd(&nxt[d], 1);
        csr[p] = src[e];
    }
}

// ---------------- neighbor mean-aggregation (pull via CSR) ----------------
// one wave per node; half-wave per edge, float4 per lane (32 lanes cover 128 cols)
__global__ void k_gather(const float* __restrict__ x, const int* __restrict__ ptr,
                         const int* __restrict__ csr, const float* __restrict__ invd,
                         float* __restrict__ agg) {
    int wid = threadIdx.x >> 6;
    int lane = threadIdx.x & 63;
    int half = lane >> 5;
    int l32 = lane & 31;
    int n = blockIdx.x * 4 + wid;
    if (n >= NN) return;
    int beg = ptr[n], end = ptr[n + 1];
    float4 a0 = make_float4(0.f, 0.f, 0.f, 0.f);
    float4 a1 = make_float4(0.f, 0.f, 0.f, 0.f);
    int e = beg + half;
    // main: 2 edges per half-lane iteration (4 edges/wave in flight)
    for (; e + 2 < end; e += 4) {
        int s0 = csr[e];
        int s1 = csr[e + 2];
        float4 v0 = *(const float4*)(x + (size_t)s0 * DD + 4 * l32);
        float4 v1 = *(const float4*)(x + (size_t)s1 * DD + 4 * l32);
        a0.x += v0.x; a0.y += v0.y; a0.z += v0.z; a0.w += v0.w;
        a1.x += v1.x; a1.y += v1.y; a1.z += v1.z; a1.w += v1.w;
    }
    if (e < end) {
        int s0 = csr[e];
        float4 v0 = *(const float4*)(x + (size_t)s0 * DD + 4 * l32);
        a0.x += v0.x; a0.y += v0.y; a0.z += v0.z; a0.w += v0.w;
    }
    a0.x += a1.x; a0.y += a1.y; a0.z += a1.z; a0.w += a1.w;
    // combine the two half-waves (lane i += lane i+32)
    a0.x += __shfl_down(a0.x, 32, 64);
    a0.y += __shfl_down(a0.y, 32, 64);
    a0.z += __shfl_down(a0.z, 32, 64);
    a0.w += __shfl_down(a0.w, 32, 64);
    if (half == 0) {
        float id = invd[n];
        float4 o;
        o.x = a0.x * id; o.y = a0.y * id; o.z = a0.z * id; o.w = a0.w * id;
        *(float4*)(agg + (size_t)n * DD + 4 * l32) = o;
    }
}

// ---------------- fused SAGE layer GEMM ----------------
// C[r][j] = relu( s[j]*(sum_k A[r][k]*Wl[k][j] + sum_k X[r][k]*Wr[k][j] + bl[j] - mn[j]) + be[j] )
// C may alias A (row-local: each block reads only its own 64 rows before writing them).
// If dopool != 0: instead of storing C, atomicAdd results into pool[batch[row]*DD + col].
__launch_bounds__(256)
__global__ void k_gemm(const float* __restrict__ A, const float* __restrict__ X,
                       const float* __restrict__ Wl, const float* __restrict__ Wr,
                       const float* __restrict__ bl, const float* __restrict__ g,
                       const float* __restrict__ be, const float* __restrict__ mn,
                       const float* __restrict__ vr, float* __restrict__ C,
                       const int* __restrict__ batch, float* __restrict__ pool,
                       int dopool) {
    __shared__ float As[32][68];   // [k][row], +4 pad
    __shared__ float Bs[32][128];  // [k][j]
    int tid = threadIdx.x;
    int r0 = blockIdx.x * 64;
    int trow = (tid >> 4) * 4;   // 0..60
    int tcol = (tid & 15) * 4;   // 0..60 ; thread's cols = tcol..tcol+3 and tcol+64..tcol+67

    float acc[4][8];
#pragma unroll
    for (int i = 0; i < 4; i++)
#pragma unroll
        for (int j = 0; j < 8; j++) acc[i][j] = 0.f;

    int la_r = tid >> 3;         // 0..31 (A loader)
    int la_k = (tid & 7) * 4;
    int lb_k = tid >> 5;         // 0..7  (B loader)
    int lb_j = (tid & 31) * 4;

#pragma unroll
    for (int phase = 0; phase < 2; phase++) {
        const float* S = phase ? X : A;
        const float* W = phase ? Wr : Wl;
        for (int kc = 0; kc < 128; kc += 32) {
            __syncthreads();
#pragma unroll
            for (int p = 0; p < 2; p++) {
                int row = p * 32 + la_r;
                int grow = r0 + row;
                float4 v = make_float4(0.f, 0.f, 0.f, 0.f);
                if (grow < NN) v = *(const float4*)(S + (size_t)grow * DD + kc + la_k);
                As[la_k + 0][row] = v.x;
                As[la_k + 1][row] = v.y;
                As[la_k + 2][row] = v.z;
                As[la_k + 3][row] = v.w;
            }
#pragma unroll
            for (int p = 0; p < 4; p++) {
                int k = p * 8 + lb_k;
                *(float4*)&Bs[k][lb_j] = *(const float4*)(W + (size_t)(kc + k) * DD + lb_j);
            }
            __syncthreads();
#pragma unroll
            for (int kk = 0; kk < 32; kk++) {
                float4 a4 = *(const float4*)&As[kk][trow];
                float4 b0 = *(const float4*)&Bs[kk][tcol];        // banks 4*lane..: conflict-free
                float4 b1 = *(const float4*)&Bs[kk][tcol + 64];   // conflict-free
                float av[4] = {a4.x, a4.y, a4.z, a4.w};
                float bv[8] = {b0.x, b0.y, b0.z, b0.w, b1.x, b1.y, b1.z, b1.w};
#pragma unroll
                for (int i = 0; i < 4; i++)
#pragma unroll
                    for (int j = 0; j < 8; j++) acc[i][j] += av[i] * bv[j];
            }
        }
    }

    // epilogue: bias + BN(eval) + relu  (cols tcol..tcol+3, tcol+64..tcol+67)
    float sc[8], sh[8];
#pragma unroll
    for (int j = 0; j < 8; j++) {
        int jj = tcol + (j < 4 ? j : 60 + j);   // j>=4 -> tcol+64+(j-4)
        float s = g[jj] * rsqrtf(vr[jj] + EPSV);
        sc[j] = s;
        sh[j] = (bl[jj] - mn[jj]) * s + be[jj];
    }
#pragma unroll
    for (int i = 0; i < 4; i++) {
        int grow = r0 + trow + i;
        if (grow < NN) {
            float o[8];
#pragma unroll
            for (int j = 0; j < 8; j++) o[j] = fmaxf(acc[i][j] * sc[j] + sh[j], 0.f);
            if (dopool) {
                int b = batch[grow];
                float* pb = pool + (size_t)b * DD;
#pragma unroll
                for (int j = 0; j < 4; j++) atomicAdd(&pb[tcol + j], o[j]);
#pragma unroll
                for (int j = 4; j < 8; j++) atomicAdd(&pb[tcol + 60 + j], o[j]);
            } else {
                float4 o0 = make_float4(o[0], o[1], o[2], o[3]);
                float4 o1 = make_float4(o[4], o[5], o[6], o[7]);
                *(float4*)(C + (size_t)grow * DD + tcol) = o0;
                *(float4*)(C + (size_t)grow * DD + tcol + 64) = o1;
            }
        }
    }
}

// ---------------- final MLP head ----------------
__launch_bounds__(128)
__global__ void k_mlp(const float* __restrict__ p1, const float* __restrict__ p2,
                      const int* __restrict__ rel, const float* __restrict__ kge,
                      const float* __restrict__ W1, const float* __restrict__ b1,
                      const float* __restrict__ W2, const float* __restrict__ b2,
                      float* __restrict__ out) {
    int b = blockIdx.x;
    int tid = threadIdx.x;
    __shared__ float z[384];
    z[tid] = p1[(size_t)b * DD + tid];
    z[tid + 128] = p2[(size_t)b * DD + tid];
    int r = rel[b];
    z[tid + 256] = kge[(size_t)r * DD + tid];
    __syncthreads();
    float acc = b1[tid];
#pragma unroll 8
    for (int k = 0; k < 384; k++) acc += z[k] * W1[k * DD + tid];
    float h = fmaxf(acc, 0.f);
    float v = h * W2[tid];
#pragma unroll
    for (int off = 32; off > 0; off >>= 1) v += __shfl_down(v, off, 64);
    __shared__ float wsf[2];
    if ((tid & 63) == 0) wsf[tid >> 6] = v;
    __syncthreads();
    if (tid == 0) out[b] = wsf[0] + wsf[1] + b2[0];
}

extern "C" void kernel_launch(void* const* d_in, const int* in_sizes, int n_in,
                              void* d_out, int out_size, void* d_ws, size_t ws_size,
                              hipStream_t stream) {
    const float* x1  = (const float*)d_in[0];
    const float* x2  = (const float*)d_in[1];
    const int*   ei1 = (const int*)d_in[2];
    const int*   ei2 = (const int*)d_in[3];
    const int*   bt1 = (const int*)d_in[4];
    const int*   bt2 = (const int*)d_in[5];
    const int*   rel = (const int*)d_in[6];
    const float* Wl  = (const float*)d_in[7];
    const float* bl  = (const float*)d_in[8];
    const float* Wr  = (const float*)d_in[9];
    const float* g   = (const float*)d_in[10];
    const float* be  = (const float*)d_in[11];
    const float* mn  = (const float*)d_in[12];
    const float* vr  = (const float*)d_in[13];
    const float* kge = (const float*)d_in[14];
    const float* W1  = (const float*)d_in[15];
    const float* b1v = (const float*)d_in[16];
    const float* W2  = (const float*)d_in[17];
    const float* b2v = (const float*)d_in[18];

    char* ws = (char*)d_ws;
    size_t off = 0;
    auto alloc = [&](size_t bytes) {
        void* p = ws + off;
        off += (bytes + 255) & ~(size_t)255;
        return p;
    };
    float* bufA  = (float*)alloc((size_t)NN * DD * 4);
    float* bufB  = (float*)alloc((size_t)NN * DD * 4);
    float* p1    = (float*)alloc((size_t)NB * DD * 4);
    float* p2    = (float*)alloc((size_t)NB * DD * 4);
    int*   cnt   = (int*)alloc((size_t)NN * 4);
    int*   ptr   = (int*)alloc((size_t)(NN + 1) * 4);
    int*   nxt   = (int*)alloc((size_t)NN * 4);
    float* invd  = (float*)alloc((size_t)NN * 4);
    int*   csr   = (int*)alloc((size_t)NE * 4);
    int*   bsum  = (int*)alloc(256 * 4);
    int*   boff  = (int*)alloc(256 * 4);
    if (off > ws_size) return;

    const int nbScan = (NN + 255) / 256;     // 196
    const int nbEdge = (NE + 255) / 256;     // 2344
    const int nbNode4 = (NN + 3) / 4;        // 12500
    const int nbGemm = (NN + 63) / 64;       // 782

    for (int side = 0; side < 2; side++) {
        const float* x   = side ? x2 : x1;
        const int*   src = side ? ei2 : ei1;
        const int*   dst = src + NE;
        const int*   bat = side ? bt2 : bt1;
        float*       pp  = side ? p2 : p1;

        hipMemsetAsync(cnt, 0, (size_t)NN * 4, stream);
        hipMemsetAsync(pp, 0, (size_t)NB * DD * 4, stream);
        k_deg<<<nbEdge, 256, 0, stream>>>(dst, cnt);
        k_scan1<<<nbScan, 256, 0, stream>>>(cnt, ptr, bsum);
        k_scan2<<<1, 256, 0, stream>>>(bsum, boff, nbScan);
        k_scan3<<<nbScan, 256, 0, stream>>>(cnt, boff, ptr, nxt, invd);
        k_scatter<<<nbEdge, 256, 0, stream>>>(src, dst, nxt, csr);

        // layer 0
        k_gather<<<nbNode4, 256, 0, stream>>>(x, ptr, csr, invd, bufB);
        k_gemm<<<nbGemm, 256, 0, stream>>>(bufB, x, Wl, Wr, bl, g, be, mn, vr, bufB,
                                           bat, pp, 0);
        // layer 1
        k_gather<<<nbNode4, 256, 0, stream>>>(bufB, ptr, csr, invd, bufA);
        k_gemm<<<nbGemm, 256, 0, stream>>>(bufA, bufB, Wl + 16384, Wr + 16384, bl + 128,
                                           g + 128, be + 128, mn + 128, vr + 128, bufA,
                                           bat, pp, 0);
        // layer 2 (+ fused global_add_pool)
        k_gather<<<nbNode4, 256, 0, stream>>>(bufA, ptr, csr, invd, bufB);
        k_gemm<<<nbGemm, 256, 0, stream>>>(bufB, bufA, Wl + 32768, Wr + 32768, bl + 256,
                                           g + 256, be + 256, mn + 256, vr + 256, bufB,
                                           bat, pp, 1);
    }

    k_mlp<<<NB, 128, 0, stream>>>(p1, p2, rel, kge, W1, b1v, W2, b2v, (float*)d_out);
}

// Round 3
// 904.669 us; speedup vs baseline: 1.2340x; 1.1315x over previous
//
#include <hip/hip_runtime.h>

#define NN 50000
#define NE 600000
#define NB 4096
#define DD 128
#define EPSV 1e-5f

// ---------------- CSR build ----------------
__global__ void k_deg(const int* __restrict__ dst, int* __restrict__ cnt) {
    int e = blockIdx.x * 256 + threadIdx.x;
    if (e < NE) atomicAdd(&cnt[dst[e]], 1);
}

__global__ void k_scan1(const int* __restrict__ cnt, int* __restrict__ ptr,
                        int* __restrict__ bsum) {
    int tid = threadIdx.x;
    int i = blockIdx.x * 256 + tid;
    int v = (i < NN) ? cnt[i] : 0;
    int lane = tid & 63, wid = tid >> 6;
    int x = v;
#pragma unroll
    for (int off = 1; off < 64; off <<= 1) {
        int y = __shfl_up(x, off, 64);
        if (lane >= off) x += y;
    }
    __shared__ int wsum[4];
    if (lane == 63) wsum[wid] = x;
    __syncthreads();
    int add = 0;
#pragma unroll
    for (int w = 0; w < 4; w++)
        if (w < wid) add += wsum[w];
    int incl = x + add;
    if (i < NN) ptr[i] = incl - v;           // block-local exclusive scan
    if (tid == 255) bsum[blockIdx.x] = incl; // block total
}

__global__ void k_scan2(const int* __restrict__ bsum, int* __restrict__ boff, int nb) {
    int tid = threadIdx.x;
    int v = (tid < nb) ? bsum[tid] : 0;
    int lane = tid & 63, wid = tid >> 6;
    int x = v;
#pragma unroll
    for (int off = 1; off < 64; off <<= 1) {
        int y = __shfl_up(x, off, 64);
        if (lane >= off) x += y;
    }
    __shared__ int wsum[4];
    if (lane == 63) wsum[wid] = x;
    __syncthreads();
    int add = 0;
#pragma unroll
    for (int w = 0; w < 4; w++)
        if (w < wid) add += wsum[w];
    boff[tid] = x + add - v;                 // exclusive
}

__global__ void k_scan3(const int* __restrict__ cnt, const int* __restrict__ boff,
                        int* __restrict__ ptr, int* __restrict__ nxt,
                        float* __restrict__ invd) {
    int i = blockIdx.x * 256 + threadIdx.x;
    if (i < NN) {
        int p = ptr[i] + boff[blockIdx.x];
        ptr[i] = p;
        nxt[i] = p;
        int c = cnt[i];
        invd[i] = 1.0f / (float)(c > 1 ? c : 1);
    }
    if (i == 0) ptr[NN] = NE;
}

__global__ void k_scatter(const int* __restrict__ src, const int* __restrict__ dst,
                          int* __restrict__ nxt, int* __restrict__ csr) {
    int e = blockIdx.x * 256 + threadIdx.x;
    if (e < NE) {
        int d = dst[e];
        int p = atomicAdd(&nxt[d], 1);
        csr[p] = src[e];
    }
}

// ---------------- neighbor mean-aggregation (pull via CSR) ----------------
// one wave per node; half-wave per edge, float4 per lane (32 lanes cover 128 cols)
__global__ void k_gather(const float* __restrict__ x, const int* __restrict__ ptr,
                         const int* __restrict__ csr, const float* __restrict__ invd,
                         float* __restrict__ agg) {
    int wid = threadIdx.x >> 6;
    int lane = threadIdx.x & 63;
    int half = lane >> 5;
    int l32 = lane & 31;
    int n = blockIdx.x * 4 + wid;
    if (n >= NN) return;
    int beg = ptr[n], end = ptr[n + 1];
    float4 a0 = make_float4(0.f, 0.f, 0.f, 0.f);
    float4 a1 = make_float4(0.f, 0.f, 0.f, 0.f);
    int e = beg + half;
    for (; e + 2 < end; e += 4) {
        int s0 = csr[e];
        int s1 = csr[e + 2];
        float4 v0 = *(const float4*)(x + (size_t)s0 * DD + 4 * l32);
        float4 v1 = *(const float4*)(x + (size_t)s1 * DD + 4 * l32);
        a0.x += v0.x; a0.y += v0.y; a0.z += v0.z; a0.w += v0.w;
        a1.x += v1.x; a1.y += v1.y; a1.z += v1.z; a1.w += v1.w;
    }
    if (e < end) {
        int s0 = csr[e];
        float4 v0 = *(const float4*)(x + (size_t)s0 * DD + 4 * l32);
        a0.x += v0.x; a0.y += v0.y; a0.z += v0.z; a0.w += v0.w;
    }
    a0.x += a1.x; a0.y += a1.y; a0.z += a1.z; a0.w += a1.w;
    a0.x += __shfl_down(a0.x, 32, 64);
    a0.y += __shfl_down(a0.y, 32, 64);
    a0.z += __shfl_down(a0.z, 32, 64);
    a0.w += __shfl_down(a0.w, 32, 64);
    if (half == 0) {
        float id = invd[n];
        float4 o;
        o.x = a0.x * id; o.y = a0.y * id; o.z = a0.z * id; o.w = a0.w * id;
        *(float4*)(agg + (size_t)n * DD + 4 * l32) = o;
    }
}

// ---------------- fused SAGE layer GEMM ----------------
// C[r][j] = relu( s[j]*(sum_k A[r][k]*Wl[k][j] + sum_k X[r][k]*Wr[k][j] + bl[j] - mn[j]) + be[j] )
// C may alias A (row-local: each block reads only its own 64 rows before writing them).
__launch_bounds__(256)
__global__ void k_gemm(const float* __restrict__ A, const float* __restrict__ X,
                       const float* __restrict__ Wl, const float* __restrict__ Wr,
                       const float* __restrict__ bl, const float* __restrict__ g,
                       const float* __restrict__ be, const float* __restrict__ mn,
                       const float* __restrict__ vr, float* __restrict__ C) {
    __shared__ float As[32][68];   // [k][row], +4 pad
    __shared__ float Bs[32][128];  // [k][j]
    int tid = threadIdx.x;
    int r0 = blockIdx.x * 64;
    int trow = (tid >> 4) * 4;   // 0..60
    int tcol = (tid & 15) * 4;   // cols tcol..tcol+3 and tcol+64..tcol+67 (conflict-free)

    float acc[4][8];
#pragma unroll
    for (int i = 0; i < 4; i++)
#pragma unroll
        for (int j = 0; j < 8; j++) acc[i][j] = 0.f;

    int la_r = tid >> 3;         // 0..31 (A loader)
    int la_k = (tid & 7) * 4;
    int lb_k = tid >> 5;         // 0..7  (B loader)
    int lb_j = (tid & 31) * 4;

#pragma unroll
    for (int phase = 0; phase < 2; phase++) {
        const float* S = phase ? X : A;
        const float* W = phase ? Wr : Wl;
        for (int kc = 0; kc < 128; kc += 32) {
            __syncthreads();
#pragma unroll
            for (int p = 0; p < 2; p++) {
                int row = p * 32 + la_r;
                int grow = r0 + row;
                float4 v = make_float4(0.f, 0.f, 0.f, 0.f);
                if (grow < NN) v = *(const float4*)(S + (size_t)grow * DD + kc + la_k);
                As[la_k + 0][row] = v.x;
                As[la_k + 1][row] = v.y;
                As[la_k + 2][row] = v.z;
                As[la_k + 3][row] = v.w;
            }
#pragma unroll
            for (int p = 0; p < 4; p++) {
                int k = p * 8 + lb_k;
                *(float4*)&Bs[k][lb_j] = *(const float4*)(W + (size_t)(kc + k) * DD + lb_j);
            }
            __syncthreads();
#pragma unroll
            for (int kk = 0; kk < 32; kk++) {
                float4 a4 = *(const float4*)&As[kk][trow];
                float4 b0 = *(const float4*)&Bs[kk][tcol];
                float4 b1 = *(const float4*)&Bs[kk][tcol + 64];
                float av[4] = {a4.x, a4.y, a4.z, a4.w};
                float bv[8] = {b0.x, b0.y, b0.z, b0.w, b1.x, b1.y, b1.z, b1.w};
#pragma unroll
                for (int i = 0; i < 4; i++)
#pragma unroll
                    for (int j = 0; j < 8; j++) acc[i][j] += av[i] * bv[j];
            }
        }
    }

    // epilogue: bias + BN(eval) + relu
    float sc[8], sh[8];
#pragma unroll
    for (int j = 0; j < 8; j++) {
        int jj = tcol + (j < 4 ? j : 60 + j);   // j>=4 -> tcol+64+(j-4)
        float s = g[jj] * rsqrtf(vr[jj] + EPSV);
        sc[j] = s;
        sh[j] = (bl[jj] - mn[jj]) * s + be[jj];
    }
#pragma unroll
    for (int i = 0; i < 4; i++) {
        int grow = r0 + trow + i;
        if (grow < NN) {
            float4 o0, o1;
            o0.x = fmaxf(acc[i][0] * sc[0] + sh[0], 0.f);
            o0.y = fmaxf(acc[i][1] * sc[1] + sh[1], 0.f);
            o0.z = fmaxf(acc[i][2] * sc[2] + sh[2], 0.f);
            o0.w = fmaxf(acc[i][3] * sc[3] + sh[3], 0.f);
            o1.x = fmaxf(acc[i][4] * sc[4] + sh[4], 0.f);
            o1.y = fmaxf(acc[i][5] * sc[5] + sh[5], 0.f);
            o1.z = fmaxf(acc[i][6] * sc[6] + sh[6], 0.f);
            o1.w = fmaxf(acc[i][7] * sc[7] + sh[7], 0.f);
            *(float4*)(C + (size_t)grow * DD + tcol) = o0;
            *(float4*)(C + (size_t)grow * DD + tcol + 64) = o1;
        }
    }
}

// ---------------- global add pool (atomic-free: batch is sorted) ----------------
__launch_bounds__(128)
__global__ void k_pool2(const float* __restrict__ h, const int* __restrict__ batch,
                        float* __restrict__ p) {
    int b = blockIdx.x;
    __shared__ int sr[2];
    if (threadIdx.x < 2) {
        int target = b + (int)threadIdx.x;   // lower_bound(target) in sorted batch[]
        int lo = 0, hi = NN;
        while (lo < hi) {
            int mid = (lo + hi) >> 1;
            if (batch[mid] < target) lo = mid + 1; else hi = mid;
        }
        sr[threadIdx.x] = lo;
    }
    __syncthreads();
    int beg = sr[0], end = sr[1];
    int t = threadIdx.x;
    float acc = 0.f;
    for (int r = beg; r < end; r++) acc += h[(size_t)r * DD + t];
    p[(size_t)b * DD + t] = acc;
}

// ---------------- final MLP head ----------------
__launch_bounds__(128)
__global__ void k_mlp(const float* __restrict__ p1, const float* __restrict__ p2,
                      const int* __restrict__ rel, const float* __restrict__ kge,
                      const float* __restrict__ W1, const float* __restrict__ b1,
                      const float* __restrict__ W2, const float* __restrict__ b2,
                      float* __restrict__ out) {
    int b = blockIdx.x;
    int tid = threadIdx.x;
    __shared__ float z[384];
    z[tid] = p1[(size_t)b * DD + tid];
    z[tid + 128] = p2[(size_t)b * DD + tid];
    int r = rel[b];
    z[tid + 256] = kge[(size_t)r * DD + tid];
    __syncthreads();
    float acc = b1[tid];
#pragma unroll 8
    for (int k = 0; k < 384; k++) acc += z[k] * W1[k * DD + tid];
    float h = fmaxf(acc, 0.f);
    float v = h * W2[tid];
#pragma unroll
    for (int off = 32; off > 0; off >>= 1) v += __shfl_down(v, off, 64);
    __shared__ float wsf[2];
    if ((tid & 63) == 0) wsf[tid >> 6] = v;
    __syncthreads();
    if (tid == 0) out[b] = wsf[0] + wsf[1] + b2[0];
}

extern "C" void kernel_launch(void* const* d_in, const int* in_sizes, int n_in,
                              void* d_out, int out_size, void* d_ws, size_t ws_size,
                              hipStream_t stream) {
    const float* x1  = (const float*)d_in[0];
    const float* x2  = (const float*)d_in[1];
    const int*   ei1 = (const int*)d_in[2];
    const int*   ei2 = (const int*)d_in[3];
    const int*   bt1 = (const int*)d_in[4];
    const int*   bt2 = (const int*)d_in[5];
    const int*   rel = (const int*)d_in[6];
    const float* Wl  = (const float*)d_in[7];
    const float* bl  = (const float*)d_in[8];
    const float* Wr  = (const float*)d_in[9];
    const float* g   = (const float*)d_in[10];
    const float* be  = (const float*)d_in[11];
    const float* mn  = (const float*)d_in[12];
    const float* vr  = (const float*)d_in[13];
    const float* kge = (const float*)d_in[14];
    const float* W1  = (const float*)d_in[15];
    const float* b1v = (const float*)d_in[16];
    const float* W2  = (const float*)d_in[17];
    const float* b2v = (const float*)d_in[18];

    char* ws = (char*)d_ws;
    size_t off = 0;
    auto alloc = [&](size_t bytes) {
        void* p = ws + off;
        off += (bytes + 255) & ~(size_t)255;
        return p;
    };
    float* bufA  = (float*)alloc((size_t)NN * DD * 4);
    float* bufB  = (float*)alloc((size_t)NN * DD * 4);
    float* p1    = (float*)alloc((size_t)NB * DD * 4);
    float* p2    = (float*)alloc((size_t)NB * DD * 4);
    int*   cnt   = (int*)alloc((size_t)NN * 4);
    int*   ptr   = (int*)alloc((size_t)(NN + 1) * 4);
    int*   nxt   = (int*)alloc((size_t)NN * 4);
    float* invd  = (float*)alloc((size_t)NN * 4);
    int*   csr   = (int*)alloc((size_t)NE * 4);
    int*   bsum  = (int*)alloc(256 * 4);
    int*   boff  = (int*)alloc(256 * 4);
    if (off > ws_size) return;

    const int nbScan = (NN + 255) / 256;     // 196
    const int nbEdge = (NE + 255) / 256;     // 2344
    const int nbNode4 = (NN + 3) / 4;        // 12500
    const int nbGemm = (NN + 63) / 64;       // 782

    for (int side = 0; side < 2; side++) {
        const float* x   = side ? x2 : x1;
        const int*   src = side ? ei2 : ei1;
        const int*   dst = src + NE;
        const int*   bat = side ? bt2 : bt1;
        float*       pp  = side ? p2 : p1;

        hipMemsetAsync(cnt, 0, (size_t)NN * 4, stream);
        k_deg<<<nbEdge, 256, 0, stream>>>(dst, cnt);
        k_scan1<<<nbScan, 256, 0, stream>>>(cnt, ptr, bsum);
        k_scan2<<<1, 256, 0, stream>>>(bsum, boff, nbScan);
        k_scan3<<<nbScan, 256, 0, stream>>>(cnt, boff, ptr, nxt, invd);
        k_scatter<<<nbEdge, 256, 0, stream>>>(src, dst, nxt, csr);

        // layer 0
        k_gather<<<nbNode4, 256, 0, stream>>>(x, ptr, csr, invd, bufB);
        k_gemm<<<nbGemm, 256, 0, stream>>>(bufB, x, Wl, Wr, bl, g, be, mn, vr, bufB);
        // layer 1
        k_gather<<<nbNode4, 256, 0, stream>>>(bufB, ptr, csr, invd, bufA);
        k_gemm<<<nbGemm, 256, 0, stream>>>(bufA, bufB, Wl + 16384, Wr + 16384, bl + 128,
                                           g + 128, be + 128, mn + 128, vr + 128, bufA);
        // layer 2
        k_gather<<<nbNode4, 256, 0, stream>>>(bufA, ptr, csr, invd, bufB);
        k_gemm<<<nbGemm, 256, 0, stream>>>(bufB, bufA, Wl + 32768, Wr + 32768, bl + 256,
                                           g + 256, be + 256, mn + 256, vr + 256, bufB);

        // atomic-free global add pool (batch sorted -> contiguous ranges)
        k_pool2<<<NB, 128, 0, stream>>>(bufB, bat, pp);
    }

    k_mlp<<<NB, 128, 0, stream>>>(p1, p2, rel, kge, W1, b1v, W2, b2v, (float*)d_out);
}

// Round 4
// 817.506 us; speedup vs baseline: 1.3656x; 1.1066x over previous
//
#include <hip/hip_runtime.h>

#define NN 50000
#define NE 600000
#define NB 4096
#define DD 128
#define EPSV 1e-5f

typedef __bf16 bf16x8 __attribute__((ext_vector_type(8)));
typedef float f32x4 __attribute__((ext_vector_type(4)));

__device__ inline unsigned short f2bf(float f) {
    unsigned u = __float_as_uint(f);
    u = (u + 0x7FFFu + ((u >> 16) & 1u)) >> 16;
    return (unsigned short)u;
}
__device__ inline float bf2f(unsigned short h) {
    return __uint_as_float(((unsigned)h) << 16);
}
// packed: hi bf16 in high 16 bits, lo bf16 in low 16 bits; value = hi + lo (~fp32)
__device__ inline unsigned packbf(float f) {
    unsigned short h = f2bf(f);
    unsigned short l = f2bf(f - bf2f(h));
    return ((unsigned)h << 16) | (unsigned)l;
}
__device__ inline float unpackbf(unsigned p) {
    return __uint_as_float(p & 0xFFFF0000u) + __uint_as_float(p << 16);
}

// ---------------- input conversions ----------------
__global__ void k_cvt(const float* __restrict__ x, unsigned* __restrict__ xp, int n4) {
    int i = blockIdx.x * 256 + threadIdx.x;
    if (i >= n4) return;
    float4 v = ((const float4*)x)[i];
    uint4 o;
    o.x = packbf(v.x); o.y = packbf(v.y); o.z = packbf(v.z); o.w = packbf(v.w);
    ((uint4*)xp)[i] = o;
}

// weights: build Wt[layer][n][k], k in [0,256): k<128 -> Wl[k][n], k>=128 -> Wr[k-128][n]
__global__ void k_wcvt(const float* __restrict__ Wl, const float* __restrict__ Wr,
                       unsigned* __restrict__ wtp) {
    int t = blockIdx.x * 256 + threadIdx.x;
    if (t >= 3 * 128 * 256) return;
    int k = t & 255;
    int n = (t >> 8) & 127;
    int l = t >> 15;
    float w = (k < 128) ? Wl[l * 16384 + k * 128 + n] : Wr[l * 16384 + (k - 128) * 128 + n];
    wtp[t] = packbf(w);
}

// ---------------- CSR build ----------------
__global__ void k_deg(const int* __restrict__ dst, int* __restrict__ cnt) {
    int e = blockIdx.x * 256 + threadIdx.x;
    if (e < NE) atomicAdd(&cnt[dst[e]], 1);
}

__global__ void k_scan1(const int* __restrict__ cnt, int* __restrict__ ptr,
                        int* __restrict__ bsum) {
    int tid = threadIdx.x;
    int i = blockIdx.x * 256 + tid;
    int v = (i < NN) ? cnt[i] : 0;
    int lane = tid & 63, wid = tid >> 6;
    int x = v;
#pragma unroll
    for (int off = 1; off < 64; off <<= 1) {
        int y = __shfl_up(x, off, 64);
        if (lane >= off) x += y;
    }
    __shared__ int wsum[4];
    if (lane == 63) wsum[wid] = x;
    __syncthreads();
    int add = 0;
#pragma unroll
    for (int w = 0; w < 4; w++)
        if (w < wid) add += wsum[w];
    int incl = x + add;
    if (i < NN) ptr[i] = incl - v;
    if (tid == 255) bsum[blockIdx.x] = incl;
}

__global__ void k_scan2(const int* __restrict__ bsum, int* __restrict__ boff, int nb) {
    int tid = threadIdx.x;
    int v = (tid < nb) ? bsum[tid] : 0;
    int lane = tid & 63, wid = tid >> 6;
    int x = v;
#pragma unroll
    for (int off = 1; off < 64; off <<= 1) {
        int y = __shfl_up(x, off, 64);
        if (lane >= off) x += y;
    }
    __shared__ int wsum[4];
    if (lane == 63) wsum[wid] = x;
    __syncthreads();
    int add = 0;
#pragma unroll
    for (int w = 0; w < 4; w++)
        if (w < wid) add += wsum[w];
    boff[tid] = x + add - v;
}

__global__ void k_scan3(const int* __restrict__ cnt, const int* __restrict__ boff,
                        int* __restrict__ ptr, int* __restrict__ nxt,
                        float* __restrict__ invd) {
    int i = blockIdx.x * 256 + threadIdx.x;
    if (i < NN) {
        int p = ptr[i] + boff[blockIdx.x];
        ptr[i] = p;
        nxt[i] = p;
        int c = cnt[i];
        invd[i] = 1.0f / (float)(c > 1 ? c : 1);
    }
    if (i == 0) ptr[NN] = NE;
}

__global__ void k_scatter(const int* __restrict__ src, const int* __restrict__ dst,
                          int* __restrict__ nxt, int* __restrict__ csr) {
    int e = blockIdx.x * 256 + threadIdx.x;
    if (e < NE) {
        int d = dst[e];
        int p = atomicAdd(&nxt[d], 1);
        csr[p] = src[e];
    }
}

// ---------------- neighbor mean-aggregation (packed bf16 hi/lo) ----------------
// one wave per node; lane covers 2 features; 4 edges in flight
__global__ void k_gather(const unsigned* __restrict__ xp, const int* __restrict__ ptr,
                         const int* __restrict__ csr, const float* __restrict__ invd,
                         unsigned* __restrict__ ap) {
    int wid = threadIdx.x >> 6;
    int lane = threadIdx.x & 63;
    int n = blockIdx.x * 4 + wid;
    if (n >= NN) return;
    int beg = ptr[n], end = ptr[n + 1];
    float s0 = 0.f, s1 = 0.f, t0 = 0.f, t1 = 0.f;
    float u0 = 0.f, u1 = 0.f, v0 = 0.f, v1 = 0.f;
    int e = beg;
    for (; e + 3 < end; e += 4) {
        int i0 = csr[e], i1 = csr[e + 1], i2 = csr[e + 2], i3 = csr[e + 3];
        uint2 a = *(const uint2*)(xp + (size_t)i0 * DD + lane * 2);
        uint2 b = *(const uint2*)(xp + (size_t)i1 * DD + lane * 2);
        uint2 c = *(const uint2*)(xp + (size_t)i2 * DD + lane * 2);
        uint2 d = *(const uint2*)(xp + (size_t)i3 * DD + lane * 2);
        s0 += unpackbf(a.x); s1 += unpackbf(a.y);
        t0 += unpackbf(b.x); t1 += unpackbf(b.y);
        u0 += unpackbf(c.x); u1 += unpackbf(c.y);
        v0 += unpackbf(d.x); v1 += unpackbf(d.y);
    }
    for (; e < end; e++) {
        int i0 = csr[e];
        uint2 a = *(const uint2*)(xp + (size_t)i0 * DD + lane * 2);
        s0 += unpackbf(a.x); s1 += unpackbf(a.y);
    }
    float f0 = (s0 + t0) + (u0 + v0);
    float f1 = (s1 + t1) + (u1 + v1);
    float id = invd[n];
    f0 *= id; f1 *= id;
    uint2 o;
    o.x = packbf(f0); o.y = packbf(f1);
    *(uint2*)(ap + (size_t)n * DD + lane * 2) = o;
}

// ---------------- fused SAGE layer GEMM: split-bf16 MFMA ----------------
// h = relu(BN(agg@Wl + x@Wr + bl)) via [agg | x] @ Wt (K=256), each operand = hi+lo bf16;
// products hi*hi + hi*lo + lo*hi accumulated fp32 (lo*lo dropped, ~2^-16 rel).
// BM=128, BN=64, BK=32; 128 threads = 2 waves; wave tile 64x64 (4x4 of 16x16).
__launch_bounds__(128)
__global__ void k_gemm(const unsigned* __restrict__ Ap, const unsigned* __restrict__ Xp,
                       const unsigned* __restrict__ Wtp,
                       const float* __restrict__ bl, const float* __restrict__ g,
                       const float* __restrict__ be, const float* __restrict__ mn,
                       const float* __restrict__ vr,
                       unsigned* __restrict__ Op, float* __restrict__ Of, int f32out) {
    __shared__ __align__(16) unsigned short sA[2][128 * 40];  // [hi/lo][row][k], k-stride 40
    __shared__ __align__(16) unsigned short sW[2][64 * 40];   // [hi/lo][n][k]
    int tid = threadIdx.x;
    int gx = blockIdx.x;
    int m0 = (gx >> 1) * 128;
    int n0 = (gx & 1) * 64;
    int lane = tid & 63;
    int w = tid >> 6;
    int fm = lane & 15, q = lane >> 4;
    int wm0 = w * 64;

    f32x4 acc[4][4];
#pragma unroll
    for (int i = 0; i < 4; i++)
#pragma unroll
        for (int j = 0; j < 4; j++) acc[i][j] = (f32x4){0.f, 0.f, 0.f, 0.f};

    for (int c = 0; c < 8; c++) {
        const unsigned* pA = (c < 4) ? Ap : Xp;
        int k0A = (c & 3) * 32;
        int k0W = c * 32;
        __syncthreads();
        // stage: A 128 rows x 8 segs + W 64 rows x 8 segs, each seg = 4 packed uints
#pragma unroll
        for (int i = 0; i < 12; i++) {
            int u = tid + 128 * i;           // 0..1535
            uint4 val = make_uint4(0, 0, 0, 0);
            if (u < 1024) {
                int row = u >> 3, seg = u & 7;
                int grow = m0 + row;
                if (grow < NN)
                    val = *(const uint4*)(pA + (size_t)grow * DD + k0A + seg * 4);
                ushort4 hi, lo;
                hi.x = val.x >> 16; hi.y = val.y >> 16; hi.z = val.z >> 16; hi.w = val.w >> 16;
                lo.x = val.x & 0xFFFF; lo.y = val.y & 0xFFFF; lo.z = val.z & 0xFFFF; lo.w = val.w & 0xFFFF;
                *(ushort4*)&sA[0][row * 40 + seg * 4] = hi;
                *(ushort4*)&sA[1][row * 40 + seg * 4] = lo;
            } else {
                int v = u - 1024;
                int row = v >> 3, seg = v & 7;
                val = *(const uint4*)(Wtp + (size_t)(n0 + row) * 256 + k0W + seg * 4);
                ushort4 hi, lo;
                hi.x = val.x >> 16; hi.y = val.y >> 16; hi.z = val.z >> 16; hi.w = val.w >> 16;
                lo.x = val.x & 0xFFFF; lo.y = val.y & 0xFFFF; lo.z = val.z & 0xFFFF; lo.w = val.w & 0xFFFF;
                *(ushort4*)&sW[0][row * 40 + seg * 4] = hi;
                *(ushort4*)&sW[1][row * 40 + seg * 4] = lo;
            }
        }
        __syncthreads();
        // A fragments: A[m=lane&15][k=q*8+j]
        bf16x8 af[4][2];
#pragma unroll
        for (int mt = 0; mt < 4; mt++) {
            int r = wm0 + mt * 16 + fm;
            af[mt][0] = *(const bf16x8*)&sA[0][r * 40 + q * 8];
            af[mt][1] = *(const bf16x8*)&sA[1][r * 40 + q * 8];
        }
#pragma unroll
        for (int nt = 0; nt < 4; nt++) {
            int nr = nt * 16 + fm;
            bf16x8 wh = *(const bf16x8*)&sW[0][nr * 40 + q * 8];
            bf16x8 wl = *(const bf16x8*)&sW[1][nr * 40 + q * 8];
#pragma unroll
            for (int mt = 0; mt < 4; mt++) {
                acc[mt][nt] = __builtin_amdgcn_mfma_f32_16x16x32_bf16(af[mt][0], wh, acc[mt][nt], 0, 0, 0);
                acc[mt][nt] = __builtin_amdgcn_mfma_f32_16x16x32_bf16(af[mt][0], wl, acc[mt][nt], 0, 0, 0);
                acc[mt][nt] = __builtin_amdgcn_mfma_f32_16x16x32_bf16(af[mt][1], wh, acc[mt][nt], 0, 0, 0);
            }
        }
    }

    // epilogue: BN(eval) + relu; C layout col=lane&15, row=q*4+reg
    float scv[4], shv[4];
#pragma unroll
    for (int nt = 0; nt < 4; nt++) {
        int jj = n0 + nt * 16 + fm;
        float s = g[jj] * rsqrtf(vr[jj] + EPSV);
        scv[nt] = s;
        shv[nt] = (bl[jj] - mn[jj]) * s + be[jj];
    }
#pragma unroll
    for (int mt = 0; mt < 4; mt++) {
#pragma unroll
        for (int r = 0; r < 4; r++) {
            int grow = m0 + wm0 + mt * 16 + q * 4 + r;
            if (grow < NN) {
#pragma unroll
                for (int nt = 0; nt < 4; nt++) {
                    int gcol = n0 + nt * 16 + fm;
                    float o = fmaxf(acc[mt][nt][r] * scv[nt] + shv[nt], 0.f);
                    if (f32out) Of[(size_t)grow * DD + gcol] = o;
                    else Op[(size_t)grow * DD + gcol] = packbf(o);
                }
            }
        }
    }
}

// ---------------- global add pool (atomic-free: batch is sorted) ----------------
__launch_bounds__(128)
__global__ void k_pool2(const float* __restrict__ h, const int* __restrict__ batch,
                        float* __restrict__ p) {
    int b = blockIdx.x;
    __shared__ int sr[2];
    if (threadIdx.x < 2) {
        int target = b + (int)threadIdx.x;
        int lo = 0, hi = NN;
        while (lo < hi) {
            int mid = (lo + hi) >> 1;
            if (batch[mid] < target) lo = mid + 1; else hi = mid;
        }
        sr[threadIdx.x] = lo;
    }
    __syncthreads();
    int beg = sr[0], end = sr[1];
    int t = threadIdx.x;
    float acc = 0.f;
    for (int r = beg; r < end; r++) acc += h[(size_t)r * DD + t];
    p[(size_t)b * DD + t] = acc;
}

// ---------------- final MLP head ----------------
__launch_bounds__(128)
__global__ void k_mlp(const float* __restrict__ p1, const float* __restrict__ p2,
                      const int* __restrict__ rel, const float* __restrict__ kge,
                      const float* __restrict__ W1, const float* __restrict__ b1,
                      const float* __restrict__ W2, const float* __restrict__ b2,
                      float* __restrict__ out) {
    int b = blockIdx.x;
    int tid = threadIdx.x;
    __shared__ float z[384];
    z[tid] = p1[(size_t)b * DD + tid];
    z[tid + 128] = p2[(size_t)b * DD + tid];
    int r = rel[b];
    z[tid + 256] = kge[(size_t)r * DD + tid];
    __syncthreads();
    float acc = b1[tid];
#pragma unroll 8
    for (int k = 0; k < 384; k++) acc += z[k] * W1[k * DD + tid];
    float h = fmaxf(acc, 0.f);
    float v = h * W2[tid];
#pragma unroll
    for (int off = 32; off > 0; off >>= 1) v += __shfl_down(v, off, 64);
    __shared__ float wsf[2];
    if ((tid & 63) == 0) wsf[tid >> 6] = v;
    __syncthreads();
    if (tid == 0) out[b] = wsf[0] + wsf[1] + b2[0];
}

extern "C" void kernel_launch(void* const* d_in, const int* in_sizes, int n_in,
                              void* d_out, int out_size, void* d_ws, size_t ws_size,
                              hipStream_t stream) {
    const float* x1  = (const float*)d_in[0];
    const float* x2  = (const float*)d_in[1];
    const int*   ei1 = (const int*)d_in[2];
    const int*   ei2 = (const int*)d_in[3];
    const int*   bt1 = (const int*)d_in[4];
    const int*   bt2 = (const int*)d_in[5];
    const int*   rel = (const int*)d_in[6];
    const float* Wl  = (const float*)d_in[7];
    const float* bl  = (const float*)d_in[8];
    const float* Wr  = (const float*)d_in[9];
    const float* g   = (const float*)d_in[10];
    const float* be  = (const float*)d_in[11];
    const float* mn  = (const float*)d_in[12];
    const float* vr  = (const float*)d_in[13];
    const float* kge = (const float*)d_in[14];
    const float* W1  = (const float*)d_in[15];
    const float* b1v = (const float*)d_in[16];
    const float* W2  = (const float*)d_in[17];
    const float* b2v = (const float*)d_in[18];

    char* ws = (char*)d_ws;
    size_t off = 0;
    auto alloc = [&](size_t bytes) {
        void* p = ws + off;
        off += (bytes + 255) & ~(size_t)255;
        return p;
    };
    unsigned* ap  = (unsigned*)alloc((size_t)NN * DD * 4);
    unsigned* op  = (unsigned*)alloc((size_t)NN * DD * 4);   // also aliased as fp32 out
    unsigned* xp  = (unsigned*)alloc((size_t)NN * DD * 4);
    unsigned* wtp = (unsigned*)alloc((size_t)3 * 128 * 256 * 4);
    float* p1    = (float*)alloc((size_t)NB * DD * 4);
    float* p2    = (float*)alloc((size_t)NB * DD * 4);
    int*   cnt   = (int*)alloc((size_t)NN * 4);
    int*   ptr   = (int*)alloc((size_t)(NN + 1) * 4);
    int*   nxt   = (int*)alloc((size_t)NN * 4);
    float* invd  = (float*)alloc((size_t)NN * 4);
    int*   csr   = (int*)alloc((size_t)NE * 4);
    int*   bsum  = (int*)alloc(256 * 4);
    int*   boff  = (int*)alloc(256 * 4);
    if (off > ws_size) return;

    float* cf = (float*)op;   // layer-2 fp32 output aliases op (op dead by then)

    const int nbScan = (NN + 255) / 256;
    const int nbEdge = (NE + 255) / 256;
    const int nbNode4 = (NN + 3) / 4;
    const int nbGemm = ((NN + 127) / 128) * 2;   // 391 * 2 = 782
    const int nbCvt = (NN * DD / 4 + 255) / 256;

    k_wcvt<<<(3 * 128 * 256 + 255) / 256, 256, 0, stream>>>(Wl, Wr, wtp);

    for (int side = 0; side < 2; side++) {
        const float* x   = side ? x2 : x1;
        const int*   src = side ? ei2 : ei1;
        const int*   dst = src + NE;
        const int*   bat = side ? bt2 : bt1;
        float*       pp  = side ? p2 : p1;

        k_cvt<<<nbCvt, 256, 0, stream>>>(x, xp, NN * DD / 4);

        hipMemsetAsync(cnt, 0, (size_t)NN * 4, stream);
        k_deg<<<nbEdge, 256, 0, stream>>>(dst, cnt);
        k_scan1<<<nbScan, 256, 0, stream>>>(cnt, ptr, bsum);
        k_scan2<<<1, 256, 0, stream>>>(bsum, boff, nbScan);
        k_scan3<<<nbScan, 256, 0, stream>>>(cnt, boff, ptr, nxt, invd);
        k_scatter<<<nbEdge, 256, 0, stream>>>(src, dst, nxt, csr);

        // layer 0: gather(xp)->ap ; gemm(ap, xp, W0) -> op
        k_gather<<<nbNode4, 256, 0, stream>>>(xp, ptr, csr, invd, ap);
        k_gemm<<<nbGemm, 128, 0, stream>>>(ap, xp, wtp, bl, g, be, mn, vr,
                                           op, (float*)nullptr, 0);
        // layer 1: gather(op)->ap ; gemm(ap, op, W1) -> xp
        k_gather<<<nbNode4, 256, 0, stream>>>(op, ptr, csr, invd, ap);
        k_gemm<<<nbGemm, 128, 0, stream>>>(ap, op, wtp + 32768, bl + 128, g + 128,
                                           be + 128, mn + 128, vr + 128,
                                           xp, (float*)nullptr, 0);
        // layer 2: gather(xp)->ap ; gemm(ap, xp, W2) -> cf (fp32)
        k_gather<<<nbNode4, 256, 0, stream>>>(xp, ptr, csr, invd, ap);
        k_gemm<<<nbGemm, 128, 0, stream>>>(ap, xp, wtp + 65536, bl + 256, g + 256,
                                           be + 256, mn + 256, vr + 256,
                                           (unsigned*)nullptr, cf, 1);

        k_pool2<<<NB, 128, 0, stream>>>(cf, bat, pp);
    }

    k_mlp<<<NB, 128, 0, stream>>>(p1, p2, rel, kge, W1, b1v, W2, b2v, (float*)d_out);
}

// Round 5
// 802.661 us; speedup vs baseline: 1.3908x; 1.0185x over previous
//
#include <hip/hip_runtime.h>

#define NN 50000
#define NE 600000
#define NB 4096
#define DD 128
#define EPSV 1e-5f

typedef __bf16 bf16x8 __attribute__((ext_vector_type(8)));
typedef float f32x4 __attribute__((ext_vector_type(4)));

__device__ inline unsigned short f2bf(float f) {
    unsigned u = __float_as_uint(f);
    u = (u + 0x7FFFu + ((u >> 16) & 1u)) >> 16;
    return (unsigned short)u;
}
__device__ inline float bf2f(unsigned short h) {
    return __uint_as_float(((unsigned)h) << 16);
}
// packed: hi bf16 in high 16 bits, lo bf16 in low 16 bits; value = hi + lo (~fp32)
__device__ inline unsigned packbf(float f) {
    unsigned short h = f2bf(f);
    unsigned short l = f2bf(f - bf2f(h));
    return ((unsigned)h << 16) | (unsigned)l;
}
__device__ inline float unpackbf(unsigned p) {
    return __uint_as_float(p & 0xFFFF0000u) + __uint_as_float(p << 16);
}

// ---------------- input conversions ----------------
__global__ void k_cvt(const float* __restrict__ x, unsigned* __restrict__ xp, int n4) {
    int i = blockIdx.x * 256 + threadIdx.x;
    if (i >= n4) return;
    float4 v = ((const float4*)x)[i];
    uint4 o;
    o.x = packbf(v.x); o.y = packbf(v.y); o.z = packbf(v.z); o.w = packbf(v.w);
    ((uint4*)xp)[i] = o;
}

// weights: build Wt[layer][n][k], k in [0,256): k<128 -> Wl[k][n], k>=128 -> Wr[k-128][n]
__global__ void k_wcvt(const float* __restrict__ Wl, const float* __restrict__ Wr,
                       unsigned* __restrict__ wtp) {
    int t = blockIdx.x * 256 + threadIdx.x;
    if (t >= 3 * 128 * 256) return;
    int k = t & 255;
    int n = (t >> 8) & 127;
    int l = t >> 15;
    float w = (k < 128) ? Wl[l * 16384 + k * 128 + n] : Wr[l * 16384 + (k - 128) * 128 + n];
    wtp[t] = packbf(w);
}

// ---------------- CSR build (both sides in one dispatch) ----------------
__global__ void k_deg2(const int* __restrict__ d0, const int* __restrict__ d1,
                       int* __restrict__ c0, int* __restrict__ c1) {
    int e = blockIdx.x * 256 + threadIdx.x;
    if (e < NE) atomicAdd(&c0[d0[e]], 1);
    else if (e < 2 * NE) atomicAdd(&c1[d1[e - NE]], 1);
}

__global__ void k_scan1m(const int* __restrict__ cnt0, const int* __restrict__ cnt1,
                         int* __restrict__ ptr0, int* __restrict__ ptr1,
                         int* __restrict__ bsum0, int* __restrict__ bsum1, int nbScan) {
    int side = (blockIdx.x >= nbScan) ? 1 : 0;
    int lb = blockIdx.x - side * nbScan;
    const int* cnt = side ? cnt1 : cnt0;
    int* ptr = side ? ptr1 : ptr0;
    int* bsum = side ? bsum1 : bsum0;
    int tid = threadIdx.x;
    int i = lb * 256 + tid;
    int v = (i < NN) ? cnt[i] : 0;
    int lane = tid & 63, wid = tid >> 6;
    int x = v;
#pragma unroll
    for (int off = 1; off < 64; off <<= 1) {
        int y = __shfl_up(x, off, 64);
        if (lane >= off) x += y;
    }
    __shared__ int wsum[4];
    if (lane == 63) wsum[wid] = x;
    __syncthreads();
    int add = 0;
#pragma unroll
    for (int w = 0; w < 4; w++)
        if (w < wid) add += wsum[w];
    int incl = x + add;
    if (i < NN) ptr[i] = incl - v;
    if (tid == 255) bsum[lb] = incl;
}

__global__ void k_scan2m(const int* __restrict__ bsum0, const int* __restrict__ bsum1,
                         int* __restrict__ boff0, int* __restrict__ boff1, int nb) {
    int side = blockIdx.x;
    const int* bsum = side ? bsum1 : bsum0;
    int* boff = side ? boff1 : boff0;
    int tid = threadIdx.x;
    int v = (tid < nb) ? bsum[tid] : 0;
    int lane = tid & 63, wid = tid >> 6;
    int x = v;
#pragma unroll
    for (int off = 1; off < 64; off <<= 1) {
        int y = __shfl_up(x, off, 64);
        if (lane >= off) x += y;
    }
    __shared__ int wsum[4];
    if (lane == 63) wsum[wid] = x;
    __syncthreads();
    int add = 0;
#pragma unroll
    for (int w = 0; w < 4; w++)
        if (w < wid) add += wsum[w];
    boff[tid] = x + add - v;
}

__global__ void k_scan3m(const int* __restrict__ cnt0, const int* __restrict__ cnt1,
                         const int* __restrict__ boff0, const int* __restrict__ boff1,
                         int* __restrict__ ptr0, int* __restrict__ ptr1,
                         int* __restrict__ nxt0, int* __restrict__ nxt1,
                         float* __restrict__ invd0, float* __restrict__ invd1, int nbScan) {
    int side = (blockIdx.x >= nbScan) ? 1 : 0;
    int lb = blockIdx.x - side * nbScan;
    const int* cnt = side ? cnt1 : cnt0;
    const int* boff = side ? boff1 : boff0;
    int* ptr = side ? ptr1 : ptr0;
    int* nxt = side ? nxt1 : nxt0;
    float* invd = side ? invd1 : invd0;
    int i = lb * 256 + threadIdx.x;
    if (i < NN) {
        int p = ptr[i] + boff[lb];
        ptr[i] = p;
        nxt[i] = p;
        int c = cnt[i];
        invd[i] = 1.0f / (float)(c > 1 ? c : 1);
    }
    if (i == 0) ptr[NN] = NE;
}

__global__ void k_scatter2(const int* __restrict__ s0, const int* __restrict__ d0,
                           const int* __restrict__ s1, const int* __restrict__ d1,
                           int* __restrict__ nxt0, int* __restrict__ nxt1,
                           int* __restrict__ csr0, int* __restrict__ csr1) {
    int e = blockIdx.x * 256 + threadIdx.x;
    if (e < NE) {
        int d = d0[e];
        int p = atomicAdd(&nxt0[d], 1);
        csr0[p] = s0[e];
    } else if (e < 2 * NE) {
        int ee = e - NE;
        int d = d1[ee];
        int p = atomicAdd(&nxt1[d], 1);
        csr1[p] = s1[ee];
    }
}

// ---------------- neighbor mean-aggregation (packed bf16 hi/lo) ----------------
// one wave per node; half-wave per edge, uint4 (16B) per lane, 8 edges in flight/wave
__global__ void k_gather(const unsigned* __restrict__ xp, const int* __restrict__ ptr,
                         const int* __restrict__ csr, const float* __restrict__ invd,
                         unsigned* __restrict__ ap) {
    int wid = threadIdx.x >> 6;
    int lane = threadIdx.x & 63;
    int half = lane >> 5;
    int l32 = lane & 31;
    int n = blockIdx.x * 4 + wid;
    if (n >= NN) return;
    int beg = ptr[n], end = ptr[n + 1];
    f32x4 a0 = {0.f, 0.f, 0.f, 0.f}, a1 = {0.f, 0.f, 0.f, 0.f};
    f32x4 a2 = {0.f, 0.f, 0.f, 0.f}, a3 = {0.f, 0.f, 0.f, 0.f};
    int e = beg;
    for (; e + 8 <= end; e += 8) {
        int i0 = csr[e + half];
        int i1 = csr[e + half + 2];
        int i2 = csr[e + half + 4];
        int i3 = csr[e + half + 6];
        uint4 v0 = *(const uint4*)(xp + (size_t)i0 * DD + l32 * 4);
        uint4 v1 = *(const uint4*)(xp + (size_t)i1 * DD + l32 * 4);
        uint4 v2 = *(const uint4*)(xp + (size_t)i2 * DD + l32 * 4);
        uint4 v3 = *(const uint4*)(xp + (size_t)i3 * DD + l32 * 4);
        a0.x += unpackbf(v0.x); a0.y += unpackbf(v0.y); a0.z += unpackbf(v0.z); a0.w += unpackbf(v0.w);
        a1.x += unpackbf(v1.x); a1.y += unpackbf(v1.y); a1.z += unpackbf(v1.z); a1.w += unpackbf(v1.w);
        a2.x += unpackbf(v2.x); a2.y += unpackbf(v2.y); a2.z += unpackbf(v2.z); a2.w += unpackbf(v2.w);
        a3.x += unpackbf(v3.x); a3.y += unpackbf(v3.y); a3.z += unpackbf(v3.z); a3.w += unpackbf(v3.w);
    }
    for (; e + half < end; e += 2) {
        int i0 = csr[e + half];
        uint4 v0 = *(const uint4*)(xp + (size_t)i0 * DD + l32 * 4);
        a0.x += unpackbf(v0.x); a0.y += unpackbf(v0.y); a0.z += unpackbf(v0.z); a0.w += unpackbf(v0.w);
    }
    a0.x += a1.x + a2.x + a3.x;
    a0.y += a1.y + a2.y + a3.y;
    a0.z += a1.z + a2.z + a3.z;
    a0.w += a1.w + a2.w + a3.w;
    a0.x += __shfl_down(a0.x, 32, 64);
    a0.y += __shfl_down(a0.y, 32, 64);
    a0.z += __shfl_down(a0.z, 32, 64);
    a0.w += __shfl_down(a0.w, 32, 64);
    if (half == 0) {
        float id = invd[n];
        uint4 o;
        o.x = packbf(a0.x * id);
        o.y = packbf(a0.y * id);
        o.z = packbf(a0.z * id);
        o.w = packbf(a0.w * id);
        *(uint4*)(ap + (size_t)n * DD + l32 * 4) = o;
    }
}

// ---------------- fused SAGE layer GEMM: split-bf16 MFMA ----------------
__launch_bounds__(128)
__global__ void k_gemm(const unsigned* __restrict__ Ap, const unsigned* __restrict__ Xp,
                       const unsigned* __restrict__ Wtp,
                       const float* __restrict__ bl, const float* __restrict__ g,
                       const float* __restrict__ be, const float* __restrict__ mn,
                       const float* __restrict__ vr,
                       unsigned* __restrict__ Op, float* __restrict__ Of, int f32out) {
    __shared__ __align__(16) unsigned short sA[2][128 * 40];  // [hi/lo][row][k], k-stride 40
    __shared__ __align__(16) unsigned short sW[2][64 * 40];   // [hi/lo][n][k]
    int tid = threadIdx.x;
    int gx = blockIdx.x;
    int m0 = (gx >> 1) * 128;
    int n0 = (gx & 1) * 64;
    int lane = tid & 63;
    int w = tid >> 6;
    int fm = lane & 15, q = lane >> 4;
    int wm0 = w * 64;

    f32x4 acc[4][4];
#pragma unroll
    for (int i = 0; i < 4; i++)
#pragma unroll
        for (int j = 0; j < 4; j++) acc[i][j] = (f32x4){0.f, 0.f, 0.f, 0.f};

    for (int c = 0; c < 8; c++) {
        const unsigned* pA = (c < 4) ? Ap : Xp;
        int k0A = (c & 3) * 32;
        int k0W = c * 32;
        __syncthreads();
#pragma unroll
        for (int i = 0; i < 12; i++) {
            int u = tid + 128 * i;           // 0..1535
            uint4 val = make_uint4(0, 0, 0, 0);
            if (u < 1024) {
                int row = u >> 3, seg = u & 7;
                int grow = m0 + row;
                if (grow < NN)
                    val = *(const uint4*)(pA + (size_t)grow * DD + k0A + seg * 4);
                ushort4 hi, lo;
                hi.x = val.x >> 16; hi.y = val.y >> 16; hi.z = val.z >> 16; hi.w = val.w >> 16;
                lo.x = val.x & 0xFFFF; lo.y = val.y & 0xFFFF; lo.z = val.z & 0xFFFF; lo.w = val.w & 0xFFFF;
                *(ushort4*)&sA[0][row * 40 + seg * 4] = hi;
                *(ushort4*)&sA[1][row * 40 + seg * 4] = lo;
            } else {
                int v = u - 1024;
                int row = v >> 3, seg = v & 7;
                val = *(const uint4*)(Wtp + (size_t)(n0 + row) * 256 + k0W + seg * 4);
                ushort4 hi, lo;
                hi.x = val.x >> 16; hi.y = val.y >> 16; hi.z = val.z >> 16; hi.w = val.w >> 16;
                lo.x = val.x & 0xFFFF; lo.y = val.y & 0xFFFF; lo.z = val.z & 0xFFFF; lo.w = val.w & 0xFFFF;
                *(ushort4*)&sW[0][row * 40 + seg * 4] = hi;
                *(ushort4*)&sW[1][row * 40 + seg * 4] = lo;
            }
        }
        __syncthreads();
        bf16x8 af[4][2];
#pragma unroll
        for (int mt = 0; mt < 4; mt++) {
            int r = wm0 + mt * 16 + fm;
            af[mt][0] = *(const bf16x8*)&sA[0][r * 40 + q * 8];
            af[mt][1] = *(const bf16x8*)&sA[1][r * 40 + q * 8];
        }
#pragma unroll
        for (int nt = 0; nt < 4; nt++) {
            int nr = nt * 16 + fm;
            bf16x8 wh = *(const bf16x8*)&sW[0][nr * 40 + q * 8];
            bf16x8 wl = *(const bf16x8*)&sW[1][nr * 40 + q * 8];
#pragma unroll
            for (int mt = 0; mt < 4; mt++) {
                acc[mt][nt] = __builtin_amdgcn_mfma_f32_16x16x32_bf16(af[mt][0], wh, acc[mt][nt], 0, 0, 0);
                acc[mt][nt] = __builtin_amdgcn_mfma_f32_16x16x32_bf16(af[mt][0], wl, acc[mt][nt], 0, 0, 0);
                acc[mt][nt] = __builtin_amdgcn_mfma_f32_16x16x32_bf16(af[mt][1], wh, acc[mt][nt], 0, 0, 0);
            }
        }
    }

    float scv[4], shv[4];
#pragma unroll
    for (int nt = 0; nt < 4; nt++) {
        int jj = n0 + nt * 16 + fm;
        float s = g[jj] * rsqrtf(vr[jj] + EPSV);
        scv[nt] = s;
        shv[nt] = (bl[jj] - mn[jj]) * s + be[jj];
    }
#pragma unroll
    for (int mt = 0; mt < 4; mt++) {
#pragma unroll
        for (int r = 0; r < 4; r++) {
            int grow = m0 + wm0 + mt * 16 + q * 4 + r;
            if (grow < NN) {
#pragma unroll
                for (int nt = 0; nt < 4; nt++) {
                    int gcol = n0 + nt * 16 + fm;
                    float o = fmaxf(acc[mt][nt][r] * scv[nt] + shv[nt], 0.f);
                    if (f32out) Of[(size_t)grow * DD + gcol] = o;
                    else Op[(size_t)grow * DD + gcol] = packbf(o);
                }
            }
        }
    }
}

// ---------------- global add pool (atomic-free: batch is sorted) ----------------
__launch_bounds__(128)
__global__ void k_pool2(const float* __restrict__ h, const int* __restrict__ batch,
                        float* __restrict__ p) {
    int b = blockIdx.x;
    __shared__ int sr[2];
    if (threadIdx.x < 2) {
        int target = b + (int)threadIdx.x;
        int lo = 0, hi = NN;
        while (lo < hi) {
            int mid = (lo + hi) >> 1;
            if (batch[mid] < target) lo = mid + 1; else hi = mid;
        }
        sr[threadIdx.x] = lo;
    }
    __syncthreads();
    int beg = sr[0], end = sr[1];
    int t = threadIdx.x;
    float acc = 0.f;
    for (int r = beg; r < end; r++) acc += h[(size_t)r * DD + t];
    p[(size_t)b * DD + t] = acc;
}

// ---------------- final MLP head ----------------
__launch_bounds__(128)
__global__ void k_mlp(const float* __restrict__ p1, const float* __restrict__ p2,
                      const int* __restrict__ rel, const float* __restrict__ kge,
                      const float* __restrict__ W1, const float* __restrict__ b1,
                      const float* __restrict__ W2, const float* __restrict__ b2,
                      float* __restrict__ out) {
    int b = blockIdx.x;
    int tid = threadIdx.x;
    __shared__ float z[384];
    z[tid] = p1[(size_t)b * DD + tid];
    z[tid + 128] = p2[(size_t)b * DD + tid];
    int r = rel[b];
    z[tid + 256] = kge[(size_t)r * DD + tid];
    __syncthreads();
    float acc = b1[tid];
#pragma unroll 8
    for (int k = 0; k < 384; k++) acc += z[k] * W1[k * DD + tid];
    float h = fmaxf(acc, 0.f);
    float v = h * W2[tid];
#pragma unroll
    for (int off = 32; off > 0; off >>= 1) v += __shfl_down(v, off, 64);
    __shared__ float wsf[2];
    if ((tid & 63) == 0) wsf[tid >> 6] = v;
    __syncthreads();
    if (tid == 0) out[b] = wsf[0] + wsf[1] + b2[0];
}

extern "C" void kernel_launch(void* const* d_in, const int* in_sizes, int n_in,
                              void* d_out, int out_size, void* d_ws, size_t ws_size,
                              hipStream_t stream) {
    const float* x1  = (const float*)d_in[0];
    const float* x2  = (const float*)d_in[1];
    const int*   ei1 = (const int*)d_in[2];
    const int*   ei2 = (const int*)d_in[3];
    const int*   bt1 = (const int*)d_in[4];
    const int*   bt2 = (const int*)d_in[5];
    const int*   rel = (const int*)d_in[6];
    const float* Wl  = (const float*)d_in[7];
    const float* bl  = (const float*)d_in[8];
    const float* Wr  = (const float*)d_in[9];
    const float* g   = (const float*)d_in[10];
    const float* be  = (const float*)d_in[11];
    const float* mn  = (const float*)d_in[12];
    const float* vr  = (const float*)d_in[13];
    const float* kge = (const float*)d_in[14];
    const float* W1  = (const float*)d_in[15];
    const float* b1v = (const float*)d_in[16];
    const float* W2  = (const float*)d_in[17];
    const float* b2v = (const float*)d_in[18];

    char* ws = (char*)d_ws;
    size_t off = 0;
    auto alloc = [&](size_t bytes) {
        void* p = ws + off;
        off += (bytes + 255) & ~(size_t)255;
        return p;
    };
    unsigned* ap   = (unsigned*)alloc((size_t)NN * DD * 4);
    unsigned* op   = (unsigned*)alloc((size_t)NN * DD * 4);   // layer-2 fp32 out aliases
    unsigned* xp   = (unsigned*)alloc((size_t)NN * DD * 4);
    unsigned* wtp  = (unsigned*)alloc((size_t)3 * 128 * 256 * 4);
    float* p1      = (float*)alloc((size_t)NB * DD * 4);
    float* p2      = (float*)alloc((size_t)NB * DD * 4);
    int*   cnt2    = (int*)alloc((size_t)2 * NN * 4);
    int*   ptr0    = (int*)alloc((size_t)(NN + 1) * 4);
    int*   ptr1    = (int*)alloc((size_t)(NN + 1) * 4);
    int*   nxt2    = (int*)alloc((size_t)2 * NN * 4);
    float* invd0   = (float*)alloc((size_t)NN * 4);
    float* invd1   = (float*)alloc((size_t)NN * 4);
    int*   csr0    = (int*)alloc((size_t)NE * 4);
    int*   csr1    = (int*)alloc((size_t)NE * 4);
    int*   bsum2   = (int*)alloc(512 * 4);
    int*   boff2   = (int*)alloc(512 * 4);
    if (off > ws_size) return;

    int* cnt0 = cnt2;        int* cnt1 = cnt2 + NN;
    int* nxt0 = nxt2;        int* nxt1 = nxt2 + NN;
    int* bsum0 = bsum2;      int* bsum1 = bsum2 + 256;
    int* boff0 = boff2;      int* boff1 = boff2 + 256;
    float* cf = (float*)op;  // layer-2 fp32 output aliases op (dead by then)

    const int nbScan = (NN + 255) / 256;         // 196
    const int nbEdge = (NE + 255) / 256;         // 2344
    const int nbNode4 = (NN + 3) / 4;            // 12500
    const int nbGemm = ((NN + 127) / 128) * 2;   // 782
    const int nbCvt = (NN * DD / 4 + 255) / 256;

    k_wcvt<<<(3 * 128 * 256 + 255) / 256, 256, 0, stream>>>(Wl, Wr, wtp);

    // CSR build, both sides at once
    hipMemsetAsync(cnt2, 0, (size_t)2 * NN * 4, stream);
    k_deg2<<<2 * nbEdge, 256, 0, stream>>>(ei1 + NE, ei2 + NE, cnt0, cnt1);
    k_scan1m<<<2 * nbScan, 256, 0, stream>>>(cnt0, cnt1, ptr0, ptr1, bsum0, bsum1, nbScan);
    k_scan2m<<<2, 256, 0, stream>>>(bsum0, bsum1, boff0, boff1, nbScan);
    k_scan3m<<<2 * nbScan, 256, 0, stream>>>(cnt0, cnt1, boff0, boff1, ptr0, ptr1,
                                             nxt0, nxt1, invd0, invd1, nbScan);
    k_scatter2<<<2 * nbEdge, 256, 0, stream>>>(ei1, ei1 + NE, ei2, ei2 + NE,
                                               nxt0, nxt1, csr0, csr1);

    for (int side = 0; side < 2; side++) {
        const float* x   = side ? x2 : x1;
        const int*   ptr = side ? ptr1 : ptr0;
        const int*   csr = side ? csr1 : csr0;
        const float* ivd = side ? invd1 : invd0;
        const int*   bat = side ? bt2 : bt1;
        float*       pp  = side ? p2 : p1;

        k_cvt<<<nbCvt, 256, 0, stream>>>(x, xp, NN * DD / 4);

        // layer 0: gather(xp)->ap ; gemm(ap, xp, W0) -> op
        k_gather<<<nbNode4, 256, 0, stream>>>(xp, ptr, csr, ivd, ap);
        k_gemm<<<nbGemm, 128, 0, stream>>>(ap, xp, wtp, bl, g, be, mn, vr,
                                           op, (float*)nullptr, 0);
        // layer 1: gather(op)->ap ; gemm(ap, op, W1) -> xp
        k_gather<<<nbNode4, 256, 0, stream>>>(op, ptr, csr, ivd, ap);
        k_gemm<<<nbGemm, 128, 0, stream>>>(ap, op, wtp + 32768, bl + 128, g + 128,
                                           be + 128, mn + 128, vr + 128,
                                           xp, (float*)nullptr, 0);
        // layer 2: gather(xp)->ap ; gemm(ap, xp, W2) -> cf (fp32)
        k_gather<<<nbNode4, 256, 0, stream>>>(xp, ptr, csr, ivd, ap);
        k_gemm<<<nbGemm, 128, 0, stream>>>(ap, xp, wtp + 65536, bl + 256, g + 256,
                                           be + 256, mn + 256, vr + 256,
                                           (unsigned*)nullptr, cf, 1);

        k_pool2<<<NB, 128, 0, stream>>>(cf, bat, pp);
    }

    k_mlp<<<NB, 128, 0, stream>>>(p1, p2, rel, kge, W1, b1v, W2, b2v, (float*)d_out);
}

// Round 6
// 671.913 us; speedup vs baseline: 1.6615x; 1.1946x over previous
//
#include <hip/hip_runtime.h>

#define NN 50000
#define NE 600000
#define NB 4096
#define DD 128
#define EPSV 1e-5f

typedef __bf16 bf16x8 __attribute__((ext_vector_type(8)));
typedef float f32x4 __attribute__((ext_vector_type(4)));

__device__ inline unsigned short f2bf(float f) {
    unsigned u = __float_as_uint(f);
    u = (u + 0x7FFFu + ((u >> 16) & 1u)) >> 16;
    return (unsigned short)u;
}
__device__ inline float bf2f(unsigned short h) {
    return __uint_as_float(((unsigned)h) << 16);
}
// packed: hi bf16 in high 16 bits, lo bf16 in low 16 bits; value = hi + lo (~fp32)
__device__ inline unsigned packbf(float f) {
    unsigned short h = f2bf(f);
    unsigned short l = f2bf(f - bf2f(h));
    return ((unsigned)h << 16) | (unsigned)l;
}

// ---------------- input conversions ----------------
// packed hi|lo plane (xp) for GEMM + bf16-only plane (xh) for gather
__global__ void k_cvt(const float* __restrict__ x, unsigned* __restrict__ xp,
                      unsigned short* __restrict__ xh, int n4) {
    int i = blockIdx.x * 256 + threadIdx.x;
    if (i >= n4) return;
    float4 v = ((const float4*)x)[i];
    uint4 o;
    o.x = packbf(v.x); o.y = packbf(v.y); o.z = packbf(v.z); o.w = packbf(v.w);
    ((uint4*)xp)[i] = o;
    ushort4 h;
    h.x = o.x >> 16; h.y = o.y >> 16; h.z = o.z >> 16; h.w = o.w >> 16;
    ((ushort4*)xh)[i] = h;
}

// weights: build Wt[layer][n][k], k in [0,256): k<128 -> Wl[k][n], k>=128 -> Wr[k-128][n]
__global__ void k_wcvt(const float* __restrict__ Wl, const float* __restrict__ Wr,
                       unsigned* __restrict__ wtp) {
    int t = blockIdx.x * 256 + threadIdx.x;
    if (t >= 3 * 128 * 256) return;
    int k = t & 255;
    int n = (t >> 8) & 127;
    int l = t >> 15;
    float w = (k < 128) ? Wl[l * 16384 + k * 128 + n] : Wr[l * 16384 + (k - 128) * 128 + n];
    wtp[t] = packbf(w);
}

// ---------------- CSR build (both sides in one dispatch, rank-recording) ----------------
__global__ void k_deg2(const int* __restrict__ d0, const int* __restrict__ d1,
                       int* __restrict__ c0, int* __restrict__ c1,
                       int* __restrict__ r0, int* __restrict__ r1) {
    int e = blockIdx.x * 256 + threadIdx.x;
    if (e < NE) r0[e] = atomicAdd(&c0[d0[e]], 1);
    else if (e < 2 * NE) r1[e - NE] = atomicAdd(&c1[d1[e - NE]], 1);
}

__global__ void k_scan1m(const int* __restrict__ cnt0, const int* __restrict__ cnt1,
                         int* __restrict__ ptr0, int* __restrict__ ptr1,
                         int* __restrict__ bsum0, int* __restrict__ bsum1, int nbScan) {
    int side = (blockIdx.x >= nbScan) ? 1 : 0;
    int lb = blockIdx.x - side * nbScan;
    const int* cnt = side ? cnt1 : cnt0;
    int* ptr = side ? ptr1 : ptr0;
    int* bsum = side ? bsum1 : bsum0;
    int tid = threadIdx.x;
    int i = lb * 256 + tid;
    int v = (i < NN) ? cnt[i] : 0;
    int lane = tid & 63, wid = tid >> 6;
    int x = v;
#pragma unroll
    for (int off = 1; off < 64; off <<= 1) {
        int y = __shfl_up(x, off, 64);
        if (lane >= off) x += y;
    }
    __shared__ int wsum[4];
    if (lane == 63) wsum[wid] = x;
    __syncthreads();
    int add = 0;
#pragma unroll
    for (int w = 0; w < 4; w++)
        if (w < wid) add += wsum[w];
    int incl = x + add;
    if (i < NN) ptr[i] = incl - v;
    if (tid == 255) bsum[lb] = incl;
}

__global__ void k_scan2m(const int* __restrict__ bsum0, const int* __restrict__ bsum1,
                         int* __restrict__ boff0, int* __restrict__ boff1, int nb) {
    int side = blockIdx.x;
    const int* bsum = side ? bsum1 : bsum0;
    int* boff = side ? boff1 : boff0;
    int tid = threadIdx.x;
    int v = (tid < nb) ? bsum[tid] : 0;
    int lane = tid & 63, wid = tid >> 6;
    int x = v;
#pragma unroll
    for (int off = 1; off < 64; off <<= 1) {
        int y = __shfl_up(x, off, 64);
        if (lane >= off) x += y;
    }
    __shared__ int wsum[4];
    if (lane == 63) wsum[wid] = x;
    __syncthreads();
    int add = 0;
#pragma unroll
    for (int w = 0; w < 4; w++)
        if (w < wid) add += wsum[w];
    boff[tid] = x + add - v;
}

__global__ void k_scan3m(const int* __restrict__ cnt0, const int* __restrict__ cnt1,
                         const int* __restrict__ boff0, const int* __restrict__ boff1,
                         int* __restrict__ ptr0, int* __restrict__ ptr1,
                         float* __restrict__ invd0, float* __restrict__ invd1, int nbScan) {
    int side = (blockIdx.x >= nbScan) ? 1 : 0;
    int lb = blockIdx.x - side * nbScan;
    const int* cnt = side ? cnt1 : cnt0;
    const int* boff = side ? boff1 : boff0;
    int* ptr = side ? ptr1 : ptr0;
    float* invd = side ? invd1 : invd0;
    int i = lb * 256 + threadIdx.x;
    if (i < NN) {
        ptr[i] = ptr[i] + boff[lb];
        int c = cnt[i];
        invd[i] = 1.0f / (float)(c > 1 ? c : 1);
    }
    if (i == 0) ptr[NN] = NE;
}

// atomic-free placement: csr[ptr[dst] + rank] = src
__global__ void k_place2(const int* __restrict__ s0, const int* __restrict__ d0,
                         const int* __restrict__ r0, const int* __restrict__ ptr0,
                         const int* __restrict__ s1, const int* __restrict__ d1,
                         const int* __restrict__ r1, const int* __restrict__ ptr1,
                         int* __restrict__ csr0, int* __restrict__ csr1) {
    int e = blockIdx.x * 256 + threadIdx.x;
    if (e < NE) {
        csr0[ptr0[d0[e]] + r0[e]] = s0[e];
    } else if (e < 2 * NE) {
        int ee = e - NE;
        csr1[ptr1[d1[ee]] + r1[ee]] = s1[ee];
    }
}

// ---------------- neighbor mean-aggregation (bf16 plane in, packed out) ----------------
// one wave per node; half-wave per edge, ushort4 (8B) per lane, 8 edges in flight/wave
__global__ void k_gather(const unsigned short* __restrict__ xh, const int* __restrict__ ptr,
                         const int* __restrict__ csr, const float* __restrict__ invd,
                         unsigned* __restrict__ ap) {
    int wid = threadIdx.x >> 6;
    int lane = threadIdx.x & 63;
    int half = lane >> 5;
    int l32 = lane & 31;
    int n = blockIdx.x * 4 + wid;
    if (n >= NN) return;
    int beg = ptr[n], end = ptr[n + 1];
    f32x4 a0 = {0.f, 0.f, 0.f, 0.f}, a1 = {0.f, 0.f, 0.f, 0.f};
    f32x4 a2 = {0.f, 0.f, 0.f, 0.f}, a3 = {0.f, 0.f, 0.f, 0.f};
    int e = beg;
    for (; e + 8 <= end; e += 8) {
        int i0 = csr[e + half];
        int i1 = csr[e + half + 2];
        int i2 = csr[e + half + 4];
        int i3 = csr[e + half + 6];
        ushort4 v0 = *(const ushort4*)(xh + (size_t)i0 * DD + l32 * 4);
        ushort4 v1 = *(const ushort4*)(xh + (size_t)i1 * DD + l32 * 4);
        ushort4 v2 = *(const ushort4*)(xh + (size_t)i2 * DD + l32 * 4);
        ushort4 v3 = *(const ushort4*)(xh + (size_t)i3 * DD + l32 * 4);
        a0.x += bf2f(v0.x); a0.y += bf2f(v0.y); a0.z += bf2f(v0.z); a0.w += bf2f(v0.w);
        a1.x += bf2f(v1.x); a1.y += bf2f(v1.y); a1.z += bf2f(v1.z); a1.w += bf2f(v1.w);
        a2.x += bf2f(v2.x); a2.y += bf2f(v2.y); a2.z += bf2f(v2.z); a2.w += bf2f(v2.w);
        a3.x += bf2f(v3.x); a3.y += bf2f(v3.y); a3.z += bf2f(v3.z); a3.w += bf2f(v3.w);
    }
    for (; e + half < end; e += 2) {
        int i0 = csr[e + half];
        ushort4 v0 = *(const ushort4*)(xh + (size_t)i0 * DD + l32 * 4);
        a0.x += bf2f(v0.x); a0.y += bf2f(v0.y); a0.z += bf2f(v0.z); a0.w += bf2f(v0.w);
    }
    a0.x += a1.x + a2.x + a3.x;
    a0.y += a1.y + a2.y + a3.y;
    a0.z += a1.z + a2.z + a3.z;
    a0.w += a1.w + a2.w + a3.w;
    a0.x += __shfl_down(a0.x, 32, 64);
    a0.y += __shfl_down(a0.y, 32, 64);
    a0.z += __shfl_down(a0.z, 32, 64);
    a0.w += __shfl_down(a0.w, 32, 64);
    if (half == 0) {
        float id = invd[n];
        uint4 o;
        o.x = packbf(a0.x * id);
        o.y = packbf(a0.y * id);
        o.z = packbf(a0.z * id);
        o.w = packbf(a0.w * id);
        *(uint4*)(ap + (size_t)n * DD + l32 * 4) = o;
    }
}

// ---------------- fused SAGE layer GEMM: split-bf16 MFMA ----------------
// outputs: packed (Op) + bf16 plane (Oh) for the next gather, or fp32 (Of) for pooling
__launch_bounds__(128)
__global__ void k_gemm(const unsigned* __restrict__ Ap, const unsigned* __restrict__ Xp,
                       const unsigned* __restrict__ Wtp,
                       const float* __restrict__ bl, const float* __restrict__ g,
                       const float* __restrict__ be, const float* __restrict__ mn,
                       const float* __restrict__ vr,
                       unsigned* __restrict__ Op, unsigned short* __restrict__ Oh,
                       float* __restrict__ Of, int f32out) {
    __shared__ __align__(16) unsigned short sA[2][128 * 40];  // [hi/lo][row][k], k-stride 40
    __shared__ __align__(16) unsigned short sW[2][64 * 40];   // [hi/lo][n][k]
    int tid = threadIdx.x;
    int gx = blockIdx.x;
    int m0 = (gx >> 1) * 128;
    int n0 = (gx & 1) * 64;
    int lane = tid & 63;
    int w = tid >> 6;
    int fm = lane & 15, q = lane >> 4;
    int wm0 = w * 64;

    f32x4 acc[4][4];
#pragma unroll
    for (int i = 0; i < 4; i++)
#pragma unroll
        for (int j = 0; j < 4; j++) acc[i][j] = (f32x4){0.f, 0.f, 0.f, 0.f};

    for (int c = 0; c < 8; c++) {
        const unsigned* pA = (c < 4) ? Ap : Xp;
        int k0A = (c & 3) * 32;
        int k0W = c * 32;
        __syncthreads();
#pragma unroll
        for (int i = 0; i < 12; i++) {
            int u = tid + 128 * i;           // 0..1535
            uint4 val = make_uint4(0, 0, 0, 0);
            if (u < 1024) {
                int row = u >> 3, seg = u & 7;
                int grow = m0 + row;
                if (grow < NN)
                    val = *(const uint4*)(pA + (size_t)grow * DD + k0A + seg * 4);
                ushort4 hi, lo;
                hi.x = val.x >> 16; hi.y = val.y >> 16; hi.z = val.z >> 16; hi.w = val.w >> 16;
                lo.x = val.x & 0xFFFF; lo.y = val.y & 0xFFFF; lo.z = val.z & 0xFFFF; lo.w = val.w & 0xFFFF;
                *(ushort4*)&sA[0][row * 40 + seg * 4] = hi;
                *(ushort4*)&sA[1][row * 40 + seg * 4] = lo;
            } else {
                int v = u - 1024;
                int row = v >> 3, seg = v & 7;
                val = *(const uint4*)(Wtp + (size_t)(n0 + row) * 256 + k0W + seg * 4);
                ushort4 hi, lo;
                hi.x = val.x >> 16; hi.y = val.y >> 16; hi.z = val.z >> 16; hi.w = val.w >> 16;
                lo.x = val.x & 0xFFFF; lo.y = val.y & 0xFFFF; lo.z = val.z & 0xFFFF; lo.w = val.w & 0xFFFF;
                *(ushort4*)&sW[0][row * 40 + seg * 4] = hi;
                *(ushort4*)&sW[1][row * 40 + seg * 4] = lo;
            }
        }
        __syncthreads();
        bf16x8 af[4][2];
#pragma unroll
        for (int mt = 0; mt < 4; mt++) {
            int r = wm0 + mt * 16 + fm;
            af[mt][0] = *(const bf16x8*)&sA[0][r * 40 + q * 8];
            af[mt][1] = *(const bf16x8*)&sA[1][r * 40 + q * 8];
        }
#pragma unroll
        for (int nt = 0; nt < 4; nt++) {
            int nr = nt * 16 + fm;
            bf16x8 wh = *(const bf16x8*)&sW[0][nr * 40 + q * 8];
            bf16x8 wl = *(const bf16x8*)&sW[1][nr * 40 + q * 8];
#pragma unroll
            for (int mt = 0; mt < 4; mt++) {
                acc[mt][nt] = __builtin_amdgcn_mfma_f32_16x16x32_bf16(af[mt][0], wh, acc[mt][nt], 0, 0, 0);
                acc[mt][nt] = __builtin_amdgcn_mfma_f32_16x16x32_bf16(af[mt][0], wl, acc[mt][nt], 0, 0, 0);
                acc[mt][nt] = __builtin_amdgcn_mfma_f32_16x16x32_bf16(af[mt][1], wh, acc[mt][nt], 0, 0, 0);
            }
        }
    }

    float scv[4], shv[4];
#pragma unroll
    for (int nt = 0; nt < 4; nt++) {
        int jj = n0 + nt * 16 + fm;
        float s = g[jj] * rsqrtf(vr[jj] + EPSV);
        scv[nt] = s;
        shv[nt] = (bl[jj] - mn[jj]) * s + be[jj];
    }
#pragma unroll
    for (int mt = 0; mt < 4; mt++) {
#pragma unroll
        for (int r = 0; r < 4; r++) {
            int grow = m0 + wm0 + mt * 16 + q * 4 + r;
            if (grow < NN) {
#pragma unroll
                for (int nt = 0; nt < 4; nt++) {
                    int gcol = n0 + nt * 16 + fm;
                    float o = fmaxf(acc[mt][nt][r] * scv[nt] + shv[nt], 0.f);
                    if (f32out) {
                        Of[(size_t)grow * DD + gcol] = o;
                    } else {
                        unsigned pv = packbf(o);
                        Op[(size_t)grow * DD + gcol] = pv;
                        Oh[(size_t)grow * DD + gcol] = (unsigned short)(pv >> 16);
                    }
                }
            }
        }
    }
}

// ---------------- global add pool (atomic-free: batch is sorted) ----------------
__launch_bounds__(128)
__global__ void k_pool2(const float* __restrict__ h, const int* __restrict__ batch,
                        float* __restrict__ p) {
    int b = blockIdx.x;
    __shared__ int sr[2];
    if (threadIdx.x < 2) {
        int target = b + (int)threadIdx.x;
        int lo = 0, hi = NN;
        while (lo < hi) {
            int mid = (lo + hi) >> 1;
            if (batch[mid] < target) lo = mid + 1; else hi = mid;
        }
        sr[threadIdx.x] = lo;
    }
    __syncthreads();
    int beg = sr[0], end = sr[1];
    int t = threadIdx.x;
    float acc = 0.f;
    for (int r = beg; r < end; r++) acc += h[(size_t)r * DD + t];
    p[(size_t)b * DD + t] = acc;
}

// ---------------- final MLP head ----------------
__launch_bounds__(128)
__global__ void k_mlp(const float* __restrict__ p1, const float* __restrict__ p2,
                      const int* __restrict__ rel, const float* __restrict__ kge,
                      const float* __restrict__ W1, const float* __restrict__ b1,
                      const float* __restrict__ W2, const float* __restrict__ b2,
                      float* __restrict__ out) {
    int b = blockIdx.x;
    int tid = threadIdx.x;
    __shared__ float z[384];
    z[tid] = p1[(size_t)b * DD + tid];
    z[tid + 128] = p2[(size_t)b * DD + tid];
    int r = rel[b];
    z[tid + 256] = kge[(size_t)r * DD + tid];
    __syncthreads();
    float acc = b1[tid];
#pragma unroll 8
    for (int k = 0; k < 384; k++) acc += z[k] * W1[k * DD + tid];
    float h = fmaxf(acc, 0.f);
    float v = h * W2[tid];
#pragma unroll
    for (int off = 32; off > 0; off >>= 1) v += __shfl_down(v, off, 64);
    __shared__ float wsf[2];
    if ((tid & 63) == 0) wsf[tid >> 6] = v;
    __syncthreads();
    if (tid == 0) out[b] = wsf[0] + wsf[1] + b2[0];
}

extern "C" void kernel_launch(void* const* d_in, const int* in_sizes, int n_in,
                              void* d_out, int out_size, void* d_ws, size_t ws_size,
                              hipStream_t stream) {
    const float* x1  = (const float*)d_in[0];
    const float* x2  = (const float*)d_in[1];
    const int*   ei1 = (const int*)d_in[2];
    const int*   ei2 = (const int*)d_in[3];
    const int*   bt1 = (const int*)d_in[4];
    const int*   bt2 = (const int*)d_in[5];
    const int*   rel = (const int*)d_in[6];
    const float* Wl  = (const float*)d_in[7];
    const float* bl  = (const float*)d_in[8];
    const float* Wr  = (const float*)d_in[9];
    const float* g   = (const float*)d_in[10];
    const float* be  = (const float*)d_in[11];
    const float* mn  = (const float*)d_in[12];
    const float* vr  = (const float*)d_in[13];
    const float* kge = (const float*)d_in[14];
    const float* W1  = (const float*)d_in[15];
    const float* b1v = (const float*)d_in[16];
    const float* W2  = (const float*)d_in[17];
    const float* b2v = (const float*)d_in[18];

    char* ws = (char*)d_ws;
    size_t off = 0;
    auto alloc = [&](size_t bytes) {
        void* p = ws + off;
        off += (bytes + 255) & ~(size_t)255;
        return p;
    };
    unsigned* ap   = (unsigned*)alloc((size_t)NN * DD * 4);
    unsigned* op   = (unsigned*)alloc((size_t)NN * DD * 4);   // layer-2 fp32 out aliases
    unsigned* xp   = (unsigned*)alloc((size_t)NN * DD * 4);
    unsigned short* xh = (unsigned short*)alloc((size_t)NN * DD * 2);
    unsigned short* oh = (unsigned short*)alloc((size_t)NN * DD * 2);
    unsigned* wtp  = (unsigned*)alloc((size_t)3 * 128 * 256 * 4);
    float* p1      = (float*)alloc((size_t)NB * DD * 4);
    float* p2      = (float*)alloc((size_t)NB * DD * 4);
    int*   cnt2    = (int*)alloc((size_t)2 * NN * 4);
    int*   ptr0    = (int*)alloc((size_t)(NN + 1) * 4);
    int*   ptr1    = (int*)alloc((size_t)(NN + 1) * 4);
    int*   rank0   = (int*)alloc((size_t)NE * 4);
    int*   rank1   = (int*)alloc((size_t)NE * 4);
    float* invd0   = (float*)alloc((size_t)NN * 4);
    float* invd1   = (float*)alloc((size_t)NN * 4);
    int*   csr0    = (int*)alloc((size_t)NE * 4);
    int*   csr1    = (int*)alloc((size_t)NE * 4);
    int*   bsum2   = (int*)alloc(512 * 4);
    int*   boff2   = (int*)alloc(512 * 4);
    if (off > ws_size) return;

    int* cnt0 = cnt2;        int* cnt1 = cnt2 + NN;
    int* bsum0 = bsum2;      int* bsum1 = bsum2 + 256;
    int* boff0 = boff2;      int* boff1 = boff2 + 256;
    float* cf = (float*)op;  // layer-2 fp32 output aliases op (dead by then)

    const int nbScan = (NN + 255) / 256;         // 196
    const int nbEdge = (NE + 255) / 256;         // 2344
    const int nbNode4 = (NN + 3) / 4;            // 12500
    const int nbGemm = ((NN + 127) / 128) * 2;   // 782
    const int nbCvt = (NN * DD / 4 + 255) / 256;

    k_wcvt<<<(3 * 128 * 256 + 255) / 256, 256, 0, stream>>>(Wl, Wr, wtp);

    // CSR build, both sides at once, atomic only in the degree pass
    hipMemsetAsync(cnt2, 0, (size_t)2 * NN * 4, stream);
    k_deg2<<<2 * nbEdge, 256, 0, stream>>>(ei1 + NE, ei2 + NE, cnt0, cnt1, rank0, rank1);
    k_scan1m<<<2 * nbScan, 256, 0, stream>>>(cnt0, cnt1, ptr0, ptr1, bsum0, bsum1, nbScan);
    k_scan2m<<<2, 256, 0, stream>>>(bsum0, bsum1, boff0, boff1, nbScan);
    k_scan3m<<<2 * nbScan, 256, 0, stream>>>(cnt0, cnt1, boff0, boff1, ptr0, ptr1,
                                             invd0, invd1, nbScan);
    k_place2<<<2 * nbEdge, 256, 0, stream>>>(ei1, ei1 + NE, rank0, ptr0,
                                             ei2, ei2 + NE, rank1, ptr1, csr0, csr1);

    for (int side = 0; side < 2; side++) {
        const float* x   = side ? x2 : x1;
        const int*   ptr = side ? ptr1 : ptr0;
        const int*   csr = side ? csr1 : csr0;
        const float* ivd = side ? invd1 : invd0;
        const int*   bat = side ? bt2 : bt1;
        float*       pp  = side ? p2 : p1;

        k_cvt<<<nbCvt, 256, 0, stream>>>(x, xp, xh, NN * DD / 4);

        // layer 0: gather(xh)->ap ; gemm(ap, xp, W0) -> op + oh
        k_gather<<<nbNode4, 256, 0, stream>>>(xh, ptr, csr, ivd, ap);
        k_gemm<<<nbGemm, 128, 0, stream>>>(ap, xp, wtp, bl, g, be, mn, vr,
                                           op, oh, (float*)nullptr, 0);
        // layer 1: gather(oh)->ap ; gemm(ap, op, W1) -> xp + xh
        k_gather<<<nbNode4, 256, 0, stream>>>(oh, ptr, csr, ivd, ap);
        k_gemm<<<nbGemm, 128, 0, stream>>>(ap, op, wtp + 32768, bl + 128, g + 128,
                                           be + 128, mn + 128, vr + 128,
                                           xp, xh, (float*)nullptr, 0);
        // layer 2: gather(xh)->ap ; gemm(ap, xp, W2) -> cf (fp32)
        k_gather<<<nbNode4, 256, 0, stream>>>(xh, ptr, csr, ivd, ap);
        k_gemm<<<nbGemm, 128, 0, stream>>>(ap, xp, wtp + 65536, bl + 256, g + 256,
                                           be + 256, mn + 256, vr + 256,
                                           (unsigned*)nullptr, (unsigned short*)nullptr, cf, 1);

        k_pool2<<<NB, 128, 0, stream>>>(cf, bat, pp);
    }

    k_mlp<<<NB, 128, 0, stream>>>(p1, p2, rel, kge, W1, b1v, W2, b2v, (float*)d_out);
}

// Round 7
// 620.071 us; speedup vs baseline: 1.8004x; 1.0836x over previous
//
#include <hip/hip_runtime.h>

#define NN 50000
#define NE 600000
#define NB 4096
#define DD 128
#define EPSV 1e-5f

typedef __bf16 bf16x8 __attribute__((ext_vector_type(8)));
typedef float f32x4 __attribute__((ext_vector_type(4)));

__device__ inline unsigned short f2bf(float f) {
    unsigned u = __float_as_uint(f);
    u = (u + 0x7FFFu + ((u >> 16) & 1u)) >> 16;
    return (unsigned short)u;
}
__device__ inline float bf2f(unsigned short h) {
    return __uint_as_float(((unsigned)h) << 16);
}
// packed: hi bf16 in high 16 bits, lo bf16 in low 16 bits; value = hi + lo (~fp32)
__device__ inline unsigned packbf(float f) {
    unsigned short h = f2bf(f);
    unsigned short l = f2bf(f - bf2f(h));
    return ((unsigned)h << 16) | (unsigned)l;
}

// ---------------- input conversions ----------------
// packed hi|lo plane (xp) for GEMM + bf16-only plane (xh) for gather
__global__ void k_cvt(const float* __restrict__ x, unsigned* __restrict__ xp,
                      unsigned short* __restrict__ xh, int n4) {
    int i = blockIdx.x * 256 + threadIdx.x;
    if (i >= n4) return;
    float4 v = ((const float4*)x)[i];
    uint4 o;
    o.x = packbf(v.x); o.y = packbf(v.y); o.z = packbf(v.z); o.w = packbf(v.w);
    ((uint4*)xp)[i] = o;
    ushort4 h;
    h.x = o.x >> 16; h.y = o.y >> 16; h.z = o.z >> 16; h.w = o.w >> 16;
    ((ushort4*)xh)[i] = h;
}

// weights: build Wt[layer][n][k], k in [0,256): k<128 -> Wl[k][n], k>=128 -> Wr[k-128][n]
__global__ void k_wcvt(const float* __restrict__ Wl, const float* __restrict__ Wr,
                       unsigned* __restrict__ wtp) {
    int t = blockIdx.x * 256 + threadIdx.x;
    if (t >= 3 * 128 * 256) return;
    int k = t & 255;
    int n = (t >> 8) & 127;
    int l = t >> 15;
    float w = (k < 128) ? Wl[l * 16384 + k * 128 + n] : Wr[l * 16384 + (k - 128) * 128 + n];
    wtp[t] = packbf(w);
}

// ---------------- CSR build (both sides in one dispatch, rank-recording) ----------------
__global__ void k_deg2(const int* __restrict__ d0, const int* __restrict__ d1,
                       int* __restrict__ c0, int* __restrict__ c1,
                       int* __restrict__ r0, int* __restrict__ r1) {
    int e = blockIdx.x * 256 + threadIdx.x;
    if (e < NE) r0[e] = atomicAdd(&c0[d0[e]], 1);
    else if (e < 2 * NE) r1[e - NE] = atomicAdd(&c1[d1[e - NE]], 1);
}

__global__ void k_scan1m(const int* __restrict__ cnt0, const int* __restrict__ cnt1,
                         int* __restrict__ ptr0, int* __restrict__ ptr1,
                         int* __restrict__ bsum0, int* __restrict__ bsum1, int nbScan) {
    int side = (blockIdx.x >= nbScan) ? 1 : 0;
    int lb = blockIdx.x - side * nbScan;
    const int* cnt = side ? cnt1 : cnt0;
    int* ptr = side ? ptr1 : ptr0;
    int* bsum = side ? bsum1 : bsum0;
    int tid = threadIdx.x;
    int i = lb * 256 + tid;
    int v = (i < NN) ? cnt[i] : 0;
    int lane = tid & 63, wid = tid >> 6;
    int x = v;
#pragma unroll
    for (int off = 1; off < 64; off <<= 1) {
        int y = __shfl_up(x, off, 64);
        if (lane >= off) x += y;
    }
    __shared__ int wsum[4];
    if (lane == 63) wsum[wid] = x;
    __syncthreads();
    int add = 0;
#pragma unroll
    for (int w = 0; w < 4; w++)
        if (w < wid) add += wsum[w];
    int incl = x + add;
    if (i < NN) ptr[i] = incl - v;
    if (tid == 255) bsum[lb] = incl;
}

__global__ void k_scan2m(const int* __restrict__ bsum0, const int* __restrict__ bsum1,
                         int* __restrict__ boff0, int* __restrict__ boff1, int nb) {
    int side = blockIdx.x;
    const int* bsum = side ? bsum1 : bsum0;
    int* boff = side ? boff1 : boff0;
    int tid = threadIdx.x;
    int v = (tid < nb) ? bsum[tid] : 0;
    int lane = tid & 63, wid = tid >> 6;
    int x = v;
#pragma unroll
    for (int off = 1; off < 64; off <<= 1) {
        int y = __shfl_up(x, off, 64);
        if (lane >= off) x += y;
    }
    __shared__ int wsum[4];
    if (lane == 63) wsum[wid] = x;
    __syncthreads();
    int add = 0;
#pragma unroll
    for (int w = 0; w < 4; w++)
        if (w < wid) add += wsum[w];
    boff[tid] = x + add - v;
}

__global__ void k_scan3m(const int* __restrict__ cnt0, const int* __restrict__ cnt1,
                         const int* __restrict__ boff0, const int* __restrict__ boff1,
                         int* __restrict__ ptr0, int* __restrict__ ptr1,
                         float* __restrict__ invd0, float* __restrict__ invd1, int nbScan) {
    int side = (blockIdx.x >= nbScan) ? 1 : 0;
    int lb = blockIdx.x - side * nbScan;
    const int* cnt = side ? cnt1 : cnt0;
    const int* boff = side ? boff1 : boff0;
    int* ptr = side ? ptr1 : ptr0;
    float* invd = side ? invd1 : invd0;
    int i = lb * 256 + threadIdx.x;
    if (i < NN) {
        ptr[i] = ptr[i] + boff[lb];
        int c = cnt[i];
        invd[i] = 1.0f / (float)(c > 1 ? c : 1);
    }
    if (i == 0) ptr[NN] = NE;
}

// atomic-free placement: csr[ptr[dst] + rank] = src
__global__ void k_place2(const int* __restrict__ s0, const int* __restrict__ d0,
                         const int* __restrict__ r0, const int* __restrict__ ptr0,
                         const int* __restrict__ s1, const int* __restrict__ d1,
                         const int* __restrict__ r1, const int* __restrict__ ptr1,
                         int* __restrict__ csr0, int* __restrict__ csr1) {
    int e = blockIdx.x * 256 + threadIdx.x;
    if (e < NE) {
        csr0[ptr0[d0[e]] + r0[e]] = s0[e];
    } else if (e < 2 * NE) {
        int ee = e - NE;
        csr1[ptr1[d1[ee]] + r1[ee]] = s1[ee];
    }
}

// ---------------- neighbor mean-aggregation (bf16 plane in, packed out) ----------------
__global__ void k_gather(const unsigned short* __restrict__ xh, const int* __restrict__ ptr,
                         const int* __restrict__ csr, const float* __restrict__ invd,
                         unsigned* __restrict__ ap) {
    int wid = threadIdx.x >> 6;
    int lane = threadIdx.x & 63;
    int half = lane >> 5;
    int l32 = lane & 31;
    int n = blockIdx.x * 4 + wid;
    if (n >= NN) return;
    int beg = ptr[n], end = ptr[n + 1];
    f32x4 a0 = {0.f, 0.f, 0.f, 0.f}, a1 = {0.f, 0.f, 0.f, 0.f};
    f32x4 a2 = {0.f, 0.f, 0.f, 0.f}, a3 = {0.f, 0.f, 0.f, 0.f};
    int e = beg;
    for (; e + 8 <= end; e += 8) {
        int i0 = csr[e + half];
        int i1 = csr[e + half + 2];
        int i2 = csr[e + half + 4];
        int i3 = csr[e + half + 6];
        ushort4 v0 = *(const ushort4*)(xh + (size_t)i0 * DD + l32 * 4);
        ushort4 v1 = *(const ushort4*)(xh + (size_t)i1 * DD + l32 * 4);
        ushort4 v2 = *(const ushort4*)(xh + (size_t)i2 * DD + l32 * 4);
        ushort4 v3 = *(const ushort4*)(xh + (size_t)i3 * DD + l32 * 4);
        a0.x += bf2f(v0.x); a0.y += bf2f(v0.y); a0.z += bf2f(v0.z); a0.w += bf2f(v0.w);
        a1.x += bf2f(v1.x); a1.y += bf2f(v1.y); a1.z += bf2f(v1.z); a1.w += bf2f(v1.w);
        a2.x += bf2f(v2.x); a2.y += bf2f(v2.y); a2.z += bf2f(v2.z); a2.w += bf2f(v2.w);
        a3.x += bf2f(v3.x); a3.y += bf2f(v3.y); a3.z += bf2f(v3.z); a3.w += bf2f(v3.w);
    }
    for (; e + half < end; e += 2) {
        int i0 = csr[e + half];
        ushort4 v0 = *(const ushort4*)(xh + (size_t)i0 * DD + l32 * 4);
        a0.x += bf2f(v0.x); a0.y += bf2f(v0.y); a0.z += bf2f(v0.z); a0.w += bf2f(v0.w);
    }
    a0.x += a1.x + a2.x + a3.x;
    a0.y += a1.y + a2.y + a3.y;
    a0.z += a1.z + a2.z + a3.z;
    a0.w += a1.w + a2.w + a3.w;
    a0.x += __shfl_down(a0.x, 32, 64);
    a0.y += __shfl_down(a0.y, 32, 64);
    a0.z += __shfl_down(a0.z, 32, 64);
    a0.w += __shfl_down(a0.w, 32, 64);
    if (half == 0) {
        float id = invd[n];
        uint4 o;
        o.x = packbf(a0.x * id);
        o.y = packbf(a0.y * id);
        o.z = packbf(a0.z * id);
        o.w = packbf(a0.w * id);
        *(uint4*)(ap + (size_t)n * DD + l32 * 4) = o;
    }
}

// ---------------- fused SAGE layer GEMM: split-bf16 MFMA ----------------
// BM=64, BN=64, BK=32; 256 threads = 4 waves, wave tile 32x32 (2x2 of 16x16).
// grid = mtiles*2 (6.1 blocks/CU) for latency hiding; LDS 20.5 KB.
__launch_bounds__(256)
__global__ void k_gemm(const unsigned* __restrict__ Ap, const unsigned* __restrict__ Xp,
                       const unsigned* __restrict__ Wtp,
                       const float* __restrict__ bl, const float* __restrict__ g,
                       const float* __restrict__ be, const float* __restrict__ mn,
                       const float* __restrict__ vr,
                       unsigned* __restrict__ Op, unsigned short* __restrict__ Oh,
                       float* __restrict__ Of, int f32out) {
    __shared__ __align__(16) unsigned short sA[2][64 * 40];  // [hi/lo][row][k], k-stride 40
    __shared__ __align__(16) unsigned short sW[2][64 * 40];  // [hi/lo][n][k]
    int tid = threadIdx.x;
    int gx = blockIdx.x;
    int m0 = (gx >> 1) * 64;
    int n0 = (gx & 1) * 64;
    int lane = tid & 63;
    int w = tid >> 6;           // wave 0..3
    int fm = lane & 15, q = lane >> 4;
    int wr = (w & 1) * 32;      // wave row offset in tile
    int wn = (w >> 1) * 32;     // wave col offset in tile

    f32x4 acc[2][2];
#pragma unroll
    for (int i = 0; i < 2; i++)
#pragma unroll
        for (int j = 0; j < 2; j++) acc[i][j] = (f32x4){0.f, 0.f, 0.f, 0.f};

    for (int c = 0; c < 8; c++) {
        const unsigned* pA = (c < 4) ? Ap : Xp;
        int k0A = (c & 3) * 32;
        int k0W = c * 32;
        __syncthreads();
        // stage: A 64 rows x 8 segs + W 64 rows x 8 segs (seg = uint4 = 4 packed)
#pragma unroll
        for (int i = 0; i < 4; i++) {
            int u = tid + 256 * i;           // 0..1023
            uint4 val = make_uint4(0, 0, 0, 0);
            int row = (u >> 3) & 63, seg = u & 7;
            if (u < 512) {
                int grow = m0 + row;
                if (grow < NN)
                    val = *(const uint4*)(pA + (size_t)grow * DD + k0A + seg * 4);
                ushort4 hi, lo;
                hi.x = val.x >> 16; hi.y = val.y >> 16; hi.z = val.z >> 16; hi.w = val.w >> 16;
                lo.x = val.x & 0xFFFF; lo.y = val.y & 0xFFFF; lo.z = val.z & 0xFFFF; lo.w = val.w & 0xFFFF;
                *(ushort4*)&sA[0][row * 40 + seg * 4] = hi;
                *(ushort4*)&sA[1][row * 40 + seg * 4] = lo;
            } else {
                val = *(const uint4*)(Wtp + (size_t)(n0 + row) * 256 + k0W + seg * 4);
                ushort4 hi, lo;
                hi.x = val.x >> 16; hi.y = val.y >> 16; hi.z = val.z >> 16; hi.w = val.w >> 16;
                lo.x = val.x & 0xFFFF; lo.y = val.y & 0xFFFF; lo.z = val.z & 0xFFFF; lo.w = val.w & 0xFFFF;
                *(ushort4*)&sW[0][row * 40 + seg * 4] = hi;
                *(ushort4*)&sW[1][row * 40 + seg * 4] = lo;
            }
        }
        __syncthreads();
        bf16x8 af[2][2];
#pragma unroll
        for (int mt = 0; mt < 2; mt++) {
            int r = wr + mt * 16 + fm;
            af[mt][0] = *(const bf16x8*)&sA[0][r * 40 + q * 8];
            af[mt][1] = *(const bf16x8*)&sA[1][r * 40 + q * 8];
        }
#pragma unroll
        for (int nt = 0; nt < 2; nt++) {
            int nr = wn + nt * 16 + fm;
            bf16x8 wh = *(const bf16x8*)&sW[0][nr * 40 + q * 8];
            bf16x8 wl = *(const bf16x8*)&sW[1][nr * 40 + q * 8];
#pragma unroll
            for (int mt = 0; mt < 2; mt++) {
                acc[mt][nt] = __builtin_amdgcn_mfma_f32_16x16x32_bf16(af[mt][0], wh, acc[mt][nt], 0, 0, 0);
                acc[mt][nt] = __builtin_amdgcn_mfma_f32_16x16x32_bf16(af[mt][0], wl, acc[mt][nt], 0, 0, 0);
                acc[mt][nt] = __builtin_amdgcn_mfma_f32_16x16x32_bf16(af[mt][1], wh, acc[mt][nt], 0, 0, 0);
            }
        }
    }

    // epilogue: BN(eval) + relu; C layout col=lane&15, row=q*4+reg
    float scv[2], shv[2];
#pragma unroll
    for (int nt = 0; nt < 2; nt++) {
        int jj = n0 + wn + nt * 16 + fm;
        float s = g[jj] * rsqrtf(vr[jj] + EPSV);
        scv[nt] = s;
        shv[nt] = (bl[jj] - mn[jj]) * s + be[jj];
    }
#pragma unroll
    for (int mt = 0; mt < 2; mt++) {
#pragma unroll
        for (int r = 0; r < 4; r++) {
            int grow = m0 + wr + mt * 16 + q * 4 + r;
            if (grow < NN) {
#pragma unroll
                for (int nt = 0; nt < 2; nt++) {
                    int gcol = n0 + wn + nt * 16 + fm;
                    float o = fmaxf(acc[mt][nt][r] * scv[nt] + shv[nt], 0.f);
                    if (f32out) {
                        Of[(size_t)grow * DD + gcol] = o;
                    } else {
                        unsigned pv = packbf(o);
                        Op[(size_t)grow * DD + gcol] = pv;
                        Oh[(size_t)grow * DD + gcol] = (unsigned short)(pv >> 16);
                    }
                }
            }
        }
    }
}

// ---------------- global add pool (atomic-free: batch is sorted) ----------------
__launch_bounds__(128)
__global__ void k_pool2(const float* __restrict__ h, const int* __restrict__ batch,
                        float* __restrict__ p) {
    int b = blockIdx.x;
    __shared__ int sr[2];
    if (threadIdx.x < 2) {
        int target = b + (int)threadIdx.x;
        int lo = 0, hi = NN;
        while (lo < hi) {
            int mid = (lo + hi) >> 1;
            if (batch[mid] < target) lo = mid + 1; else hi = mid;
        }
        sr[threadIdx.x] = lo;
    }
    __syncthreads();
    int beg = sr[0], end = sr[1];
    int t = threadIdx.x;
    float acc = 0.f;
    for (int r = beg; r < end; r++) acc += h[(size_t)r * DD + t];
    p[(size_t)b * DD + t] = acc;
}

// ---------------- final MLP head ----------------
__launch_bounds__(128)
__global__ void k_mlp(const float* __restrict__ p1, const float* __restrict__ p2,
                      const int* __restrict__ rel, const float* __restrict__ kge,
                      const float* __restrict__ W1, const float* __restrict__ b1,
                      const float* __restrict__ W2, const float* __restrict__ b2,
                      float* __restrict__ out) {
    int b = blockIdx.x;
    int tid = threadIdx.x;
    __shared__ float z[384];
    z[tid] = p1[(size_t)b * DD + tid];
    z[tid + 128] = p2[(size_t)b * DD + tid];
    int r = rel[b];
    z[tid + 256] = kge[(size_t)r * DD + tid];
    __syncthreads();
    float acc = b1[tid];
#pragma unroll 8
    for (int k = 0; k < 384; k++) acc += z[k] * W1[k * DD + tid];
    float h = fmaxf(acc, 0.f);
    float v = h * W2[tid];
#pragma unroll
    for (int off = 32; off > 0; off >>= 1) v += __shfl_down(v, off, 64);
    __shared__ float wsf[2];
    if ((tid & 63) == 0) wsf[tid >> 6] = v;
    __syncthreads();
    if (tid == 0) out[b] = wsf[0] + wsf[1] + b2[0];
}

extern "C" void kernel_launch(void* const* d_in, const int* in_sizes, int n_in,
                              void* d_out, int out_size, void* d_ws, size_t ws_size,
                              hipStream_t stream) {
    const float* x1  = (const float*)d_in[0];
    const float* x2  = (const float*)d_in[1];
    const int*   ei1 = (const int*)d_in[2];
    const int*   ei2 = (const int*)d_in[3];
    const int*   bt1 = (const int*)d_in[4];
    const int*   bt2 = (const int*)d_in[5];
    const int*   rel = (const int*)d_in[6];
    const float* Wl  = (const float*)d_in[7];
    const float* bl  = (const float*)d_in[8];
    const float* Wr  = (const float*)d_in[9];
    const float* g   = (const float*)d_in[10];
    const float* be  = (const float*)d_in[11];
    const float* mn  = (const float*)d_in[12];
    const float* vr  = (const float*)d_in[13];
    const float* kge = (const float*)d_in[14];
    const float* W1  = (const float*)d_in[15];
    const float* b1v = (const float*)d_in[16];
    const float* W2  = (const float*)d_in[17];
    const float* b2v = (const float*)d_in[18];

    char* ws = (char*)d_ws;
    size_t off = 0;
    auto alloc = [&](size_t bytes) {
        void* p = ws + off;
        off += (bytes + 255) & ~(size_t)255;
        return p;
    };
    unsigned* ap   = (unsigned*)alloc((size_t)NN * DD * 4);
    unsigned* op   = (unsigned*)alloc((size_t)NN * DD * 4);   // layer-2 fp32 out aliases
    unsigned* xp   = (unsigned*)alloc((size_t)NN * DD * 4);
    unsigned short* xh = (unsigned short*)alloc((size_t)NN * DD * 2);
    unsigned short* oh = (unsigned short*)alloc((size_t)NN * DD * 2);
    unsigned* wtp  = (unsigned*)alloc((size_t)3 * 128 * 256 * 4);
    float* p1      = (float*)alloc((size_t)NB * DD * 4);
    float* p2      = (float*)alloc((size_t)NB * DD * 4);
    int*   cnt2    = (int*)alloc((size_t)2 * NN * 4);
    int*   ptr0    = (int*)alloc((size_t)(NN + 1) * 4);
    int*   ptr1    = (int*)alloc((size_t)(NN + 1) * 4);
    int*   rank0   = (int*)alloc((size_t)NE * 4);
    int*   rank1   = (int*)alloc((size_t)NE * 4);
    float* invd0   = (float*)alloc((size_t)NN * 4);
    float* invd1   = (float*)alloc((size_t)NN * 4);
    int*   csr0    = (int*)alloc((size_t)NE * 4);
    int*   csr1    = (int*)alloc((size_t)NE * 4);
    int*   bsum2   = (int*)alloc(512 * 4);
    int*   boff2   = (int*)alloc(512 * 4);
    if (off > ws_size) return;

    int* cnt0 = cnt2;        int* cnt1 = cnt2 + NN;
    int* bsum0 = bsum2;      int* bsum1 = bsum2 + 256;
    int* boff0 = boff2;      int* boff1 = boff2 + 256;
    float* cf = (float*)op;  // layer-2 fp32 output aliases op (dead by then)

    const int nbScan = (NN + 255) / 256;         // 196
    const int nbEdge = (NE + 255) / 256;         // 2344
    const int nbNode4 = (NN + 3) / 4;            // 12500
    const int nbGemm = ((NN + 63) / 64) * 2;     // 782 * 2 = 1564
    const int nbCvt = (NN * DD / 4 + 255) / 256;

    k_wcvt<<<(3 * 128 * 256 + 255) / 256, 256, 0, stream>>>(Wl, Wr, wtp);

    // CSR build, both sides at once, atomic only in the degree pass
    hipMemsetAsync(cnt2, 0, (size_t)2 * NN * 4, stream);
    k_deg2<<<2 * nbEdge, 256, 0, stream>>>(ei1 + NE, ei2 + NE, cnt0, cnt1, rank0, rank1);
    k_scan1m<<<2 * nbScan, 256, 0, stream>>>(cnt0, cnt1, ptr0, ptr1, bsum0, bsum1, nbScan);
    k_scan2m<<<2, 256, 0, stream>>>(bsum0, bsum1, boff0, boff1, nbScan);
    k_scan3m<<<2 * nbScan, 256, 0, stream>>>(cnt0, cnt1, boff0, boff1, ptr0, ptr1,
                                             invd0, invd1, nbScan);
    k_place2<<<2 * nbEdge, 256, 0, stream>>>(ei1, ei1 + NE, rank0, ptr0,
                                             ei2, ei2 + NE, rank1, ptr1, csr0, csr1);

    for (int side = 0; side < 2; side++) {
        const float* x   = side ? x2 : x1;
        const int*   ptr = side ? ptr1 : ptr0;
        const int*   csr = side ? csr1 : csr0;
        const float* ivd = side ? invd1 : invd0;
        const int*   bat = side ? bt2 : bt1;
        float*       pp  = side ? p2 : p1;

        k_cvt<<<nbCvt, 256, 0, stream>>>(x, xp, xh, NN * DD / 4);

        // layer 0: gather(xh)->ap ; gemm(ap, xp, W0) -> op + oh
        k_gather<<<nbNode4, 256, 0, stream>>>(xh, ptr, csr, ivd, ap);
        k_gemm<<<nbGemm, 256, 0, stream>>>(ap, xp, wtp, bl, g, be, mn, vr,
                                           op, oh, (float*)nullptr, 0);
        // layer 1: gather(oh)->ap ; gemm(ap, op, W1) -> xp + xh
        k_gather<<<nbNode4, 256, 0, stream>>>(oh, ptr, csr, ivd, ap);
        k_gemm<<<nbGemm, 256, 0, stream>>>(ap, op, wtp + 32768, bl + 128, g + 128,
                                           be + 128, mn + 128, vr + 128,
                                           xp, xh, (float*)nullptr, 0);
        // layer 2: gather(xh)->ap ; gemm(ap, xp, W2) -> cf (fp32)
        k_gather<<<nbNode4, 256, 0, stream>>>(xh, ptr, csr, ivd, ap);
        k_gemm<<<nbGemm, 256, 0, stream>>>(ap, xp, wtp + 65536, bl + 256, g + 256,
                                           be + 256, mn + 256, vr + 256,
                                           (unsigned*)nullptr, (unsigned short*)nullptr, cf, 1);

        k_pool2<<<NB, 128, 0, stream>>>(cf, bat, pp);
    }

    k_mlp<<<NB, 128, 0, stream>>>(p1, p2, rel, kge, W1, b1v, W2, b2v, (float*)d_out);
}

// Round 8
// 616.813 us; speedup vs baseline: 1.8099x; 1.0053x over previous
//
#include <hip/hip_runtime.h>

#define NN 50000
#define NE 600000
#define NB 4096
#define DD 128
#define EPSV 1e-5f
#define RREP 8

typedef __bf16 bf16x8 __attribute__((ext_vector_type(8)));
typedef float f32x4 __attribute__((ext_vector_type(4)));

__device__ inline unsigned short f2bf(float f) {
    unsigned u = __float_as_uint(f);
    u = (u + 0x7FFFu + ((u >> 16) & 1u)) >> 16;
    return (unsigned short)u;
}
__device__ inline float bf2f(unsigned short h) {
    return __uint_as_float(((unsigned)h) << 16);
}
// packed: hi bf16 in high 16 bits, lo bf16 in low 16 bits; value = hi + lo (~fp32)
__device__ inline unsigned packbf(float f) {
    unsigned short h = f2bf(f);
    unsigned short l = f2bf(f - bf2f(h));
    return ((unsigned)h << 16) | (unsigned)l;
}

// ---------------- input conversions ----------------
__global__ void k_cvt(const float* __restrict__ x, unsigned* __restrict__ xp,
                      unsigned short* __restrict__ xh, int n4) {
    int i = blockIdx.x * 256 + threadIdx.x;
    if (i >= n4) return;
    float4 v = ((const float4*)x)[i];
    uint4 o;
    o.x = packbf(v.x); o.y = packbf(v.y); o.z = packbf(v.z); o.w = packbf(v.w);
    ((uint4*)xp)[i] = o;
    ushort4 h;
    h.x = o.x >> 16; h.y = o.y >> 16; h.z = o.z >> 16; h.w = o.w >> 16;
    ((ushort4*)xh)[i] = h;
}

// weights: build Wt[layer][n][k], k in [0,256): k<128 -> Wl[k][n], k>=128 -> Wr[k-128][n]
__global__ void k_wcvt(const float* __restrict__ Wl, const float* __restrict__ Wr,
                       unsigned* __restrict__ wtp) {
    int t = blockIdx.x * 256 + threadIdx.x;
    if (t >= 3 * 128 * 256) return;
    int k = t & 255;
    int n = (t >> 8) & 127;
    int l = t >> 15;
    float w = (k < 128) ? Wl[l * 16384 + k * 128 + n] : Wr[l * 16384 + (k - 128) * 128 + n];
    wtp[t] = packbf(w);
}

// ---------------- CSR build: replicated counters kill atomic serialization ----------------
// cntR layout: [side][rep][NN]
__global__ void k_deg2(const int* __restrict__ d0, const int* __restrict__ d1,
                       int* __restrict__ cntR,
                       int* __restrict__ r0, int* __restrict__ r1) {
    int e = blockIdx.x * 256 + threadIdx.x;
    int rep = blockIdx.x & (RREP - 1);
    if (e < NE) {
        r0[e] = atomicAdd(&cntR[rep * NN + d0[e]], 1);
    } else if (e < 2 * NE) {
        r1[e - NE] = atomicAdd(&cntR[RREP * NN + rep * NN + d1[e - NE]], 1);
    }
}

// per node: degree = sum over reps; replace cntR with per-rep exclusive offsets
__global__ void k_sumoff(int* __restrict__ cntR, int* __restrict__ deg,
                         float* __restrict__ invd0, float* __restrict__ invd1, int nbScan) {
    int side = (blockIdx.x >= nbScan) ? 1 : 0;
    int lb = blockIdx.x - side * nbScan;
    int i = lb * 256 + threadIdx.x;
    if (i >= NN) return;
    int* c = cntR + side * RREP * NN;
    int s = 0;
#pragma unroll
    for (int r = 0; r < RREP; r++) {
        int t = c[r * NN + i];
        c[r * NN + i] = s;
        s += t;
    }
    deg[side * NN + i] = s;
    float* invd = side ? invd1 : invd0;
    invd[i] = 1.0f / (float)(s > 1 ? s : 1);
}

__global__ void k_scan1m(const int* __restrict__ deg,
                         int* __restrict__ ptr0, int* __restrict__ ptr1,
                         int* __restrict__ bsum0, int* __restrict__ bsum1, int nbScan) {
    int side = (blockIdx.x >= nbScan) ? 1 : 0;
    int lb = blockIdx.x - side * nbScan;
    int* ptr = side ? ptr1 : ptr0;
    int* bsum = side ? bsum1 : bsum0;
    int tid = threadIdx.x;
    int i = lb * 256 + tid;
    int v = (i < NN) ? deg[side * NN + i] : 0;
    int lane = tid & 63, wid = tid >> 6;
    int x = v;
#pragma unroll
    for (int off = 1; off < 64; off <<= 1) {
        int y = __shfl_up(x, off, 64);
        if (lane >= off) x += y;
    }
    __shared__ int wsum[4];
    if (lane == 63) wsum[wid] = x;
    __syncthreads();
    int add = 0;
#pragma unroll
    for (int w = 0; w < 4; w++)
        if (w < wid) add += wsum[w];
    int incl = x + add;
    if (i < NN) ptr[i] = incl - v;
    if (tid == 255) bsum[lb] = incl;
}

__global__ void k_scan2m(const int* __restrict__ bsum0, const int* __restrict__ bsum1,
                         int* __restrict__ boff0, int* __restrict__ boff1, int nb) {
    int side = blockIdx.x;
    const int* bsum = side ? bsum1 : bsum0;
    int* boff = side ? boff1 : boff0;
    int tid = threadIdx.x;
    int v = (tid < nb) ? bsum[tid] : 0;
    int lane = tid & 63, wid = tid >> 6;
    int x = v;
#pragma unroll
    for (int off = 1; off < 64; off <<= 1) {
        int y = __shfl_up(x, off, 64);
        if (lane >= off) x += y;
    }
    __shared__ int wsum[4];
    if (lane == 63) wsum[wid] = x;
    __syncthreads();
    int add = 0;
#pragma unroll
    for (int w = 0; w < 4; w++)
        if (w < wid) add += wsum[w];
    boff[tid] = x + add - v;
}

__global__ void k_scan3m(const int* __restrict__ boff0, const int* __restrict__ boff1,
                         int* __restrict__ ptr0, int* __restrict__ ptr1, int nbScan) {
    int side = (blockIdx.x >= nbScan) ? 1 : 0;
    int lb = blockIdx.x - side * nbScan;
    const int* boff = side ? boff1 : boff0;
    int* ptr = side ? ptr1 : ptr0;
    int i = lb * 256 + threadIdx.x;
    if (i < NN) ptr[i] += boff[lb];
    if (i == 0) ptr[NN] = NE;
}

// atomic-free placement: csr[ptr[d] + off[rep][d] + rank] = src  (rep mapping matches k_deg2)
__global__ void k_place2(const int* __restrict__ s0, const int* __restrict__ d0,
                         const int* __restrict__ r0, const int* __restrict__ ptr0,
                         const int* __restrict__ s1, const int* __restrict__ d1,
                         const int* __restrict__ r1, const int* __restrict__ ptr1,
                         const int* __restrict__ cntR,
                         int* __restrict__ csr0, int* __restrict__ csr1) {
    int e = blockIdx.x * 256 + threadIdx.x;
    int rep = blockIdx.x & (RREP - 1);
    if (e < NE) {
        int d = d0[e];
        csr0[ptr0[d] + cntR[rep * NN + d] + r0[e]] = s0[e];
    } else if (e < 2 * NE) {
        int ee = e - NE;
        int d = d1[ee];
        csr1[ptr1[d] + cntR[RREP * NN + rep * NN + d] + r1[ee]] = s1[ee];
    }
}

// ---------------- neighbor mean-aggregation (bf16 plane in, packed out) ----------------
// half-wave per edge slot; masked 4-deep unroll: every edge processed at ILP 4
__global__ void k_gather(const unsigned short* __restrict__ xh, const int* __restrict__ ptr,
                         const int* __restrict__ csr, const float* __restrict__ invd,
                         unsigned* __restrict__ ap) {
    int wid = threadIdx.x >> 6;
    int lane = threadIdx.x & 63;
    int half = lane >> 5;
    int l32 = lane & 31;
    int n = blockIdx.x * 4 + wid;
    if (n >= NN) return;
    int beg = ptr[n], end = ptr[n + 1];
    f32x4 a0 = {0.f, 0.f, 0.f, 0.f}, a1 = {0.f, 0.f, 0.f, 0.f};
    f32x4 a2 = {0.f, 0.f, 0.f, 0.f}, a3 = {0.f, 0.f, 0.f, 0.f};
    for (int e = beg + half; e < end; e += 8) {
        int e1 = e + 2, e2 = e + 4, e3 = e + 6;
        int i0 = csr[e];
        int i1 = csr[min(e1, end - 1)];
        int i2 = csr[min(e2, end - 1)];
        int i3 = csr[min(e3, end - 1)];
        float w1 = (e1 < end) ? 1.f : 0.f;
        float w2 = (e2 < end) ? 1.f : 0.f;
        float w3 = (e3 < end) ? 1.f : 0.f;
        ushort4 v0 = *(const ushort4*)(xh + (size_t)i0 * DD + l32 * 4);
        ushort4 v1 = *(const ushort4*)(xh + (size_t)i1 * DD + l32 * 4);
        ushort4 v2 = *(const ushort4*)(xh + (size_t)i2 * DD + l32 * 4);
        ushort4 v3 = *(const ushort4*)(xh + (size_t)i3 * DD + l32 * 4);
        a0.x += bf2f(v0.x); a0.y += bf2f(v0.y); a0.z += bf2f(v0.z); a0.w += bf2f(v0.w);
        a1.x += w1 * bf2f(v1.x); a1.y += w1 * bf2f(v1.y); a1.z += w1 * bf2f(v1.z); a1.w += w1 * bf2f(v1.w);
        a2.x += w2 * bf2f(v2.x); a2.y += w2 * bf2f(v2.y); a2.z += w2 * bf2f(v2.z); a2.w += w2 * bf2f(v2.w);
        a3.x += w3 * bf2f(v3.x); a3.y += w3 * bf2f(v3.y); a3.z += w3 * bf2f(v3.z); a3.w += w3 * bf2f(v3.w);
    }
    a0.x += a1.x + a2.x + a3.x;
    a0.y += a1.y + a2.y + a3.y;
    a0.z += a1.z + a2.z + a3.z;
    a0.w += a1.w + a2.w + a3.w;
    a0.x += __shfl_down(a0.x, 32, 64);
    a0.y += __shfl_down(a0.y, 32, 64);
    a0.z += __shfl_down(a0.z, 32, 64);
    a0.w += __shfl_down(a0.w, 32, 64);
    if (half == 0) {
        float id = invd[n];
        uint4 o;
        o.x = packbf(a0.x * id);
        o.y = packbf(a0.y * id);
        o.z = packbf(a0.z * id);
        o.w = packbf(a0.w * id);
        *(uint4*)(ap + (size_t)n * DD + l32 * 4) = o;
    }
}

// ---------------- fused SAGE layer GEMM: split-bf16 MFMA ----------------
// BM=64, BN=64, BK=32; 256 threads = 4 waves, wave tile 32x32 (2x2 of 16x16).
__launch_bounds__(256)
__global__ void k_gemm(const unsigned* __restrict__ Ap, const unsigned* __restrict__ Xp,
                       const unsigned* __restrict__ Wtp,
                       const float* __restrict__ bl, const float* __restrict__ g,
                       const float* __restrict__ be, const float* __restrict__ mn,
                       const float* __restrict__ vr,
                       unsigned* __restrict__ Op, unsigned short* __restrict__ Oh,
                       float* __restrict__ Of, int f32out) {
    __shared__ __align__(16) unsigned short sA[2][64 * 40];  // [hi/lo][row][k], k-stride 40
    __shared__ __align__(16) unsigned short sW[2][64 * 40];  // [hi/lo][n][k]
    int tid = threadIdx.x;
    int gx = blockIdx.x;
    int m0 = (gx >> 1) * 64;
    int n0 = (gx & 1) * 64;
    int lane = tid & 63;
    int w = tid >> 6;           // wave 0..3
    int fm = lane & 15, q = lane >> 4;
    int wr = (w & 1) * 32;      // wave row offset in tile
    int wn = (w >> 1) * 32;     // wave col offset in tile

    f32x4 acc[2][2];
#pragma unroll
    for (int i = 0; i < 2; i++)
#pragma unroll
        for (int j = 0; j < 2; j++) acc[i][j] = (f32x4){0.f, 0.f, 0.f, 0.f};

    for (int c = 0; c < 8; c++) {
        const unsigned* pA = (c < 4) ? Ap : Xp;
        int k0A = (c & 3) * 32;
        int k0W = c * 32;
        __syncthreads();
#pragma unroll
        for (int i = 0; i < 4; i++) {
            int u = tid + 256 * i;           // 0..1023
            uint4 val = make_uint4(0, 0, 0, 0);
            int row = (u >> 3) & 63, seg = u & 7;
            if (u < 512) {
                int grow = m0 + row;
                if (grow < NN)
                    val = *(const uint4*)(pA + (size_t)grow * DD + k0A + seg * 4);
                ushort4 hi, lo;
                hi.x = val.x >> 16; hi.y = val.y >> 16; hi.z = val.z >> 16; hi.w = val.w >> 16;
                lo.x = val.x & 0xFFFF; lo.y = val.y & 0xFFFF; lo.z = val.z & 0xFFFF; lo.w = val.w & 0xFFFF;
                *(ushort4*)&sA[0][row * 40 + seg * 4] = hi;
                *(ushort4*)&sA[1][row * 40 + seg * 4] = lo;
            } else {
                val = *(const uint4*)(Wtp + (size_t)(n0 + row) * 256 + k0W + seg * 4);
                ushort4 hi, lo;
                hi.x = val.x >> 16; hi.y = val.y >> 16; hi.z = val.z >> 16; hi.w = val.w >> 16;
                lo.x = val.x & 0xFFFF; lo.y = val.y & 0xFFFF; lo.z = val.z & 0xFFFF; lo.w = val.w & 0xFFFF;
                *(ushort4*)&sW[0][row * 40 + seg * 4] = hi;
                *(ushort4*)&sW[1][row * 40 + seg * 4] = lo;
            }
        }
        __syncthreads();
        bf16x8 af[2][2];
#pragma unroll
        for (int mt = 0; mt < 2; mt++) {
            int r = wr + mt * 16 + fm;
            af[mt][0] = *(const bf16x8*)&sA[0][r * 40 + q * 8];
            af[mt][1] = *(const bf16x8*)&sA[1][r * 40 + q * 8];
        }
#pragma unroll
        for (int nt = 0; nt < 2; nt++) {
            int nr = wn + nt * 16 + fm;
            bf16x8 wh = *(const bf16x8*)&sW[0][nr * 40 + q * 8];
            bf16x8 wl = *(const bf16x8*)&sW[1][nr * 40 + q * 8];
#pragma unroll
            for (int mt = 0; mt < 2; mt++) {
                acc[mt][nt] = __builtin_amdgcn_mfma_f32_16x16x32_bf16(af[mt][0], wh, acc[mt][nt], 0, 0, 0);
                acc[mt][nt] = __builtin_amdgcn_mfma_f32_16x16x32_bf16(af[mt][0], wl, acc[mt][nt], 0, 0, 0);
                acc[mt][nt] = __builtin_amdgcn_mfma_f32_16x16x32_bf16(af[mt][1], wh, acc[mt][nt], 0, 0, 0);
            }
        }
    }

    float scv[2], shv[2];
#pragma unroll
    for (int nt = 0; nt < 2; nt++) {
        int jj = n0 + wn + nt * 16 + fm;
        float s = g[jj] * rsqrtf(vr[jj] + EPSV);
        scv[nt] = s;
        shv[nt] = (bl[jj] - mn[jj]) * s + be[jj];
    }
#pragma unroll
    for (int mt = 0; mt < 2; mt++) {
#pragma unroll
        for (int r = 0; r < 4; r++) {
            int grow = m0 + wr + mt * 16 + q * 4 + r;
            if (grow < NN) {
#pragma unroll
                for (int nt = 0; nt < 2; nt++) {
                    int gcol = n0 + wn + nt * 16 + fm;
                    float o = fmaxf(acc[mt][nt][r] * scv[nt] + shv[nt], 0.f);
                    if (f32out) {
                        Of[(size_t)grow * DD + gcol] = o;
                    } else {
                        unsigned pv = packbf(o);
                        Op[(size_t)grow * DD + gcol] = pv;
                        Oh[(size_t)grow * DD + gcol] = (unsigned short)(pv >> 16);
                    }
                }
            }
        }
    }
}

// ---------------- global add pool (atomic-free: batch is sorted) ----------------
__launch_bounds__(128)
__global__ void k_pool2(const float* __restrict__ h, const int* __restrict__ batch,
                        float* __restrict__ p) {
    int b = blockIdx.x;
    __shared__ int sr[2];
    if (threadIdx.x < 2) {
        int target = b + (int)threadIdx.x;
        int lo = 0, hi = NN;
        while (lo < hi) {
            int mid = (lo + hi) >> 1;
            if (batch[mid] < target) lo = mid + 1; else hi = mid;
        }
        sr[threadIdx.x] = lo;
    }
    __syncthreads();
    int beg = sr[0], end = sr[1];
    int t = threadIdx.x;
    float acc = 0.f;
    for (int r = beg; r < end; r++) acc += h[(size_t)r * DD + t];
    p[(size_t)b * DD + t] = acc;
}

// ---------------- final MLP head ----------------
__launch_bounds__(128)
__global__ void k_mlp(const float* __restrict__ p1, const float* __restrict__ p2,
                      const int* __restrict__ rel, const float* __restrict__ kge,
                      const float* __restrict__ W1, const float* __restrict__ b1,
                      const float* __restrict__ W2, const float* __restrict__ b2,
                      float* __restrict__ out) {
    int b = blockIdx.x;
    int tid = threadIdx.x;
    __shared__ float z[384];
    z[tid] = p1[(size_t)b * DD + tid];
    z[tid + 128] = p2[(size_t)b * DD + tid];
    int r = rel[b];
    z[tid + 256] = kge[(size_t)r * DD + tid];
    __syncthreads();
    float acc = b1[tid];
#pragma unroll 8
    for (int k = 0; k < 384; k++) acc += z[k] * W1[k * DD + tid];
    float h = fmaxf(acc, 0.f);
    float v = h * W2[tid];
#pragma unroll
    for (int off = 32; off > 0; off >>= 1) v += __shfl_down(v, off, 64);
    __shared__ float wsf[2];
    if ((tid & 63) == 0) wsf[tid >> 6] = v;
    __syncthreads();
    if (tid == 0) out[b] = wsf[0] + wsf[1] + b2[0];
}

extern "C" void kernel_launch(void* const* d_in, const int* in_sizes, int n_in,
                              void* d_out, int out_size, void* d_ws, size_t ws_size,
                              hipStream_t stream) {
    const float* x1  = (const float*)d_in[0];
    const float* x2  = (const float*)d_in[1];
    const int*   ei1 = (const int*)d_in[2];
    const int*   ei2 = (const int*)d_in[3];
    const int*   bt1 = (const int*)d_in[4];
    const int*   bt2 = (const int*)d_in[5];
    const int*   rel = (const int*)d_in[6];
    const float* Wl  = (const float*)d_in[7];
    const float* bl  = (const float*)d_in[8];
    const float* Wr  = (const float*)d_in[9];
    const float* g   = (const float*)d_in[10];
    const float* be  = (const float*)d_in[11];
    const float* mn  = (const float*)d_in[12];
    const float* vr  = (const float*)d_in[13];
    const float* kge = (const float*)d_in[14];
    const float* W1  = (const float*)d_in[15];
    const float* b1v = (const float*)d_in[16];
    const float* W2  = (const float*)d_in[17];
    const float* b2v = (const float*)d_in[18];

    char* ws = (char*)d_ws;
    size_t off = 0;
    auto alloc = [&](size_t bytes) {
        void* p = ws + off;
        off += (bytes + 255) & ~(size_t)255;
        return p;
    };
    unsigned* ap   = (unsigned*)alloc((size_t)NN * DD * 4);
    unsigned* op   = (unsigned*)alloc((size_t)NN * DD * 4);   // layer-2 fp32 out aliases
    unsigned* xp   = (unsigned*)alloc((size_t)NN * DD * 4);
    unsigned short* xh = (unsigned short*)alloc((size_t)NN * DD * 2);
    unsigned short* oh = (unsigned short*)alloc((size_t)NN * DD * 2);
    unsigned* wtp  = (unsigned*)alloc((size_t)3 * 128 * 256 * 4);
    float* p1      = (float*)alloc((size_t)NB * DD * 4);
    float* p2      = (float*)alloc((size_t)NB * DD * 4);
    int*   cntR    = (int*)alloc((size_t)2 * RREP * NN * 4);
    int*   deg     = (int*)alloc((size_t)2 * NN * 4);
    int*   ptr0    = (int*)alloc((size_t)(NN + 1) * 4);
    int*   ptr1    = (int*)alloc((size_t)(NN + 1) * 4);
    int*   rank0   = (int*)alloc((size_t)NE * 4);
    int*   rank1   = (int*)alloc((size_t)NE * 4);
    float* invd0   = (float*)alloc((size_t)NN * 4);
    float* invd1   = (float*)alloc((size_t)NN * 4);
    int*   csr0    = (int*)alloc((size_t)NE * 4);
    int*   csr1    = (int*)alloc((size_t)NE * 4);
    int*   bsum2   = (int*)alloc(512 * 4);
    int*   boff2   = (int*)alloc(512 * 4);
    if (off > ws_size) return;

    int* bsum0 = bsum2;      int* bsum1 = bsum2 + 256;
    int* boff0 = boff2;      int* boff1 = boff2 + 256;
    float* cf = (float*)op;  // layer-2 fp32 output aliases op (dead by then)

    const int nbScan = (NN + 255) / 256;         // 196
    const int nbEdge = (NE + 255) / 256;         // 2344
    const int nbNode4 = (NN + 3) / 4;            // 12500
    const int nbGemm = ((NN + 63) / 64) * 2;     // 1564
    const int nbCvt = (NN * DD / 4 + 255) / 256;

    k_wcvt<<<(3 * 128 * 256 + 255) / 256, 256, 0, stream>>>(Wl, Wr, wtp);

    // CSR build, both sides at once, 8x-replicated counters
    hipMemsetAsync(cntR, 0, (size_t)2 * RREP * NN * 4, stream);
    k_deg2<<<2 * nbEdge, 256, 0, stream>>>(ei1 + NE, ei2 + NE, cntR, rank0, rank1);
    k_sumoff<<<2 * nbScan, 256, 0, stream>>>(cntR, deg, invd0, invd1, nbScan);
    k_scan1m<<<2 * nbScan, 256, 0, stream>>>(deg, ptr0, ptr1, bsum0, bsum1, nbScan);
    k_scan2m<<<2, 256, 0, stream>>>(bsum0, bsum1, boff0, boff1, nbScan);
    k_scan3m<<<2 * nbScan, 256, 0, stream>>>(boff0, boff1, ptr0, ptr1, nbScan);
    k_place2<<<2 * nbEdge, 256, 0, stream>>>(ei1, ei1 + NE, rank0, ptr0,
                                             ei2, ei2 + NE, rank1, ptr1, cntR, csr0, csr1);

    for (int side = 0; side < 2; side++) {
        const float* x   = side ? x2 : x1;
        const int*   ptr = side ? ptr1 : ptr0;
        const int*   csr = side ? csr1 : csr0;
        const float* ivd = side ? invd1 : invd0;
        const int*   bat = side ? bt2 : bt1;
        float*       pp  = side ? p2 : p1;

        k_cvt<<<nbCvt, 256, 0, stream>>>(x, xp, xh, NN * DD / 4);

        // layer 0: gather(xh)->ap ; gemm(ap, xp, W0) -> op + oh
        k_gather<<<nbNode4, 256, 0, stream>>>(xh, ptr, csr, ivd, ap);
        k_gemm<<<nbGemm, 256, 0, stream>>>(ap, xp, wtp, bl, g, be, mn, vr,
                                           op, oh, (float*)nullptr, 0);
        // layer 1: gather(oh)->ap ; gemm(ap, op, W1) -> xp + xh
        k_gather<<<nbNode4, 256, 0, stream>>>(oh, ptr, csr, ivd, ap);
        k_gemm<<<nbGemm, 256, 0, stream>>>(ap, op, wtp + 32768, bl + 128, g + 128,
                                           be + 128, mn + 128, vr + 128,
                                           xp, xh, (float*)nullptr, 0);
        // layer 2: gather(xh)->ap ; gemm(ap, xp, W2) -> cf (fp32)
        k_gather<<<nbNode4, 256, 0, stream>>>(xh, ptr, csr, ivd, ap);
        k_gemm<<<nbGemm, 256, 0, stream>>>(ap, xp, wtp + 65536, bl + 256, g + 256,
                                           be + 256, mn + 256, vr + 256,
                                           (unsigned*)nullptr, (unsigned short*)nullptr, cf, 1);

        k_pool2<<<NB, 128, 0, stream>>>(cf, bat, pp);
    }

    k_mlp<<<NB, 128, 0, stream>>>(p1, p2, rel, kge, W1, b1v, W2, b2v, (float*)d_out);
}

// Round 9
// 561.856 us; speedup vs baseline: 1.9869x; 1.0978x over previous
//
#include <hip/hip_runtime.h>

#define NN 50000
#define NE 600000
#define NB 4096
#define DD 128
#define EPSV 1e-5f
#define NBKT 196     // ceil(50000/256) buckets of 256 node ids
#define NCHUNK 256   // edge chunks per side
#define CHSZ ((NE + NCHUNK - 1) / NCHUNK)   // 2344

typedef __bf16 bf16x8 __attribute__((ext_vector_type(8)));
typedef float f32x4 __attribute__((ext_vector_type(4)));

__device__ inline unsigned short f2bf(float f) {
    unsigned u = __float_as_uint(f);
    u = (u + 0x7FFFu + ((u >> 16) & 1u)) >> 16;
    return (unsigned short)u;
}
__device__ inline float bf2f(unsigned short h) {
    return __uint_as_float(((unsigned)h) << 16);
}
// packed: hi bf16 in high 16 bits, lo bf16 in low 16 bits; value = hi + lo (~fp32)
__device__ inline unsigned packbf(float f) {
    unsigned short h = f2bf(f);
    unsigned short l = f2bf(f - bf2f(h));
    return ((unsigned)h << 16) | (unsigned)l;
}

// ---------------- input conversions ----------------
__global__ void k_cvt(const float* __restrict__ x, unsigned* __restrict__ xp,
                      unsigned short* __restrict__ xh, int n4) {
    int i = blockIdx.x * 256 + threadIdx.x;
    if (i >= n4) return;
    float4 v = ((const float4*)x)[i];
    uint4 o;
    o.x = packbf(v.x); o.y = packbf(v.y); o.z = packbf(v.z); o.w = packbf(v.w);
    ((uint4*)xp)[i] = o;
    ushort4 h;
    h.x = o.x >> 16; h.y = o.y >> 16; h.z = o.z >> 16; h.w = o.w >> 16;
    ((ushort4*)xh)[i] = h;
}

// weights: build Wt[layer][n][k], k in [0,256): k<128 -> Wl[k][n], k>=128 -> Wr[k-128][n]
__global__ void k_wcvt(const float* __restrict__ Wl, const float* __restrict__ Wr,
                       unsigned* __restrict__ wtp) {
    int t = blockIdx.x * 256 + threadIdx.x;
    if (t >= 3 * 128 * 256) return;
    int k = t & 255;
    int n = (t >> 8) & 127;
    int l = t >> 15;
    float w = (k < 128) ? Wl[l * 16384 + k * 128 + n] : Wr[l * 16384 + (k - 128) * 128 + n];
    wtp[t] = packbf(w);
}

// ---------------- CSR build: atomic-free two-level counting sort ----------------
// bcnt[(side*NCHUNK + c)*NBKT + b]: chunk c's count for bucket b (later: excl offset)
__global__ void k_hist(const int* __restrict__ d0, const int* __restrict__ d1,
                       int* __restrict__ bcnt) {
    int side = (blockIdx.x >= NCHUNK) ? 1 : 0;
    int c = blockIdx.x - side * NCHUNK;
    const int* dst = side ? d1 : d0;
    int tid = threadIdx.x;
    __shared__ int h[NBKT];
    for (int i = tid; i < NBKT; i += 256) h[i] = 0;
    __syncthreads();
    int e0 = c * CHSZ, e1 = min(e0 + CHSZ, NE);
    for (int e = e0 + tid; e < e1; e += 256) atomicAdd(&h[dst[e] >> 8], 1);
    __syncthreads();
    int* bc = bcnt + ((size_t)side * NCHUNK + c) * NBKT;
    for (int i = tid; i < NBKT; i += 256) bc[i] = h[i];
}

// per (side,bucket): exclusive scan over chunks; total -> btot
__global__ void k_s1(int* __restrict__ bcnt, int* __restrict__ btot) {
    int side = (blockIdx.x >= NBKT) ? 1 : 0;
    int b = blockIdx.x - side * NBKT;
    int tid = threadIdx.x;            // tid == chunk
    int idx = ((size_t)side * NCHUNK + tid) * NBKT + b;
    int v = bcnt[idx];
    int lane = tid & 63, wv = tid >> 6;
    int x = v;
#pragma unroll
    for (int off = 1; off < 64; off <<= 1) {
        int y = __shfl_up(x, off, 64);
        if (lane >= off) x += y;
    }
    __shared__ int ws4[4];
    if (lane == 63) ws4[wv] = x;
    __syncthreads();
    int add = 0;
#pragma unroll
    for (int w = 0; w < 4; w++)
        if (w < wv) add += ws4[w];
    int incl = x + add;
    bcnt[idx] = incl - v;
    if (tid == 255) btot[side * NBKT + b] = incl;
}

// per side: exclusive scan over buckets -> bbase; set ptr[NN]
__global__ void k_s2(const int* __restrict__ btot, int* __restrict__ bbase,
                     int* __restrict__ ptr0, int* __restrict__ ptr1) {
    int side = blockIdx.x;
    int tid = threadIdx.x;
    int v = (tid < NBKT) ? btot[side * NBKT + tid] : 0;
    int lane = tid & 63, wv = tid >> 6;
    int x = v;
#pragma unroll
    for (int off = 1; off < 64; off <<= 1) {
        int y = __shfl_up(x, off, 64);
        if (lane >= off) x += y;
    }
    __shared__ int ws4[4];
    if (lane == 63) ws4[wv] = x;
    __syncthreads();
    int add = 0;
#pragma unroll
    for (int w = 0; w < 4; w++)
        if (w < wv) add += ws4[w];
    int incl = x + add;
    if (tid < NBKT) bbase[side * NBKT + tid] = incl - v;
    if (tid == 0) {
        if (side == 0) ptr0[NN] = NE; else ptr1[NN] = NE;
    }
}

// partition edges into bucket-contiguous (src,dst) pairs; LDS atomics only
__global__ void k_part(const int* __restrict__ s0, const int* __restrict__ d0,
                       const int* __restrict__ s1, const int* __restrict__ d1,
                       const int* __restrict__ bcnt, const int* __restrict__ bbase,
                       int2* __restrict__ part) {
    int side = (blockIdx.x >= NCHUNK) ? 1 : 0;
    int c = blockIdx.x - side * NCHUNK;
    const int* src = side ? s1 : s0;
    const int* dst = side ? d1 : d0;
    int tid = threadIdx.x;
    __shared__ int off[NBKT];
    const int* bc = bcnt + ((size_t)side * NCHUNK + c) * NBKT;
    for (int i = tid; i < NBKT; i += 256) off[i] = bbase[side * NBKT + i] + bc[i];
    __syncthreads();
    int e0 = c * CHSZ, e1 = min(e0 + CHSZ, NE);
    int2* P = part + (size_t)side * NE;
    for (int e = e0 + tid; e < e1; e += 256) {
        int d = dst[e];
        int pos = atomicAdd(&off[d >> 8], 1);
        P[pos] = make_int2(src[e], d);
    }
}

// per bucket: count 256 nodes, block scan -> ptr/invd, place src into final CSR
__global__ void k_csr(const int2* __restrict__ part, const int* __restrict__ bbase,
                      int* __restrict__ ptr0, int* __restrict__ ptr1,
                      float* __restrict__ invd0, float* __restrict__ invd1,
                      int* __restrict__ csr0, int* __restrict__ csr1) {
    int side = (blockIdx.x >= NBKT) ? 1 : 0;
    int b = blockIdx.x - side * NBKT;
    int tid = threadIdx.x;
    int* ptr = side ? ptr1 : ptr0;
    float* invd = side ? invd1 : invd0;
    int* csr = side ? csr1 : csr0;
    const int2* P = part + (size_t)side * NE;
    int base = bbase[side * NBKT + b];
    int endp = (b == NBKT - 1) ? NE : bbase[side * NBKT + b + 1];
    __shared__ int cnt[256];
    cnt[tid] = 0;
    __syncthreads();
    for (int e = base + tid; e < endp; e += 256) atomicAdd(&cnt[P[e].y & 255], 1);
    __syncthreads();
    int v = cnt[tid];
    int lane = tid & 63, wv = tid >> 6;
    int x = v;
#pragma unroll
    for (int off = 1; off < 64; off <<= 1) {
        int y = __shfl_up(x, off, 64);
        if (lane >= off) x += y;
    }
    __shared__ int ws4[4];
    if (lane == 63) ws4[wv] = x;
    __syncthreads();
    int add = 0;
#pragma unroll
    for (int w = 0; w < 4; w++)
        if (w < wv) add += ws4[w];
    int excl = x + add - v;
    int node = (b << 8) + tid;
    if (node < NN) {
        ptr[node] = base + excl;
        invd[node] = 1.0f / (float)(v > 1 ? v : 1);
    }
    __syncthreads();
    cnt[tid] = excl;          // running offsets (bucket-relative)
    __syncthreads();
    for (int e = base + tid; e < endp; e += 256) {
        int2 p = P[e];
        int pos = atomicAdd(&cnt[p.y & 255], 1);
        csr[base + pos] = p.x;
    }
}

// ---------------- neighbor mean-aggregation (bf16 plane in, packed out) ----------------
// half-wave per edge slot; masked 4-deep unroll: every edge processed at ILP 4
__global__ void k_gather(const unsigned short* __restrict__ xh, const int* __restrict__ ptr,
                         const int* __restrict__ csr, const float* __restrict__ invd,
                         unsigned* __restrict__ ap) {
    int wid = threadIdx.x >> 6;
    int lane = threadIdx.x & 63;
    int half = lane >> 5;
    int l32 = lane & 31;
    int n = blockIdx.x * 4 + wid;
    if (n >= NN) return;
    int beg = ptr[n], end = ptr[n + 1];
    f32x4 a0 = {0.f, 0.f, 0.f, 0.f}, a1 = {0.f, 0.f, 0.f, 0.f};
    f32x4 a2 = {0.f, 0.f, 0.f, 0.f}, a3 = {0.f, 0.f, 0.f, 0.f};
    for (int e = beg + half; e < end; e += 8) {
        int e1 = e + 2, e2 = e + 4, e3 = e + 6;
        int i0 = csr[e];
        int i1 = csr[min(e1, end - 1)];
        int i2 = csr[min(e2, end - 1)];
        int i3 = csr[min(e3, end - 1)];
        float w1 = (e1 < end) ? 1.f : 0.f;
        float w2 = (e2 < end) ? 1.f : 0.f;
        float w3 = (e3 < end) ? 1.f : 0.f;
        ushort4 v0 = *(const ushort4*)(xh + (size_t)i0 * DD + l32 * 4);
        ushort4 v1 = *(const ushort4*)(xh + (size_t)i1 * DD + l32 * 4);
        ushort4 v2 = *(const ushort4*)(xh + (size_t)i2 * DD + l32 * 4);
        ushort4 v3 = *(const ushort4*)(xh + (size_t)i3 * DD + l32 * 4);
        a0.x += bf2f(v0.x); a0.y += bf2f(v0.y); a0.z += bf2f(v0.z); a0.w += bf2f(v0.w);
        a1.x += w1 * bf2f(v1.x); a1.y += w1 * bf2f(v1.y); a1.z += w1 * bf2f(v1.z); a1.w += w1 * bf2f(v1.w);
        a2.x += w2 * bf2f(v2.x); a2.y += w2 * bf2f(v2.y); a2.z += w2 * bf2f(v2.z); a2.w += w2 * bf2f(v2.w);
        a3.x += w3 * bf2f(v3.x); a3.y += w3 * bf2f(v3.y); a3.z += w3 * bf2f(v3.z); a3.w += w3 * bf2f(v3.w);
    }
    a0.x += a1.x + a2.x + a3.x;
    a0.y += a1.y + a2.y + a3.y;
    a0.z += a1.z + a2.z + a3.z;
    a0.w += a1.w + a2.w + a3.w;
    a0.x += __shfl_down(a0.x, 32, 64);
    a0.y += __shfl_down(a0.y, 32, 64);
    a0.z += __shfl_down(a0.z, 32, 64);
    a0.w += __shfl_down(a0.w, 32, 64);
    if (half == 0) {
        float id = invd[n];
        uint4 o;
        o.x = packbf(a0.x * id);
        o.y = packbf(a0.y * id);
        o.z = packbf(a0.z * id);
        o.w = packbf(a0.w * id);
        *(uint4*)(ap + (size_t)n * DD + l32 * 4) = o;
    }
}

// ---------------- fused SAGE layer GEMM: split-bf16 MFMA ----------------
// BM=64, BN=64, BK=32; 256 threads = 4 waves, wave tile 32x32 (2x2 of 16x16).
__launch_bounds__(256)
__global__ void k_gemm(const unsigned* __restrict__ Ap, const unsigned* __restrict__ Xp,
                       const unsigned* __restrict__ Wtp,
                       const float* __restrict__ bl, const float* __restrict__ g,
                       const float* __restrict__ be, const float* __restrict__ mn,
                       const float* __restrict__ vr,
                       unsigned* __restrict__ Op, unsigned short* __restrict__ Oh,
                       float* __restrict__ Of, int f32out) {
    __shared__ __align__(16) unsigned short sA[2][64 * 40];  // [hi/lo][row][k], k-stride 40
    __shared__ __align__(16) unsigned short sW[2][64 * 40];  // [hi/lo][n][k]
    int tid = threadIdx.x;
    int gx = blockIdx.x;
    int m0 = (gx >> 1) * 64;
    int n0 = (gx & 1) * 64;
    int lane = tid & 63;
    int w = tid >> 6;           // wave 0..3
    int fm = lane & 15, q = lane >> 4;
    int wr = (w & 1) * 32;      // wave row offset in tile
    int wn = (w >> 1) * 32;     // wave col offset in tile

    f32x4 acc[2][2];
#pragma unroll
    for (int i = 0; i < 2; i++)
#pragma unroll
        for (int j = 0; j < 2; j++) acc[i][j] = (f32x4){0.f, 0.f, 0.f, 0.f};

    for (int c = 0; c < 8; c++) {
        const unsigned* pA = (c < 4) ? Ap : Xp;
        int k0A = (c & 3) * 32;
        int k0W = c * 32;
        __syncthreads();
#pragma unroll
        for (int i = 0; i < 4; i++) {
            int u = tid + 256 * i;           // 0..1023
            uint4 val = make_uint4(0, 0, 0, 0);
            int row = (u >> 3) & 63, seg = u & 7;
            if (u < 512) {
                int grow = m0 + row;
                if (grow < NN)
                    val = *(const uint4*)(pA + (size_t)grow * DD + k0A + seg * 4);
                ushort4 hi, lo;
                hi.x = val.x >> 16; hi.y = val.y >> 16; hi.z = val.z >> 16; hi.w = val.w >> 16;
                lo.x = val.x & 0xFFFF; lo.y = val.y & 0xFFFF; lo.z = val.z & 0xFFFF; lo.w = val.w & 0xFFFF;
                *(ushort4*)&sA[0][row * 40 + seg * 4] = hi;
                *(ushort4*)&sA[1][row * 40 + seg * 4] = lo;
            } else {
                val = *(const uint4*)(Wtp + (size_t)(n0 + row) * 256 + k0W + seg * 4);
                ushort4 hi, lo;
                hi.x = val.x >> 16; hi.y = val.y >> 16; hi.z = val.z >> 16; hi.w = val.w >> 16;
                lo.x = val.x & 0xFFFF; lo.y = val.y & 0xFFFF; lo.z = val.z & 0xFFFF; lo.w = val.w & 0xFFFF;
                *(ushort4*)&sW[0][row * 40 + seg * 4] = hi;
                *(ushort4*)&sW[1][row * 40 + seg * 4] = lo;
            }
        }
        __syncthreads();
        bf16x8 af[2][2];
#pragma unroll
        for (int mt = 0; mt < 2; mt++) {
            int r = wr + mt * 16 + fm;
            af[mt][0] = *(const bf16x8*)&sA[0][r * 40 + q * 8];
            af[mt][1] = *(const bf16x8*)&sA[1][r * 40 + q * 8];
        }
#pragma unroll
        for (int nt = 0; nt < 2; nt++) {
            int nr = wn + nt * 16 + fm;
            bf16x8 wh = *(const bf16x8*)&sW[0][nr * 40 + q * 8];
            bf16x8 wl = *(const bf16x8*)&sW[1][nr * 40 + q * 8];
#pragma unroll
            for (int mt = 0; mt < 2; mt++) {
                acc[mt][nt] = __builtin_amdgcn_mfma_f32_16x16x32_bf16(af[mt][0], wh, acc[mt][nt], 0, 0, 0);
                acc[mt][nt] = __builtin_amdgcn_mfma_f32_16x16x32_bf16(af[mt][0], wl, acc[mt][nt], 0, 0, 0);
                acc[mt][nt] = __builtin_amdgcn_mfma_f32_16x16x32_bf16(af[mt][1], wh, acc[mt][nt], 0, 0, 0);
            }
        }
    }

    float scv[2], shv[2];
#pragma unroll
    for (int nt = 0; nt < 2; nt++) {
        int jj = n0 + wn + nt * 16 + fm;
        float s = g[jj] * rsqrtf(vr[jj] + EPSV);
        scv[nt] = s;
        shv[nt] = (bl[jj] - mn[jj]) * s + be[jj];
    }
#pragma unroll
    for (int mt = 0; mt < 2; mt++) {
#pragma unroll
        for (int r = 0; r < 4; r++) {
            int grow = m0 + wr + mt * 16 + q * 4 + r;
            if (grow < NN) {
#pragma unroll
                for (int nt = 0; nt < 2; nt++) {
                    int gcol = n0 + wn + nt * 16 + fm;
                    float o = fmaxf(acc[mt][nt][r] * scv[nt] + shv[nt], 0.f);
                    if (f32out) {
                        Of[(size_t)grow * DD + gcol] = o;
                    } else {
                        unsigned pv = packbf(o);
                        Op[(size_t)grow * DD + gcol] = pv;
                        Oh[(size_t)grow * DD + gcol] = (unsigned short)(pv >> 16);
                    }
                }
            }
        }
    }
}

// ---------------- global add pool (atomic-free: batch is sorted) ----------------
__launch_bounds__(128)
__global__ void k_pool2(const float* __restrict__ h, const int* __restrict__ batch,
                        float* __restrict__ p) {
    int b = blockIdx.x;
    __shared__ int sr[2];
    if (threadIdx.x < 2) {
        int target = b + (int)threadIdx.x;
        int lo = 0, hi = NN;
        while (lo < hi) {
            int mid = (lo + hi) >> 1;
            if (batch[mid] < target) lo = mid + 1; else hi = mid;
        }
        sr[threadIdx.x] = lo;
    }
    __syncthreads();
    int beg = sr[0], end = sr[1];
    int t = threadIdx.x;
    float acc = 0.f;
    for (int r = beg; r < end; r++) acc += h[(size_t)r * DD + t];
    p[(size_t)b * DD + t] = acc;
}

// ---------------- final MLP head ----------------
__launch_bounds__(128)
__global__ void k_mlp(const float* __restrict__ p1, const float* __restrict__ p2,
                      const int* __restrict__ rel, const float* __restrict__ kge,
                      const float* __restrict__ W1, const float* __restrict__ b1,
                      const float* __restrict__ W2, const float* __restrict__ b2,
                      float* __restrict__ out) {
    int b = blockIdx.x;
    int tid = threadIdx.x;
    __shared__ float z[384];
    z[tid] = p1[(size_t)b * DD + tid];
    z[tid + 128] = p2[(size_t)b * DD + tid];
    int r = rel[b];
    z[tid + 256] = kge[(size_t)r * DD + tid];
    __syncthreads();
    float acc = b1[tid];
#pragma unroll 8
    for (int k = 0; k < 384; k++) acc += z[k] * W1[k * DD + tid];
    float h = fmaxf(acc, 0.f);
    float v = h * W2[tid];
#pragma unroll
    for (int off = 32; off > 0; off >>= 1) v += __shfl_down(v, off, 64);
    __shared__ float wsf[2];
    if ((tid & 63) == 0) wsf[tid >> 6] = v;
    __syncthreads();
    if (tid == 0) out[b] = wsf[0] + wsf[1] + b2[0];
}

extern "C" void kernel_launch(void* const* d_in, const int* in_sizes, int n_in,
                              void* d_out, int out_size, void* d_ws, size_t ws_size,
                              hipStream_t stream) {
    const float* x1  = (const float*)d_in[0];
    const float* x2  = (const float*)d_in[1];
    const int*   ei1 = (const int*)d_in[2];
    const int*   ei2 = (const int*)d_in[3];
    const int*   bt1 = (const int*)d_in[4];
    const int*   bt2 = (const int*)d_in[5];
    const int*   rel = (const int*)d_in[6];
    const float* Wl  = (const float*)d_in[7];
    const float* bl  = (const float*)d_in[8];
    const float* Wr  = (const float*)d_in[9];
    const float* g   = (const float*)d_in[10];
    const float* be  = (const float*)d_in[11];
    const float* mn  = (const float*)d_in[12];
    const float* vr  = (const float*)d_in[13];
    const float* kge = (const float*)d_in[14];
    const float* W1  = (const float*)d_in[15];
    const float* b1v = (const float*)d_in[16];
    const float* W2  = (const float*)d_in[17];
    const float* b2v = (const float*)d_in[18];

    char* ws = (char*)d_ws;
    size_t off = 0;
    auto alloc = [&](size_t bytes) {
        void* p = ws + off;
        off += (bytes + 255) & ~(size_t)255;
        return p;
    };
    unsigned* ap   = (unsigned*)alloc((size_t)NN * DD * 4);
    unsigned* op   = (unsigned*)alloc((size_t)NN * DD * 4);   // layer-2 fp32 out aliases
    unsigned* xp   = (unsigned*)alloc((size_t)NN * DD * 4);
    unsigned short* xh = (unsigned short*)alloc((size_t)NN * DD * 2);
    unsigned short* oh = (unsigned short*)alloc((size_t)NN * DD * 2);
    unsigned* wtp  = (unsigned*)alloc((size_t)3 * 128 * 256 * 4);
    float* p1      = (float*)alloc((size_t)NB * DD * 4);
    float* p2      = (float*)alloc((size_t)NB * DD * 4);
    int*   bcnt    = (int*)alloc((size_t)2 * NCHUNK * NBKT * 4);
    int*   btot    = (int*)alloc((size_t)2 * NBKT * 4);
    int*   bbase   = (int*)alloc((size_t)2 * NBKT * 4);
    int2*  part    = (int2*)alloc((size_t)2 * NE * 8);
    int*   ptr0    = (int*)alloc((size_t)(NN + 1) * 4);
    int*   ptr1    = (int*)alloc((size_t)(NN + 1) * 4);
    float* invd0   = (float*)alloc((size_t)NN * 4);
    float* invd1   = (float*)alloc((size_t)NN * 4);
    int*   csr0    = (int*)alloc((size_t)NE * 4);
    int*   csr1    = (int*)alloc((size_t)NE * 4);
    if (off > ws_size) return;

    float* cf = (float*)op;  // layer-2 fp32 output aliases op (dead by then)

    const int nbNode4 = (NN + 3) / 4;            // 12500
    const int nbGemm = ((NN + 63) / 64) * 2;     // 1564
    const int nbCvt = (NN * DD / 4 + 255) / 256;

    k_wcvt<<<(3 * 128 * 256 + 255) / 256, 256, 0, stream>>>(Wl, Wr, wtp);

    // atomic-free CSR build (LDS atomics only)
    k_hist<<<2 * NCHUNK, 256, 0, stream>>>(ei1 + NE, ei2 + NE, bcnt);
    k_s1<<<2 * NBKT, 256, 0, stream>>>(bcnt, btot);
    k_s2<<<2, 256, 0, stream>>>(btot, bbase, ptr0, ptr1);
    k_part<<<2 * NCHUNK, 256, 0, stream>>>(ei1, ei1 + NE, ei2, ei2 + NE, bcnt, bbase, part);
    k_csr<<<2 * NBKT, 256, 0, stream>>>(part, bbase, ptr0, ptr1, invd0, invd1, csr0, csr1);

    for (int side = 0; side < 2; side++) {
        const float* x   = side ? x2 : x1;
        const int*   ptr = side ? ptr1 : ptr0;
        const int*   csr = side ? csr1 : csr0;
        const float* ivd = side ? invd1 : invd0;
        const int*   bat = side ? bt2 : bt1;
        float*       pp  = side ? p2 : p1;

        k_cvt<<<nbCvt, 256, 0, stream>>>(x, xp, xh, NN * DD / 4);

        // layer 0: gather(xh)->ap ; gemm(ap, xp, W0) -> op + oh
        k_gather<<<nbNode4, 256, 0, stream>>>(xh, ptr, csr, ivd, ap);
        k_gemm<<<nbGemm, 256, 0, stream>>>(ap, xp, wtp, bl, g, be, mn, vr,
                                           op, oh, (float*)nullptr, 0);
        // layer 1: gather(oh)->ap ; gemm(ap, op, W1) -> xp + xh
        k_gather<<<nbNode4, 256, 0, stream>>>(oh, ptr, csr, ivd, ap);
        k_gemm<<<nbGemm, 256, 0, stream>>>(ap, op, wtp + 32768, bl + 128, g + 128,
                                           be + 128, mn + 128, vr + 128,
                                           xp, xh, (float*)nullptr, 0);
        // layer 2: gather(xh)->ap ; gemm(ap, xp, W2) -> cf (fp32)
        k_gather<<<nbNode4, 256, 0, stream>>>(xh, ptr, csr, ivd, ap);
        k_gemm<<<nbGemm, 256, 0, stream>>>(ap, xp, wtp + 65536, bl + 256, g + 256,
                                           be + 256, mn + 256, vr + 256,
                                           (unsigned*)nullptr, (unsigned short*)nullptr, cf, 1);

        k_pool2<<<NB, 128, 0, stream>>>(cf, bat, pp);
    }

    k_mlp<<<NB, 128, 0, stream>>>(p1, p2, rel, kge, W1, b1v, W2, b2v, (float*)d_out);
}

// Round 10
// 469.649 us; speedup vs baseline: 2.3770x; 1.1963x over previous
//
#include <hip/hip_runtime.h>

#define NN 50000
#define NE 600000
#define NB 4096
#define DD 128
#define EPSV 1e-5f
#define NBKT 196     // ceil(50000/256) buckets of 256 node ids (per side)
#define NCHUNK 256   // edge chunks per side
#define CHSZ ((NE + NCHUNK - 1) / NCHUNK)   // 2344

typedef __bf16 bf16x8 __attribute__((ext_vector_type(8)));
typedef float f32x4 __attribute__((ext_vector_type(4)));

__device__ inline unsigned short f2bf(float f) {
    unsigned u = __float_as_uint(f);
    u = (u + 0x7FFFu + ((u >> 16) & 1u)) >> 16;
    return (unsigned short)u;
}
__device__ inline float bf2f(unsigned short h) {
    return __uint_as_float(((unsigned)h) << 16);
}

// ---------------- input conversion: fp32 -> hi/lo bf16 planes (both sides) ----------------
__global__ void k_cvt(const float* __restrict__ x1, const float* __restrict__ x2,
                      unsigned short* __restrict__ xh, unsigned short* __restrict__ xl) {
    int i = blockIdx.x * 256 + threadIdx.x;          // over 2*NN*32 float4 groups
    if (i >= 2 * NN * 32) return;
    const float* x = (i < NN * 32) ? x1 : x2;
    int j = (i < NN * 32) ? i : i - NN * 32;
    float4 v = ((const float4*)x)[j];
    ushort4 h, l;
    h.x = f2bf(v.x); l.x = f2bf(v.x - bf2f(h.x));
    h.y = f2bf(v.y); l.y = f2bf(v.y - bf2f(h.y));
    h.z = f2bf(v.z); l.z = f2bf(v.z - bf2f(h.z));
    h.w = f2bf(v.w); l.w = f2bf(v.w - bf2f(h.w));
    ((ushort4*)xh)[i] = h;
    ((ushort4*)xl)[i] = l;
}

// weights packed hi|lo uint: Wt[layer][n][k], k<128 -> Wl[k][n], k>=128 -> Wr[k-128][n];
// then W1t[n][k] (k in [0,384)) at offset 98304
__global__ void k_wcvt(const float* __restrict__ Wl, const float* __restrict__ Wr,
                       const float* __restrict__ W1, unsigned* __restrict__ wtp) {
    int t = blockIdx.x * 256 + threadIdx.x;
    if (t >= 3 * 128 * 256 + 128 * 384) return;
    float w;
    int idx;
    if (t < 3 * 128 * 256) {
        int k = t & 255;
        int n = (t >> 8) & 127;
        int l = t >> 15;
        w = (k < 128) ? Wl[l * 16384 + k * 128 + n] : Wr[l * 16384 + (k - 128) * 128 + n];
        idx = t;
    } else {
        int u = t - 3 * 128 * 256;
        int n = u / 384;
        int k = u - n * 384;
        w = W1[k * 128 + n];
        idx = t;
    }
    unsigned short h = f2bf(w);
    unsigned short l = f2bf(w - bf2f(h));
    wtp[idx] = ((unsigned)h << 16) | (unsigned)l;
}

// ---------------- CSR build: atomic-free two-level counting sort (LDS atomics only) ----------------
__global__ void k_hist(const int* __restrict__ d0, const int* __restrict__ d1,
                       int* __restrict__ bcnt) {
    int side = (blockIdx.x >= NCHUNK) ? 1 : 0;
    int c = blockIdx.x - side * NCHUNK;
    const int* dst = side ? d1 : d0;
    int tid = threadIdx.x;
    __shared__ int h[NBKT];
    for (int i = tid; i < NBKT; i += 256) h[i] = 0;
    __syncthreads();
    int e0 = c * CHSZ, e1 = min(e0 + CHSZ, NE);
    for (int e = e0 + tid; e < e1; e += 256) atomicAdd(&h[dst[e] >> 8], 1);
    __syncthreads();
    int* bc = bcnt + ((size_t)side * NCHUNK + c) * NBKT;
    for (int i = tid; i < NBKT; i += 256) bc[i] = h[i];
}

__global__ void k_s1(int* __restrict__ bcnt, int* __restrict__ btot) {
    int side = (blockIdx.x >= NBKT) ? 1 : 0;
    int b = blockIdx.x - side * NBKT;
    int tid = threadIdx.x;            // tid == chunk
    int idx = ((size_t)side * NCHUNK + tid) * NBKT + b;
    int v = bcnt[idx];
    int lane = tid & 63, wv = tid >> 6;
    int x = v;
#pragma unroll
    for (int off = 1; off < 64; off <<= 1) {
        int y = __shfl_up(x, off, 64);
        if (lane >= off) x += y;
    }
    __shared__ int ws4[4];
    if (lane == 63) ws4[wv] = x;
    __syncthreads();
    int add = 0;
#pragma unroll
    for (int w = 0; w < 4; w++)
        if (w < wv) add += ws4[w];
    int incl = x + add;
    bcnt[idx] = incl - v;
    if (tid == 255) btot[side * NBKT + b] = incl;
}

__global__ void k_s2(const int* __restrict__ btot, int* __restrict__ bbase,
                     int* __restrict__ ptrC) {
    int side = blockIdx.x;
    int tid = threadIdx.x;
    int v = (tid < NBKT) ? btot[side * NBKT + tid] : 0;
    int lane = tid & 63, wv = tid >> 6;
    int x = v;
#pragma unroll
    for (int off = 1; off < 64; off <<= 1) {
        int y = __shfl_up(x, off, 64);
        if (lane >= off) x += y;
    }
    __shared__ int ws4[4];
    if (lane == 63) ws4[wv] = x;
    __syncthreads();
    int add = 0;
#pragma unroll
    for (int w = 0; w < 4; w++)
        if (w < wv) add += ws4[w];
    int incl = x + add;
    if (tid < NBKT) bbase[side * NBKT + tid] = incl - v;
    if (tid == 0 && side == 1) ptrC[2 * NN] = 2 * NE;
}

// partition: part[side*NE + pos] = (src_global << 8) | (dst & 255)
__global__ void k_part(const int* __restrict__ s0, const int* __restrict__ d0,
                       const int* __restrict__ s1, const int* __restrict__ d1,
                       const int* __restrict__ bcnt, const int* __restrict__ bbase,
                       int* __restrict__ part) {
    int side = (blockIdx.x >= NCHUNK) ? 1 : 0;
    int c = blockIdx.x - side * NCHUNK;
    const int* src = side ? s1 : s0;
    const int* dst = side ? d1 : d0;
    int tid = threadIdx.x;
    __shared__ int off[NBKT];
    const int* bc = bcnt + ((size_t)side * NCHUNK + c) * NBKT;
    for (int i = tid; i < NBKT; i += 256) off[i] = bbase[side * NBKT + i] + bc[i];
    __syncthreads();
    int e0 = c * CHSZ, e1 = min(e0 + CHSZ, NE);
    int* P = part + (size_t)side * NE;
    int soff = side * NN;
    for (int e = e0 + tid; e < e1; e += 256) {
        int d = dst[e];
        int pos = atomicAdd(&off[d >> 8], 1);
        P[pos] = ((src[e] + soff) << 8) | (d & 255);
    }
}

// per bucket: count, scan -> ptrC/invd (combined), place src into combined CSR
__global__ void k_csr(const int* __restrict__ part, const int* __restrict__ bbase,
                      int* __restrict__ ptrC, float* __restrict__ invdC,
                      int* __restrict__ csrC) {
    int side = (blockIdx.x >= NBKT) ? 1 : 0;
    int b = blockIdx.x - side * NBKT;
    int tid = threadIdx.x;
    const int* P = part + (size_t)side * NE;
    int base = bbase[side * NBKT + b];
    int endp = (b == NBKT - 1) ? NE : bbase[side * NBKT + b + 1];
    __shared__ int cnt[256];
    cnt[tid] = 0;
    __syncthreads();
    for (int e = base + tid; e < endp; e += 256) atomicAdd(&cnt[P[e] & 255], 1);
    __syncthreads();
    int v = cnt[tid];
    int lane = tid & 63, wv = tid >> 6;
    int x = v;
#pragma unroll
    for (int off = 1; off < 64; off <<= 1) {
        int y = __shfl_up(x, off, 64);
        if (lane >= off) x += y;
    }
    __shared__ int ws4[4];
    if (lane == 63) ws4[wv] = x;
    __syncthreads();
    int add = 0;
#pragma unroll
    for (int w = 0; w < 4; w++)
        if (w < wv) add += ws4[w];
    int excl = x + add - v;
    int node = (b << 8) + tid;
    if (node < NN) {
        ptrC[side * NN + node] = side * NE + base + excl;
        invdC[side * NN + node] = 1.0f / (float)(v > 1 ? v : 1);
    }
    __syncthreads();
    cnt[tid] = excl;
    __syncthreads();
    for (int e = base + tid; e < endp; e += 256) {
        int p = P[e];
        int pos = atomicAdd(&cnt[p & 255], 1);
        csrC[(size_t)side * NE + base + pos] = p >> 8;
    }
}

// ---------------- neighbor mean-aggregation (hi plane in, hi plane out; both sides) ----------------
__global__ void k_gather(const unsigned short* __restrict__ xh, const int* __restrict__ ptr,
                         const int* __restrict__ csr, const float* __restrict__ invd,
                         unsigned short* __restrict__ aggH) {
    int wid = threadIdx.x >> 6;
    int lane = threadIdx.x & 63;
    int half = lane >> 5;
    int l32 = lane & 31;
    int n = blockIdx.x * 4 + wid;
    if (n >= 2 * NN) return;
    int beg = ptr[n], end = ptr[n + 1];
    f32x4 a0 = {0.f, 0.f, 0.f, 0.f}, a1 = {0.f, 0.f, 0.f, 0.f};
    f32x4 a2 = {0.f, 0.f, 0.f, 0.f}, a3 = {0.f, 0.f, 0.f, 0.f};
    for (int e = beg + half; e < end; e += 8) {
        int e1 = e + 2, e2 = e + 4, e3 = e + 6;
        int i0 = csr[e];
        int i1 = csr[min(e1, end - 1)];
        int i2 = csr[min(e2, end - 1)];
        int i3 = csr[min(e3, end - 1)];
        float w1 = (e1 < end) ? 1.f : 0.f;
        float w2 = (e2 < end) ? 1.f : 0.f;
        float w3 = (e3 < end) ? 1.f : 0.f;
        ushort4 v0 = *(const ushort4*)(xh + (size_t)i0 * DD + l32 * 4);
        ushort4 v1 = *(const ushort4*)(xh + (size_t)i1 * DD + l32 * 4);
        ushort4 v2 = *(const ushort4*)(xh + (size_t)i2 * DD + l32 * 4);
        ushort4 v3 = *(const ushort4*)(xh + (size_t)i3 * DD + l32 * 4);
        a0.x += bf2f(v0.x); a0.y += bf2f(v0.y); a0.z += bf2f(v0.z); a0.w += bf2f(v0.w);
        a1.x += w1 * bf2f(v1.x); a1.y += w1 * bf2f(v1.y); a1.z += w1 * bf2f(v1.z); a1.w += w1 * bf2f(v1.w);
        a2.x += w2 * bf2f(v2.x); a2.y += w2 * bf2f(v2.y); a2.z += w2 * bf2f(v2.z); a2.w += w2 * bf2f(v2.w);
        a3.x += w3 * bf2f(v3.x); a3.y += w3 * bf2f(v3.y); a3.z += w3 * bf2f(v3.z); a3.w += w3 * bf2f(v3.w);
    }
    a0.x += a1.x + a2.x + a3.x;
    a0.y += a1.y + a2.y + a3.y;
    a0.z += a1.z + a2.z + a3.z;
    a0.w += a1.w + a2.w + a3.w;
    a0.x += __shfl_down(a0.x, 32, 64);
    a0.y += __shfl_down(a0.y, 32, 64);
    a0.z += __shfl_down(a0.z, 32, 64);
    a0.w += __shfl_down(a0.w, 32, 64);
    if (half == 0) {
        float id = invd[n];
        ushort4 o;
        o.x = f2bf(a0.x * id);
        o.y = f2bf(a0.y * id);
        o.z = f2bf(a0.z * id);
        o.w = f2bf(a0.w * id);
        *(ushort4*)(aggH + (size_t)n * DD + l32 * 4) = o;
    }
}

// ---------------- fused SAGE layer GEMM: split-bf16 MFMA, both sides (M = 2NN) ----------------
// A operand (agg) = hi only (2 MFMAs); X operand = hi+lo (3 MFMAs).
__launch_bounds__(256)
__global__ void k_gemm(const unsigned short* __restrict__ AH,
                       const unsigned short* __restrict__ XH, const unsigned short* __restrict__ XL,
                       const unsigned* __restrict__ Wtp,
                       const float* __restrict__ bl, const float* __restrict__ g,
                       const float* __restrict__ be, const float* __restrict__ mn,
                       const float* __restrict__ vr,
                       unsigned short* __restrict__ OH, unsigned short* __restrict__ OL,
                       float* __restrict__ Of, int f32out) {
    __shared__ __align__(16) unsigned short sA[2][64 * 40];  // [hi/lo][row][k]
    __shared__ __align__(16) unsigned short sW[2][64 * 40];
    int tid = threadIdx.x;
    int gx = blockIdx.x;
    int m0 = (gx >> 1) * 64;
    int n0 = (gx & 1) * 64;
    int lane = tid & 63;
    int w = tid >> 6;
    int fm = lane & 15, q = lane >> 4;
    int wr = (w & 1) * 32;
    int wn = (w >> 1) * 32;

    f32x4 acc[2][2];
#pragma unroll
    for (int i = 0; i < 2; i++)
#pragma unroll
        for (int j = 0; j < 2; j++) acc[i][j] = (f32x4){0.f, 0.f, 0.f, 0.f};

    for (int c = 0; c < 8; c++) {
        int isA = (c < 4);
        const unsigned short* SH = isA ? AH : XH;
        const unsigned short* SL = isA ? (const unsigned short*)0 : XL;
        int k0 = (c & 3) * 32;
        int k0W = c * 32;
        __syncthreads();
#pragma unroll
        for (int i = 0; i < 2; i++) {
            int u = tid + 256 * i;           // 0..511: A/X rows
            int row = u >> 3, seg = u & 7;
            int grow = m0 + row;
            size_t goff = (size_t)grow * DD + k0 + seg * 4;
            ushort4 hv = make_ushort4(0, 0, 0, 0);
            if (grow < 2 * NN) hv = *(const ushort4*)(SH + goff);
            *(ushort4*)&sA[0][row * 40 + seg * 4] = hv;
            if (!isA) {
                ushort4 lv = make_ushort4(0, 0, 0, 0);
                if (grow < 2 * NN) lv = *(const ushort4*)(SL + goff);
                *(ushort4*)&sA[1][row * 40 + seg * 4] = lv;
            }
        }
#pragma unroll
        for (int i = 0; i < 2; i++) {
            int u = tid + 256 * i;           // 0..511: W rows
            int row = u >> 3, seg = u & 7;
            uint4 val = *(const uint4*)(Wtp + (size_t)(n0 + row) * 256 + k0W + seg * 4);
            ushort4 hi, lo;
            hi.x = val.x >> 16; hi.y = val.y >> 16; hi.z = val.z >> 16; hi.w = val.w >> 16;
            lo.x = val.x & 0xFFFF; lo.y = val.y & 0xFFFF; lo.z = val.z & 0xFFFF; lo.w = val.w & 0xFFFF;
            *(ushort4*)&sW[0][row * 40 + seg * 4] = hi;
            *(ushort4*)&sW[1][row * 40 + seg * 4] = lo;
        }
        __syncthreads();
        bf16x8 afh[2], afl[2];
#pragma unroll
        for (int mt = 0; mt < 2; mt++) {
            int r = wr + mt * 16 + fm;
            afh[mt] = *(const bf16x8*)&sA[0][r * 40 + q * 8];
            if (!isA) afl[mt] = *(const bf16x8*)&sA[1][r * 40 + q * 8];
        }
#pragma unroll
        for (int nt = 0; nt < 2; nt++) {
            int nr = wn + nt * 16 + fm;
            bf16x8 wh = *(const bf16x8*)&sW[0][nr * 40 + q * 8];
            bf16x8 wl = *(const bf16x8*)&sW[1][nr * 40 + q * 8];
#pragma unroll
            for (int mt = 0; mt < 2; mt++) {
                acc[mt][nt] = __builtin_amdgcn_mfma_f32_16x16x32_bf16(afh[mt], wh, acc[mt][nt], 0, 0, 0);
                acc[mt][nt] = __builtin_amdgcn_mfma_f32_16x16x32_bf16(afh[mt], wl, acc[mt][nt], 0, 0, 0);
                if (!isA)
                    acc[mt][nt] = __builtin_amdgcn_mfma_f32_16x16x32_bf16(afl[mt], wh, acc[mt][nt], 0, 0, 0);
            }
        }
    }

    float scv[2], shv[2];
#pragma unroll
    for (int nt = 0; nt < 2; nt++) {
        int jj = n0 + wn + nt * 16 + fm;
        float s = g[jj] * rsqrtf(vr[jj] + EPSV);
        scv[nt] = s;
        shv[nt] = (bl[jj] - mn[jj]) * s + be[jj];
    }
#pragma unroll
    for (int mt = 0; mt < 2; mt++) {
#pragma unroll
        for (int r = 0; r < 4; r++) {
            int grow = m0 + wr + mt * 16 + q * 4 + r;
            if (grow < 2 * NN) {
#pragma unroll
                for (int nt = 0; nt < 2; nt++) {
                    int gcol = n0 + wn + nt * 16 + fm;
                    float o = fmaxf(acc[mt][nt][r] * scv[nt] + shv[nt], 0.f);
                    if (f32out) {
                        Of[(size_t)grow * DD + gcol] = o;
                    } else {
                        unsigned short h = f2bf(o);
                        OH[(size_t)grow * DD + gcol] = h;
                        OL[(size_t)grow * DD + gcol] = f2bf(o - bf2f(h));
                    }
                }
            }
        }
    }
}

// ---------------- global add pool (atomic-free: batch sorted; both sides) ----------------
__launch_bounds__(128)
__global__ void k_pool2(const float* __restrict__ cf, const int* __restrict__ bt1,
                        const int* __restrict__ bt2, float* __restrict__ ppool) {
    int side = (blockIdx.x >= NB) ? 1 : 0;
    int b = blockIdx.x - side * NB;
    const int* batch = side ? bt2 : bt1;
    const float* h = cf + (size_t)side * NN * DD;
    __shared__ int sr[2];
    if (threadIdx.x < 2) {
        int target = b + (int)threadIdx.x;
        int lo = 0, hi = NN;
        while (lo < hi) {
            int mid = (lo + hi) >> 1;
            if (batch[mid] < target) lo = mid + 1; else hi = mid;
        }
        sr[threadIdx.x] = lo;
    }
    __syncthreads();
    int beg = sr[0], end = sr[1];
    int t = threadIdx.x;
    float acc = 0.f;
    for (int r = beg; r < end; r++) acc += h[(size_t)r * DD + t];
    ppool[((size_t)side * NB + b) * DD + t] = acc;
}

// ---------------- z build: concat(p1,p2,kge[rel]) -> hi/lo planes [NB][384] ----------------
__global__ void k_zb(const float* __restrict__ ppool, const int* __restrict__ rel,
                     const float* __restrict__ kge,
                     unsigned short* __restrict__ zh, unsigned short* __restrict__ zl) {
    int t = blockIdx.x * 256 + threadIdx.x;
    if (t >= NB * 384) return;
    int b = t / 384;
    int j = t - b * 384;
    float v;
    if (j < 128) v = ppool[(size_t)b * DD + j];
    else if (j < 256) v = ppool[(size_t)NB * DD + (size_t)b * DD + (j - 128)];
    else v = kge[(size_t)rel[b] * 128 + (j - 256)];
    unsigned short h = f2bf(v);
    zh[t] = h;
    zl[t] = f2bf(v - bf2f(h));
}

// ---------------- MLP head: split-bf16 MFMA GEMM + fused relu·W2 reduction ----------------
// M=NB (graphs), K=384, N=128. BM=32, BN=128; 256 threads = 4 waves, each wave 32 cols.
__launch_bounds__(256)
__global__ void k_mlp2(const unsigned short* __restrict__ zh, const unsigned short* __restrict__ zl,
                       const unsigned* __restrict__ w1p,
                       const float* __restrict__ b1, const float* __restrict__ W2,
                       const float* __restrict__ b2, float* __restrict__ out) {
    __shared__ __align__(16) unsigned short sZ[2][32 * 40];
    __shared__ __align__(16) unsigned short sW[2][128 * 40];
    __shared__ float hpart[32][4];
    int tid = threadIdx.x;
    int m0 = blockIdx.x * 32;
    int lane = tid & 63, w = tid >> 6;
    int fm = lane & 15, q = lane >> 4;
    int wn = w * 32;

    f32x4 acc[2][2];
#pragma unroll
    for (int i = 0; i < 2; i++)
#pragma unroll
        for (int j = 0; j < 2; j++) acc[i][j] = (f32x4){0.f, 0.f, 0.f, 0.f};

    for (int c = 0; c < 12; c++) {
        int k0 = c * 32;
        __syncthreads();
        {   // Z: 32 rows x 8 segs = 256 slots
            int row = tid >> 3, seg = tid & 7;
            size_t off = (size_t)(m0 + row) * 384 + k0 + seg * 4;
            *(ushort4*)&sZ[0][row * 40 + seg * 4] = *(const ushort4*)(zh + off);
            *(ushort4*)&sZ[1][row * 40 + seg * 4] = *(const ushort4*)(zl + off);
        }
#pragma unroll
        for (int i = 0; i < 4; i++) {   // W1: 128 rows x 8 segs = 1024 slots
            int u = tid + 256 * i;
            int row = u >> 3, seg = u & 7;
            uint4 val = *(const uint4*)(w1p + (size_t)row * 384 + k0 + seg * 4);
            ushort4 hi, lo;
            hi.x = val.x >> 16; hi.y = val.y >> 16; hi.z = val.z >> 16; hi.w = val.w >> 16;
            lo.x = val.x & 0xFFFF; lo.y = val.y & 0xFFFF; lo.z = val.z & 0xFFFF; lo.w = val.w & 0xFFFF;
            *(ushort4*)&sW[0][row * 40 + seg * 4] = hi;
            *(ushort4*)&sW[1][row * 40 + seg * 4] = lo;
        }
        __syncthreads();
        bf16x8 zfh[2], zfl[2];
#pragma unroll
        for (int mt = 0; mt < 2; mt++) {
            int r = mt * 16 + fm;
            zfh[mt] = *(const bf16x8*)&sZ[0][r * 40 + q * 8];
            zfl[mt] = *(const bf16x8*)&sZ[1][r * 40 + q * 8];
        }
#pragma unroll
        for (int nt = 0; nt < 2; nt++) {
            int nr = wn + nt * 16 + fm;
            bf16x8 wh = *(const bf16x8*)&sW[0][nr * 40 + q * 8];
            bf16x8 wl = *(const bf16x8*)&sW[1][nr * 40 + q * 8];
#pragma unroll
            for (int mt = 0; mt < 2; mt++) {
                acc[mt][nt] = __builtin_amdgcn_mfma_f32_16x16x32_bf16(zfh[mt], wh, acc[mt][nt], 0, 0, 0);
                acc[mt][nt] = __builtin_amdgcn_mfma_f32_16x16x32_bf16(zfh[mt], wl, acc[mt][nt], 0, 0, 0);
                acc[mt][nt] = __builtin_amdgcn_mfma_f32_16x16x32_bf16(zfl[mt], wh, acc[mt][nt], 0, 0, 0);
            }
        }
    }

    float b1v[2], w2v[2];
#pragma unroll
    for (int nt = 0; nt < 2; nt++) {
        int col = wn + nt * 16 + fm;
        b1v[nt] = b1[col];
        w2v[nt] = W2[col];
    }
#pragma unroll
    for (int mt = 0; mt < 2; mt++) {
#pragma unroll
        for (int r = 0; r < 4; r++) {
            float val = 0.f;
#pragma unroll
            for (int nt = 0; nt < 2; nt++)
                val += fmaxf(acc[mt][nt][r] + b1v[nt], 0.f) * w2v[nt];
#pragma unroll
            for (int m = 1; m < 16; m <<= 1) val += __shfl_xor(val, m, 64);
            if (fm == 0) hpart[mt * 16 + q * 4 + r][w] = val;
        }
    }
    __syncthreads();
    if (tid < 32)
        out[m0 + tid] = hpart[tid][0] + hpart[tid][1] + hpart[tid][2] + hpart[tid][3] + b2[0];
}

extern "C" void kernel_launch(void* const* d_in, const int* in_sizes, int n_in,
                              void* d_out, int out_size, void* d_ws, size_t ws_size,
                              hipStream_t stream) {
    const float* x1  = (const float*)d_in[0];
    const float* x2  = (const float*)d_in[1];
    const int*   ei1 = (const int*)d_in[2];
    const int*   ei2 = (const int*)d_in[3];
    const int*   bt1 = (const int*)d_in[4];
    const int*   bt2 = (const int*)d_in[5];
    const int*   rel = (const int*)d_in[6];
    const float* Wl  = (const float*)d_in[7];
    const float* bl  = (const float*)d_in[8];
    const float* Wr  = (const float*)d_in[9];
    const float* g   = (const float*)d_in[10];
    const float* be  = (const float*)d_in[11];
    const float* mn  = (const float*)d_in[12];
    const float* vr  = (const float*)d_in[13];
    const float* kge = (const float*)d_in[14];
    const float* W1  = (const float*)d_in[15];
    const float* b1v = (const float*)d_in[16];
    const float* W2  = (const float*)d_in[17];
    const float* b2v = (const float*)d_in[18];

    char* ws = (char*)d_ws;
    size_t off = 0;
    auto alloc = [&](size_t bytes) {
        void* p = ws + off;
        off += (bytes + 255) & ~(size_t)255;
        return p;
    };
    const size_t PL = (size_t)2 * NN * DD;      // elements per plane
    unsigned short* xbufH = (unsigned short*)alloc(PL * 2);
    unsigned short* xbufL = (unsigned short*)alloc(PL * 2);
    unsigned short* obufH = (unsigned short*)alloc(PL * 2);   // cf aliases obufH+obufL
    unsigned short* obufL = (unsigned short*)alloc(PL * 2);
    unsigned short* aggH  = (unsigned short*)alloc(PL * 2);
    unsigned* wtp  = (unsigned*)alloc((size_t)(3 * 128 * 256 + 128 * 384) * 4);
    float* ppool   = (float*)alloc((size_t)2 * NB * DD * 4);
    unsigned short* zh = (unsigned short*)alloc((size_t)NB * 384 * 2);
    unsigned short* zl = (unsigned short*)alloc((size_t)NB * 384 * 2);
    int*   bcnt    = (int*)alloc((size_t)2 * NCHUNK * NBKT * 4);
    int*   btot    = (int*)alloc((size_t)2 * NBKT * 4);
    int*   bbase   = (int*)alloc((size_t)2 * NBKT * 4);
    int*   part    = (int*)alloc((size_t)2 * NE * 4);
    int*   ptrC    = (int*)alloc((size_t)(2 * NN + 1) * 4);
    float* invdC   = (float*)alloc((size_t)2 * NN * 4);
    int*   csrC    = (int*)alloc((size_t)2 * NE * 4);
    if (off > ws_size) return;

    float* cf = (float*)obufH;   // 2NN*DD fp32 spans obufH+obufL (contiguous)

    const int nbCvt   = 12500;                       // 2*NN*32 / 256
    const int nbNode4 = (2 * NN + 3) / 4;            // 25000
    const int nbGemm  = ((2 * NN + 63) / 64) * 2;    // 3126
    const int nbW     = (3 * 128 * 256 + 128 * 384 + 255) / 256;

    k_wcvt<<<nbW, 256, 0, stream>>>(Wl, Wr, W1, wtp);

    // atomic-free combined CSR build (LDS atomics only)
    k_hist<<<2 * NCHUNK, 256, 0, stream>>>(ei1 + NE, ei2 + NE, bcnt);
    k_s1<<<2 * NBKT, 256, 0, stream>>>(bcnt, btot);
    k_s2<<<2, 256, 0, stream>>>(btot, bbase, ptrC);
    k_part<<<2 * NCHUNK, 256, 0, stream>>>(ei1, ei1 + NE, ei2, ei2 + NE, bcnt, bbase, part);
    k_csr<<<2 * NBKT, 256, 0, stream>>>(part, bbase, ptrC, invdC, csrC);

    k_cvt<<<nbCvt, 256, 0, stream>>>(x1, x2, xbufH, xbufL);

    // layer 0
    k_gather<<<nbNode4, 256, 0, stream>>>(xbufH, ptrC, csrC, invdC, aggH);
    k_gemm<<<nbGemm, 256, 0, stream>>>(aggH, xbufH, xbufL, wtp, bl, g, be, mn, vr,
                                       obufH, obufL, (float*)nullptr, 0);
    // layer 1
    k_gather<<<nbNode4, 256, 0, stream>>>(obufH, ptrC, csrC, invdC, aggH);
    k_gemm<<<nbGemm, 256, 0, stream>>>(aggH, obufH, obufL, wtp + 32768, bl + 128, g + 128,
                                       be + 128, mn + 128, vr + 128,
                                       xbufH, xbufL, (float*)nullptr, 0);
    // layer 2 -> fp32 (aliases obuf)
    k_gather<<<nbNode4, 256, 0, stream>>>(xbufH, ptrC, csrC, invdC, aggH);
    k_gemm<<<nbGemm, 256, 0, stream>>>(aggH, xbufH, xbufL, wtp + 65536, bl + 256, g + 256,
                                       be + 256, mn + 256, vr + 256,
                                       (unsigned short*)nullptr, (unsigned short*)nullptr, cf, 1);

    k_pool2<<<2 * NB, 128, 0, stream>>>(cf, bt1, bt2, ppool);
    k_zb<<<(NB * 384 + 255) / 256, 256, 0, stream>>>(ppool, rel, kge, zh, zl);
    k_mlp2<<<NB / 32, 256, 0, stream>>>(zh, zl, wtp + 98304, b1v, W2, b2v, (float*)d_out);
}